// Round 6
// baseline (285.574 us; speedup 1.0000x reference)
//
#include <hip/hip_runtime.h>
#include <hip/hip_bf16.h>

// Problem constants
constexpr int B_ = 8;
constexpr int L_ = 2048;
constexpr int C_ = 512;
constexpr int R_ = 64;
constexpr int DK_ = 64;
constexpr int H_ = 1024;   // 2*C
constexpr int M_ = B_ * L_;  // 16384
constexpr int NQKV_ = 1152;  // 64 + 64 + 1024 (q|k|v concat)
constexpr float NEG_ = -32767.0f;

__device__ __forceinline__ float toF(float x) { return x; }
__device__ __forceinline__ float toF(__hip_bfloat16 x) { return __bfloat162float(x); }
__device__ __forceinline__ float siluf(float v) { return v / (1.0f + __expf(-v)); }
__device__ __forceinline__ ushort bfbits(float f) {
    __hip_bfloat16 h = __float2bfloat16(f);
    union { __hip_bfloat16 h; ushort u; } cv; cv.h = h; return cv.u;
}
__device__ __forceinline__ float bf2f(ushort u) {
    union { uint u; float f; } cv; cv.u = (uint)u << 16; return cv.f;
}

typedef __attribute__((ext_vector_type(8))) short bf16x8;   // 8 bf16 (4 VGPRs)
typedef __attribute__((ext_vector_type(4))) float f32x4;    // 4 fp32 acc

#define GLOBAL_AS __attribute__((address_space(1)))
#define LDS_AS    __attribute__((address_space(3)))
__device__ __forceinline__ void glds16(const ushort* g, ushort* l) {
    __builtin_amdgcn_global_load_lds((const GLOBAL_AS void*)g, (LDS_AS void*)l, 16, 0, 0);
}

// counted-vmcnt + raw barrier helpers (T4): loads stay in flight across barriers.
#define VMCNT(n) asm volatile("s_waitcnt vmcnt(" #n ")" ::: "memory")
#define BARRIER() do { __builtin_amdgcn_s_barrier(); asm volatile("" ::: "memory"); } while (0)

// ---------------------------------------------------------------------------
// MFMA bf16 GEMM, 128x128 tile, BK=32, 4 waves (2x2 of 64x64).
// 3-buffer, 2-deep prefetch, counted vmcnt(4). Used ONLY for qkv (grid 36).
// EPI 0: silu(acc+bias[n]) -> bf16   [round-4 verified]
// ---------------------------------------------------------------------------
template <int EPI>
__global__ __launch_bounds__(256) void mfma_gemm5(
    const ushort* __restrict__ A, const ushort* __restrict__ Bt,
    const float* __restrict__ bias,
    const float* __restrict__ residF, const ushort* __restrict__ residB,
    const int* __restrict__ mask,
    ushort* __restrict__ outB, float* __restrict__ outF, float* __restrict__ outF2,
    int Ndim, int Kdim, int gridN, long bBatch)
{
    __shared__ ushort As[3][128 * 32];   // 3 x 8 KB
    __shared__ ushort Bs[3][128 * 32];

    const int i = blockIdx.x;
    const int G = gridDim.x >> 3;        // blocks per XCD
    const int gi = (gridDim.x & 7) ? i : ((i & 7) * G + (i >> 3));
    const int nt = gi % gridN, mt = gi / gridN;
    const int m0 = mt * 128, n0 = nt * 128;

    const int tid = threadIdx.x;
    const int lane = tid & 63, w = tid >> 6;
    const int wm = (w & 1) * 64, wn = (w >> 1) * 64;
    const int lr = lane & 15, lq = lane >> 4;

    const int sr = lane >> 2;
    const int sc = (lane & 3) * 8;
    const int s0 = w * 2, s1 = w * 2 + 1;

    const ushort* Bp = Bt + (bBatch ? (long)(m0 / L_) * bBatch : 0);
    int br0 = n0 + s0 * 16 + sr; if (br0 >= Ndim) br0 = Ndim - 1;   // clamp (N<128)
    int br1 = n0 + s1 * 16 + sr; if (br1 >= Ndim) br1 = Ndim - 1;
    const ushort* a0p = A  + (size_t)(m0 + s0 * 16 + sr) * Kdim + sc;
    const ushort* a1p = A  + (size_t)(m0 + s1 * 16 + sr) * Kdim + sc;
    const ushort* b0p = Bp + (size_t)br0 * Kdim + sc;
    const ushort* b1p = Bp + (size_t)br1 * Kdim + sc;
    const int lo0 = s0 * 512 + lane * 8;
    const int lo1 = s1 * 512 + lane * 8;

    f32x4 acc[4][4];
#pragma unroll
    for (int a = 0; a < 4; ++a)
#pragma unroll
        for (int b = 0; b < 4; ++b) acc[a][b] = (f32x4){0.f, 0.f, 0.f, 0.f};

    glds16(a0p, &As[0][lo0]);
    glds16(a1p, &As[0][lo1]);
    glds16(b0p, &Bs[0][lo0]);
    glds16(b1p, &Bs[0][lo1]);
    if (32 < Kdim) {
        glds16(a0p + 32, &As[1][lo0]);
        glds16(a1p + 32, &As[1][lo1]);
        glds16(b0p + 32, &Bs[1][lo0]);
        glds16(b1p + 32, &Bs[1][lo1]);
    }

    int cur = 0;
    for (int k0 = 0; k0 < Kdim; k0 += 32) {
        if (k0 + 32 < Kdim) VMCNT(4); else VMCNT(0);
        BARRIER();
        if (k0 + 64 < Kdim) {
            const int nx = cur ? cur - 1 : 2;   // (cur+2)%3
            glds16(a0p + k0 + 64, &As[nx][lo0]);
            glds16(a1p + k0 + 64, &As[nx][lo1]);
            glds16(b0p + k0 + 64, &Bs[nx][lo0]);
            glds16(b1p + k0 + 64, &Bs[nx][lo1]);
        }
        bf16x8 af[4], bf[4];
#pragma unroll
        for (int a = 0; a < 4; ++a)
            af[a] = *(const bf16x8*)&As[cur][(wm + a * 16 + lr) * 32 + lq * 8];
#pragma unroll
        for (int b = 0; b < 4; ++b)
            bf[b] = *(const bf16x8*)&Bs[cur][(wn + b * 16 + lr) * 32 + lq * 8];
#pragma unroll
        for (int a = 0; a < 4; ++a)
#pragma unroll
            for (int b = 0; b < 4; ++b)
                acc[a][b] = __builtin_amdgcn_mfma_f32_16x16x32_bf16(af[a], bf[b], acc[a][b], 0, 0, 0);
        cur = (cur == 2) ? 0 : cur + 1;
    }

#pragma unroll
    for (int a = 0; a < 4; ++a) {
#pragma unroll
        for (int b = 0; b < 4; ++b) {
            const int col = n0 + wn + b * 16 + lr;
            if (col < Ndim) {
                const float bn = (EPI == 3) ? 0.f : bias[col];
#pragma unroll
                for (int r = 0; r < 4; ++r) {
                    const int row = m0 + wm + a * 16 + lq * 4 + r;
                    float v = acc[a][b][r];
                    if (EPI == 0) {
                        v = siluf(v + bn);
                        outB[(size_t)row * Ndim + col] = bfbits(v);
                    } else if (EPI == 2) {
                        v += bn + residF[(size_t)row * Ndim + col];
                        outB[(size_t)row * Ndim + col] = bfbits(v);
                    } else {
                        v *= bf2f(residB[(size_t)row * Ndim + col]);
                        outB[(size_t)row * Ndim + col] = bfbits(v);
                    }
                }
            }
        }
    }
}

// ---------------------------------------------------------------------------
// 256x128-tile GEMM, 8 waves (4M x 2N of 64x64), BK=32, 2-buffer ping-pong
// __syncthreads (proven r2/r4 sync pattern). 48 KB LDS, grid 256 (Wo).
// EPI 2: acc+bias[n]+residF (fp32) -> bf16
// ---------------------------------------------------------------------------
template <int EPI>
__global__ __launch_bounds__(512, 4) void gemm256(
    const ushort* __restrict__ A, const ushort* __restrict__ Bt,
    const float* __restrict__ bias, const float* __restrict__ residF,
    ushort* __restrict__ outB, int Ndim, int Kdim, int gridN)
{
    __shared__ ushort As[2][256 * 32];   // 2 x 16 KB
    __shared__ ushort Bs[2][128 * 32];   // 2 x 8 KB

    const int i = blockIdx.x;
    const int G = gridDim.x >> 3;
    const int gi = (gridDim.x & 7) ? i : ((i & 7) * G + (i >> 3));
    const int nt = gi % gridN, mt = gi / gridN;
    const int m0 = mt * 256, n0 = nt * 128;

    const int tid = threadIdx.x;
    const int lane = tid & 63, w = tid >> 6;       // 8 waves
    const int wm = (w & 3) * 64, wn = (w >> 2) * 64;
    const int lr = lane & 15, lq = lane >> 4;
    const int sr = lane >> 2, sc = (lane & 3) * 8;
    const int s0 = w * 2, s1 = w * 2 + 1;          // A segs (16 total)

    const ushort* a0p = A + (size_t)(m0 + s0 * 16 + sr) * Kdim + sc;
    const ushort* a1p = A + (size_t)(m0 + s1 * 16 + sr) * Kdim + sc;
    const ushort* b0p = Bt + (size_t)(n0 + w * 16 + sr) * Kdim + sc;  // B seg w (8 total)
    const int lo0 = s0 * 512 + lane * 8;
    const int lo1 = s1 * 512 + lane * 8;
    const int lob = w * 512 + lane * 8;

    f32x4 acc[4][4];
#pragma unroll
    for (int a = 0; a < 4; ++a)
#pragma unroll
        for (int b = 0; b < 4; ++b) acc[a][b] = (f32x4){0.f, 0.f, 0.f, 0.f};

    glds16(a0p, &As[0][lo0]);
    glds16(a1p, &As[0][lo1]);
    glds16(b0p, &Bs[0][lob]);

    int cur = 0;
    for (int k0 = 0; k0 < Kdim; k0 += 32) {
        __syncthreads();
        if (k0 + 32 < Kdim) {
            const int nx = cur ^ 1;
            glds16(a0p + k0 + 32, &As[nx][lo0]);
            glds16(a1p + k0 + 32, &As[nx][lo1]);
            glds16(b0p + k0 + 32, &Bs[nx][lob]);
        }
        bf16x8 af[4], bf[4];
#pragma unroll
        for (int a = 0; a < 4; ++a)
            af[a] = *(const bf16x8*)&As[cur][(wm + a * 16 + lr) * 32 + lq * 8];
#pragma unroll
        for (int b = 0; b < 4; ++b)
            bf[b] = *(const bf16x8*)&Bs[cur][(wn + b * 16 + lr) * 32 + lq * 8];
#pragma unroll
        for (int a = 0; a < 4; ++a)
#pragma unroll
            for (int b = 0; b < 4; ++b)
                acc[a][b] = __builtin_amdgcn_mfma_f32_16x16x32_bf16(af[a], bf[b], acc[a][b], 0, 0, 0);
        cur ^= 1;
    }

#pragma unroll
    for (int a = 0; a < 4; ++a) {
#pragma unroll
        for (int b = 0; b < 4; ++b) {
            const int col = n0 + wn + b * 16 + lr;
            const float bn = bias[col];
#pragma unroll
            for (int r = 0; r < 4; ++r) {
                const int row = m0 + wm + a * 16 + lq * 4 + r;
                float v = acc[a][b][r] + bn;
                if (EPI == 2) v += residF[(size_t)row * Ndim + col];
                else if (EPI == 0) v = siluf(v);
                outB[(size_t)row * Ndim + col] = bfbits(v);
            }
        }
    }
}

// ---------------------------------------------------------------------------
// pScore GEMM: tile 128(M) x 64(N), K=C=512, 4 waves each 32(M)x64(N).
// 3-buffer 2-deep prefetch, counted vmcnt(3). [round-4 verified]
// Fused epilogue: masked pScoreT[B,R,L] fp32 write + softmax over r -> bf16.
// ---------------------------------------------------------------------------
__global__ __launch_bounds__(256) void pscore_gemm(
    const ushort* __restrict__ x16, const ushort* __restrict__ Wpt,
    const float* __restrict__ bp, const int* __restrict__ mask,
    ushort* __restrict__ pAR16, float* __restrict__ pScoreT)
{
    __shared__ ushort As[3][128 * 32];   // 3 x 8 KB
    __shared__ ushort Bs[3][64 * 32];    // 3 x 4 KB

    const int i = blockIdx.x;
    const int G = gridDim.x >> 3;
    const int gi = (i & 7) * G + (i >> 3);   // grid = 128, %8==0
    const int m0 = gi * 128;

    const int tid = threadIdx.x;
    const int lane = tid & 63, w = tid >> 6;
    const int lr = lane & 15, lq = lane >> 4;
    const int sr = lane >> 2, sc = (lane & 3) * 8;
    const int s0 = w * 2, s1 = w * 2 + 1;

    const ushort* a0p = x16 + (size_t)(m0 + s0 * 16 + sr) * C_ + sc;
    const ushort* a1p = x16 + (size_t)(m0 + s1 * 16 + sr) * C_ + sc;
    const ushort* bwp = Wpt + (size_t)(w * 16 + sr) * C_ + sc;   // B seg w (rows 0..63)
    const int lo0 = s0 * 512 + lane * 8;
    const int lo1 = s1 * 512 + lane * 8;
    const int lob = w * 512 + lane * 8;

    f32x4 acc[2][4];
#pragma unroll
    for (int a = 0; a < 2; ++a)
#pragma unroll
        for (int b = 0; b < 4; ++b) acc[a][b] = (f32x4){0.f, 0.f, 0.f, 0.f};

    glds16(a0p, &As[0][lo0]);
    glds16(a1p, &As[0][lo1]);
    glds16(bwp, &Bs[0][lob]);
    glds16(a0p + 32, &As[1][lo0]);
    glds16(a1p + 32, &As[1][lo1]);
    glds16(bwp + 32, &Bs[1][lob]);

    int cur = 0;
    for (int k0 = 0; k0 < C_; k0 += 32) {
        if (k0 + 32 < C_) VMCNT(3); else VMCNT(0);
        BARRIER();
        if (k0 + 64 < C_) {
            const int nx = cur ? cur - 1 : 2;
            glds16(a0p + k0 + 64, &As[nx][lo0]);
            glds16(a1p + k0 + 64, &As[nx][lo1]);
            glds16(bwp + k0 + 64, &Bs[nx][lob]);
        }
        bf16x8 af[2], bf[4];
#pragma unroll
        for (int a = 0; a < 2; ++a)
            af[a] = *(const bf16x8*)&As[cur][(w * 32 + a * 16 + lr) * 32 + lq * 8];
#pragma unroll
        for (int b = 0; b < 4; ++b)
            bf[b] = *(const bf16x8*)&Bs[cur][(b * 16 + lr) * 32 + lq * 8];
#pragma unroll
        for (int a = 0; a < 2; ++a)
#pragma unroll
            for (int b = 0; b < 4; ++b)
                acc[a][b] = __builtin_amdgcn_mfma_f32_16x16x32_bf16(af[a], bf[b], acc[a][b], 0, 0, 0);
        cur = (cur == 2) ? 0 : cur + 1;
    }

    // epilogue: per row (16-lane group holds all 64 cols as 4x16)
#pragma unroll
    for (int a = 0; a < 2; ++a) {
#pragma unroll
        for (int r = 0; r < 4; ++r) {
            const int row = m0 + w * 32 + a * 16 + lq * 4 + r;
            const bool dead = (mask[row] == 0);
            const int bb = row >> 11, ll = row & (L_ - 1);
            float v[4];
            float mx = -3.4e38f;
#pragma unroll
            for (int b = 0; b < 4; ++b) {
                const int col = b * 16 + lr;
                float t = acc[a][b][r] + bp[col];
                if (dead) t = NEG_;
                v[b] = t;
                pScoreT[((size_t)bb * R_ + col) * L_ + ll] = t;
                mx = fmaxf(mx, t);
            }
#pragma unroll
            for (int o = 1; o < 16; o <<= 1) mx = fmaxf(mx, __shfl_xor(mx, o, 64));
            float e[4], s = 0.f;
#pragma unroll
            for (int b = 0; b < 4; ++b) { e[b] = __expf(v[b] - mx); s += e[b]; }
#pragma unroll
            for (int o = 1; o < 16; o <<= 1) s += __shfl_xor(s, o, 64);
            const float inv = 1.0f / s;
#pragma unroll
            for (int b = 0; b < 4; ++b)
                pAR16[(size_t)row * R_ + b * 16 + lr] = bfbits(e[b] * inv);
        }
    }
}

// ---------------------------------------------------------------------------
// Fused gate+expand: zg = silu(x@Wu + bu) * (pAR @ zsT[b]) over [M, H].
// 256x128 tile, 8 waves (4M x 2N), 18-tile stream (2 expand + 16 gate),
// 2-buffer ping-pong __syncthreads (proven pattern). 48 KB LDS, grid 512
// = 2 blocks/CU.
// ---------------------------------------------------------------------------
__global__ __launch_bounds__(512, 4) void fused_gate_z(
    const ushort* __restrict__ x16, const ushort* __restrict__ Wut,
    const float* __restrict__ bu,
    const ushort* __restrict__ pAR, const ushort* __restrict__ zsT,
    ushort* __restrict__ zg)
{
    __shared__ ushort As[2][256 * 32];   // 2 x 16 KB
    __shared__ ushort Bs[2][128 * 32];   // 2 x 8 KB

    const int i = blockIdx.x;
    const int G = gridDim.x >> 3;        // grid = 512, %8==0
    const int gi = (i & 7) * G + (i >> 3);
    constexpr int gridN = H_ / 128;      // 8
    const int nt = gi % gridN, mt = gi / gridN;
    const int m0 = mt * 256, n0 = nt * 128;

    const int tid = threadIdx.x;
    const int lane = tid & 63, w = tid >> 6;   // 8 waves
    const int wm = (w & 3) * 64, wn = (w >> 2) * 64;
    const int lr = lane & 15, lq = lane >> 4;
    const int sr = lane >> 2, sc = (lane & 3) * 8;
    const int s0 = w * 2, s1 = w * 2 + 1;

    const int bidx = m0 >> 11;           // batch (2048 % 256 == 0)
    const ushort* a0p = x16 + (size_t)(m0 + s0 * 16 + sr) * C_ + sc;
    const ushort* a1p = x16 + (size_t)(m0 + s1 * 16 + sr) * C_ + sc;
    const ushort* b0p = Wut + (size_t)(n0 + w * 16 + sr) * C_ + sc;
    const ushort* zb  = zsT + (size_t)bidx * H_ * R_;
    const ushort* c0p = pAR + (size_t)(m0 + s0 * 16 + sr) * R_ + sc;
    const ushort* c1p = pAR + (size_t)(m0 + s1 * 16 + sr) * R_ + sc;
    const ushort* d0p = zb + (size_t)(n0 + w * 16 + sr) * R_ + sc;
    const int lo0 = s0 * 512 + lane * 8;
    const int lo1 = s1 * 512 + lane * 8;
    const int lob = w * 512 + lane * 8;

    // tile t: t<2 -> expand (pAR/zsT, k=t*32); t>=2 -> gate (x16/Wut, k=(t-2)*32)
    auto stage = [&](int t, int bsel) {
        if (t < 2) {
            const int off = t * 32;
            glds16(c0p + off, &As[bsel][lo0]);
            glds16(c1p + off, &As[bsel][lo1]);
            glds16(d0p + off, &Bs[bsel][lob]);
        } else {
            const int off = (t - 2) * 32;
            glds16(a0p + off, &As[bsel][lo0]);
            glds16(a1p + off, &As[bsel][lo1]);
            glds16(b0p + off, &Bs[bsel][lob]);
        }
    };

    f32x4 acc[4][4];
#pragma unroll
    for (int a = 0; a < 4; ++a)
#pragma unroll
        for (int b = 0; b < 4; ++b) acc[a][b] = (f32x4){0.f, 0.f, 0.f, 0.f};

    uint pk[4][4][2];

    stage(0, 0);

    int cur = 0;
    for (int t = 0; t < 18; ++t) {
        __syncthreads();
        if (t + 1 < 18) stage(t + 1, cur ^ 1);
        bf16x8 af[4], bf[4];
#pragma unroll
        for (int a = 0; a < 4; ++a)
            af[a] = *(const bf16x8*)&As[cur][(wm + a * 16 + lr) * 32 + lq * 8];
#pragma unroll
        for (int b = 0; b < 4; ++b)
            bf[b] = *(const bf16x8*)&Bs[cur][(wn + b * 16 + lr) * 32 + lq * 8];
#pragma unroll
        for (int a = 0; a < 4; ++a)
#pragma unroll
            for (int b = 0; b < 4; ++b)
                acc[a][b] = __builtin_amdgcn_mfma_f32_16x16x32_bf16(af[a], bf[b], acc[a][b], 0, 0, 0);
        if (t == 1) {
            // expand done: pack to bf16 (matches old zg path precision), reset acc
#pragma unroll
            for (int a = 0; a < 4; ++a)
#pragma unroll
                for (int b = 0; b < 4; ++b) {
                    pk[a][b][0] = (uint)bfbits(acc[a][b][0]) | ((uint)bfbits(acc[a][b][1]) << 16);
                    pk[a][b][1] = (uint)bfbits(acc[a][b][2]) | ((uint)bfbits(acc[a][b][3]) << 16);
                    acc[a][b] = (f32x4){0.f, 0.f, 0.f, 0.f};
                }
        }
        cur ^= 1;
    }

    // epilogue: zg = silu(gate) * expand
#pragma unroll
    for (int a = 0; a < 4; ++a) {
#pragma unroll
        for (int b = 0; b < 4; ++b) {
            const int col = n0 + wn + b * 16 + lr;
            const float bn = bu[col];
#pragma unroll
            for (int r = 0; r < 4; ++r) {
                const int row = m0 + wm + a * 16 + lq * 4 + r;
                const ushort zu = (ushort)((r & 1) ? (pk[a][b][r >> 1] >> 16)
                                                   : (pk[a][b][r >> 1] & 0xffff));
                const float v = siluf(acc[a][b][r] + bn) * bf2f(zu);
                zg[(size_t)row * H_ + col] = bfbits(v);
            }
        }
    }
}

// x fp32 [B,L,C] -> x16 bf16 [M,C] (linear) + xT16 bf16 [B,C,L] (transposed).
__global__ __launch_bounds__(256) void x_prep(const float* __restrict__ x,
                                              ushort* __restrict__ x16,
                                              ushort* __restrict__ xT16)
{
    __shared__ float tile[32][33];
    const int tx = threadIdx.x & 31, ty = threadIdx.x >> 5;   // 32x8
    const int c0 = blockIdx.x * 32, l0 = blockIdx.y * 32;
#pragma unroll
    for (int i = 0; i < 32; i += 8) {
        const float v = x[(size_t)(l0 + ty + i) * C_ + c0 + tx];
        tile[ty + i][tx] = v;
        x16[(size_t)(l0 + ty + i) * C_ + c0 + tx] = bfbits(v);
    }
    __syncthreads();
    const int bb = l0 >> 11, ll0 = l0 & (L_ - 1);
#pragma unroll
    for (int i = 0; i < 32; i += 8)
        xT16[((size_t)bb * C_ + c0 + ty + i) * L_ + ll0 + tx] = bfbits(tile[tx][ty + i]);
}

// All weight transposes in ONE launch: Wu^T, Wo^T, Wp^T, Wq|Wk|Wv -> Wqkvt.
__global__ __launch_bounds__(256) void prep_w(
    const float* __restrict__ Wu, const float* __restrict__ Wo, const float* __restrict__ Wp,
    const float* __restrict__ Wq, const float* __restrict__ bq,
    const float* __restrict__ Wk, const float* __restrict__ bk,
    const float* __restrict__ Wv, const float* __restrict__ bv,
    ushort* __restrict__ Wut, ushort* __restrict__ Wot, ushort* __restrict__ Wpt,
    ushort* __restrict__ Wqkvt, float* __restrict__ bqkv)
{
    int id = blockIdx.x;
    const float* W; ushort* Wt; const float* bsrc = nullptr;
    int K, Nloc, n0, k0, nn0;
    if (id < 512) {                 // Wu [512,1024] -> Wut [1024,512]
        W = Wu; Wt = Wut; K = 512; Nloc = 1024;
        n0 = (id & 31) * 32; k0 = (id >> 5) * 32; nn0 = n0;
    } else if (id < 1024) {         // Wo [1024,512] -> Wot [512,1024]
        id -= 512; W = Wo; Wt = Wot; K = 1024; Nloc = 512;
        n0 = (id & 15) * 32; k0 = (id >> 4) * 32; nn0 = n0;
    } else if (id < 1056) {         // Wp [512,64] -> Wpt [64,512]
        id -= 1024; W = Wp; Wt = Wpt; K = 512; Nloc = 64;
        n0 = (id & 1) * 32; k0 = (id >> 1) * 32; nn0 = n0;
    } else {                        // qkv: 36 x 16 tiles over [1152,512]
        id -= 1056; K = 512; Wt = Wqkvt;
        n0 = (id % 36) * 32; k0 = (id / 36) * 32;
        if (n0 < 64)       { W = Wq; bsrc = bq; Nloc = 64;   nn0 = n0; }
        else if (n0 < 128) { W = Wk; bsrc = bk; Nloc = 64;   nn0 = n0 - 64; }
        else               { W = Wv; bsrc = bv; Nloc = 1024; nn0 = n0 - 128; }
    }
    __shared__ float tile[32][33];
    const int tx = threadIdx.x & 31, ty = threadIdx.x >> 5;
#pragma unroll
    for (int i = 0; i < 32; i += 8)
        tile[ty + i][tx] = W[(size_t)(k0 + ty + i) * Nloc + nn0 + tx];
    __syncthreads();
#pragma unroll
    for (int i = 0; i < 32; i += 8)
        Wt[(size_t)(n0 + ty + i) * K + k0 + tx] = bfbits(tile[tx][ty + i]);
    if (bsrc && k0 == 0 && threadIdx.x < 32) bqkv[n0 + threadIdx.x] = bsrc[nn0 + threadIdx.x];
}

// coalesced softmax over L on pScoreT[B,R,L] rows -> pALT[B,R,L] bf16
__global__ __launch_bounds__(256) void softmaxL2(const float* __restrict__ pScoreT,
                                                 ushort* __restrict__ pALT)
{
    const size_t br = blockIdx.x;
    const float* row = pScoreT + br * L_;
    ushort* orow = pALT + br * L_;
    const int t = threadIdx.x;
    __shared__ float red[256];

    float v[8];
    float mx = -3.4e38f;
#pragma unroll
    for (int j = 0; j < 8; ++j) { v[j] = row[t + j * 256]; mx = fmaxf(mx, v[j]); }
    red[t] = mx; __syncthreads();
    for (int s = 128; s > 0; s >>= 1) { if (t < s) red[t] = fmaxf(red[t], red[t + s]); __syncthreads(); }
    mx = red[0]; __syncthreads();

    float e[8], sum = 0.f;
#pragma unroll
    for (int j = 0; j < 8; ++j) { e[j] = __expf(v[j] - mx); sum += e[j]; }
    red[t] = sum; __syncthreads();
    for (int s = 128; s > 0; s >>= 1) { if (t < s) red[t] += red[t + s]; __syncthreads(); }
    const float inv = 1.0f / red[0];
#pragma unroll
    for (int j = 0; j < 8; ++j) orow[t + j * 256] = bfbits(e[j] * inv);
}

// px parts: K-split MFMA compress. parts[ks][b][r][c] over K-chunk ks of L.
// Tile 64x256, BK=32, 8 waves; grid dim3(C/256, B, 4). [round-4 verified]
__global__ __launch_bounds__(512) void compress_mfma(
    const ushort* __restrict__ pALT, const ushort* __restrict__ xT,
    float* __restrict__ parts)
{
    __shared__ ushort As[3][64 * 32];    // 3 x 4 KB
    __shared__ ushort Bs[3][256 * 32];   // 3 x 16 KB

    const int bidx = blockIdx.y;
    const int n0 = blockIdx.x * 256;
    const int ks = blockIdx.z;
    const int kbeg = ks * (L_ / 4), kend = kbeg + L_ / 4;
    const int tid = threadIdx.x;
    const int lane = tid & 63, w = tid >> 6;          // 8 waves
    const int lr = lane & 15, lq = lane >> 4;
    const int sr = lane >> 2, sc = (lane & 3) * 8;
    const int wm = (w & 1) * 32, wn = (w >> 1) * 64;

    const ushort* Ab = pALT + (size_t)bidx * R_ * L_;
    const ushort* Bb = xT + (size_t)bidx * C_ * L_;

    const int aseg = (w >= 4) ? (w - 4) : 0;
    const ushort* ap = Ab + (size_t)(aseg * 16 + sr) * L_ + sc;
    const int alo = aseg * 512 + lane * 8;
    const ushort* b0p = Bb + (size_t)(n0 + (w * 2) * 16 + sr) * L_ + sc;
    const ushort* b1p = Bb + (size_t)(n0 + (w * 2 + 1) * 16 + sr) * L_ + sc;
    const int blo0 = (w * 2) * 512 + lane * 8;
    const int blo1 = (w * 2 + 1) * 512 + lane * 8;

    auto stage = [&](int k0, int bsel) {
        if (w >= 4) glds16(ap + k0, &As[bsel][alo]);
        glds16(b0p + k0, &Bs[bsel][blo0]);
        glds16(b1p + k0, &Bs[bsel][blo1]);
    };

    f32x4 acc[2][4];
#pragma unroll
    for (int a = 0; a < 2; ++a)
#pragma unroll
        for (int b = 0; b < 4; ++b) acc[a][b] = (f32x4){0.f, 0.f, 0.f, 0.f};

    stage(kbeg, 0);
    stage(kbeg + 32, 1);

    int cur = 0;
    for (int k0 = kbeg; k0 < kend; k0 += 32) {
        if (k0 + 32 < kend) {
            if (w >= 4) VMCNT(3); else VMCNT(2);
        } else {
            VMCNT(0);
        }
        BARRIER();
        if (k0 + 64 < kend) stage(k0 + 64, cur ? cur - 1 : 2);
        bf16x8 af[2], bf[4];
#pragma unroll
        for (int a = 0; a < 2; ++a)
            af[a] = *(const bf16x8*)&As[cur][(wm + a * 16 + lr) * 32 + lq * 8];
#pragma unroll
        for (int b = 0; b < 4; ++b)
            bf[b] = *(const bf16x8*)&Bs[cur][(wn + b * 16 + lr) * 32 + lq * 8];
#pragma unroll
        for (int a = 0; a < 2; ++a)
#pragma unroll
            for (int b = 0; b < 4; ++b)
                acc[a][b] = __builtin_amdgcn_mfma_f32_16x16x32_bf16(af[a], bf[b], acc[a][b], 0, 0, 0);
        cur = (cur == 2) ? 0 : cur + 1;
    }
#pragma unroll
    for (int a = 0; a < 2; ++a)
#pragma unroll
        for (int b = 0; b < 4; ++b)
#pragma unroll
            for (int r = 0; r < 4; ++r) {
                const int row = wm + a * 16 + lq * 4 + r;
                const int col = n0 + wn + b * 16 + lr;
                parts[(((size_t)ks * B_ + bidx) * R_ + row) * C_ + col] = acc[a][b][r];
            }
}

// reduce 4 K-split parts -> px16 bf16
__global__ __launch_bounds__(256) void compress_reduce16(const float* __restrict__ parts,
                                                         ushort* __restrict__ px16)
{
    const size_t i = ((size_t)blockIdx.x * 256 + threadIdx.x) * 4;
    constexpr size_t S = (size_t)B_ * R_ * C_;
    const float4 a = *(const float4*)(parts + i);
    const float4 b = *(const float4*)(parts + i + S);
    const float4 c = *(const float4*)(parts + i + 2 * S);
    const float4 d = *(const float4*)(parts + i + 3 * S);
    ushort4 o;
    o.x = bfbits(a.x + b.x + c.x + d.x);
    o.y = bfbits(a.y + b.y + c.y + d.y);
    o.z = bfbits(a.z + b.z + c.z + d.z);
    o.w = bfbits(a.w + b.w + c.w + d.w);
    *(ushort4*)(px16 + i) = o;
}

// fused scores+softmax+z from bf16 qkv16 [B*R, 1152] (q|k|v concat)
__global__ __launch_bounds__(256) void attn_fused(
    const ushort* __restrict__ qkv, const float* __restrict__ preS,
    ushort* __restrict__ zsT)
{
    const int b = blockIdx.x >> 6, r = blockIdx.x & 63;
    const int t = threadIdx.x;
    __shared__ float al[R_];
    if (t < 64) {
        const ushort* qr = qkv + (size_t)(b * R_ + r) * NQKV_;
        const ushort* ks = qkv + (size_t)(b * R_ + t) * NQKV_ + 64;
        float acc = 0.f;
#pragma unroll
        for (int d = 0; d < DK_; d += 4) {
            const ushort4 qa = *(const ushort4*)(qr + d);
            const ushort4 ka = *(const ushort4*)(ks + d);
            acc += bf2f(qa.x) * bf2f(ka.x) + bf2f(qa.y) * bf2f(ka.y)
                 + bf2f(qa.z) * bf2f(ka.z) + bf2f(qa.w) * bf2f(ka.w);
        }
        acc = acc * 0.125f + preS[((size_t)b * R_ + r) * R_ + t];
        float mx = acc;
#pragma unroll
        for (int o = 32; o > 0; o >>= 1) mx = fmaxf(mx, __shfl_xor(mx, o, 64));
        float e = __expf(acc - mx);
        float sm = e;
#pragma unroll
        for (int o = 32; o > 0; o >>= 1) sm += __shfl_xor(sm, o, 64);
        al[t] = e / sm;
    }
    __syncthreads();
    float acc[4] = {};
    for (int s = 0; s < R_; ++s) {
        const float a = al[s];
        const ushort* vr = qkv + (size_t)(b * R_ + s) * NQKV_ + 128;
#pragma unroll
        for (int j = 0; j < 4; ++j) acc[j] += a * bf2f(vr[t + j * 256]);
    }
#pragma unroll
    for (int j = 0; j < 4; ++j) {
        const int h = t + j * 256;
        zsT[((size_t)b * H_ + h) * R_ + r] = bfbits(acc[j]);
    }
}

// Row layernorm of bf16 y -> fp32 out. Vectorized: ushort2 loads, float2 I/O.
__global__ __launch_bounds__(256) void layernorm(const ushort* __restrict__ y,
                                                 const float* __restrict__ gamma,
                                                 const float* __restrict__ beta,
                                                 float* __restrict__ out)
{
    const size_t m = blockIdx.x;
    const int t = threadIdx.x;
    const ushort2 p = *(const ushort2*)(y + m * C_ + 2 * t);
    float v0 = bf2f(p.x), v1 = bf2f(p.y);
    __shared__ float rs[256], rq[256];
    rs[t] = v0 + v1;
    rq[t] = v0 * v0 + v1 * v1;
    __syncthreads();
    for (int o = 128; o > 0; o >>= 1) {
        if (t < o) { rs[t] += rs[t + o]; rq[t] += rq[t + o]; }
        __syncthreads();
    }
    const float mu = rs[0] * (1.0f / C_);
    const float var = rq[0] * (1.0f / C_) - mu * mu;
    const float inv = rsqrtf(var + 1e-5f);
    const float2 g = *(const float2*)(gamma + 2 * t);
    const float2 be = *(const float2*)(beta + 2 * t);
    float2 o;
    o.x = (v0 - mu) * inv * g.x + be.x;
    o.y = (v1 - mu) * inv * g.y + be.y;
    *(float2*)(out + m * C_ + 2 * t) = o;
}

// ---- compact-path SIMT kernels (dead in practice, kept for safety) ----
template <typename AT, typename BT, typename RT, int ACT, int EPI>
__global__ __launch_bounds__(256) void gemm64(
    const AT* __restrict__ A, const BT* __restrict__ Bw,
    const float* __restrict__ bias, const int* __restrict__ mask,
    const RT* resid, float* __restrict__ outF, __hip_bfloat16* outB,
    int Ndim, int Kdim, long bBatchStride)
{
    __shared__ float As[16][68];
    __shared__ float Bs[16][64];
    const int tid = threadIdx.x;
    const int tx = tid & 15, ty = tid >> 4;
    const int n0 = blockIdx.x * 64, m0 = blockIdx.y * 64;
    const BT* Bp = Bw + (bBatchStride ? (long)(m0 / L_) * bBatchStride : 0);
    float acc[4][4] = {};
    for (int k0 = 0; k0 < Kdim; k0 += 16) {
#pragma unroll
        for (int s = 0; s < 4; ++s) {
            int idx = tid + s * 256;
            int am = idx >> 4, ak = idx & 15;
            As[ak][am] = toF(A[(size_t)(m0 + am) * Kdim + k0 + ak]);
        }
#pragma unroll
        for (int s = 0; s < 4; ++s) {
            int idx = tid + s * 256;
            int bk = idx >> 6, bn = idx & 63;
            Bs[bk][bn] = toF(Bp[(size_t)(k0 + bk) * Ndim + n0 + bn]);
        }
        __syncthreads();
#pragma unroll
        for (int kk = 0; kk < 16; ++kk) {
            float av[4], bv[4];
            *(float4*)av = *(const float4*)&As[kk][ty * 4];
            *(float4*)bv = *(const float4*)&Bs[kk][tx * 4];
#pragma unroll
            for (int i = 0; i < 4; ++i)
#pragma unroll
                for (int j = 0; j < 4; ++j) acc[i][j] += av[i] * bv[j];
        }
        __syncthreads();
    }
#pragma unroll
    for (int i = 0; i < 4; ++i) {
        int m = m0 + ty * 4 + i;
#pragma unroll
        for (int j = 0; j < 4; ++j) {
            int n = n0 + tx * 4 + j;
            float val = acc[i][j];
            if (EPI != 3) val += bias[n];
            if (ACT) val = siluf(val);
            if (EPI == 0) outB[(size_t)m * Ndim + n] = __float2bfloat16(val);
            else if (EPI == 1) { if (mask[m] == 0) val = NEG_; outF[(size_t)m * Ndim + n] = val; }
            else if (EPI == 2) { val += toF(resid[(size_t)m * Ndim + n]); outB[(size_t)m * Ndim + n] = __float2bfloat16(val); }
            else { val *= toF(resid[(size_t)m * Ndim + n]); outB[(size_t)m * Ndim + n] = __float2bfloat16(val); }
        }
    }
}

template <int OUT>
__global__ __launch_bounds__(64) void softmaxR(const float* __restrict__ pScore,
                                               float* __restrict__ outF,
                                               ushort* __restrict__ outU)
{
    const size_t m = blockIdx.x;
    const int t = threadIdx.x;
    float v = pScore[m * R_ + t];
    float mx = v;
#pragma unroll
    for (int o = 32; o > 0; o >>= 1) mx = fmaxf(mx, __shfl_xor(mx, o, 64));
    float e = __expf(v - mx);
    float s = e;
#pragma unroll
    for (int o = 32; o > 0; o >>= 1) s += __shfl_xor(s, o, 64);
    if (OUT == 0) outF[m * R_ + t] = e / s;
    else          outU[m * R_ + t] = bfbits(e / s);
}

__global__ __launch_bounds__(256) void softmaxL(const float* __restrict__ pScore,
                                                float* __restrict__ pAlpha)
{
    const int b = blockIdx.x >> 6, r = blockIdx.x & 63;
    const int t = threadIdx.x;
    const float* base = pScore + (size_t)b * L_ * R_ + r;
    float* out = pAlpha + (size_t)b * L_ * R_ + r;
    __shared__ float red[256];
    float mx = -3.4e38f;
    for (int l = t; l < L_; l += 256) mx = fmaxf(mx, base[(size_t)l * R_]);
    red[t] = mx; __syncthreads();
    for (int s = 128; s > 0; s >>= 1) { if (t < s) red[t] = fmaxf(red[t], red[t + s]); __syncthreads(); }
    mx = red[0]; __syncthreads();
    float sum = 0.f;
    for (int l = t; l < L_; l += 256) {
        float e = __expf(base[(size_t)l * R_] - mx);
        out[(size_t)l * R_] = e; sum += e;
    }
    red[t] = sum; __syncthreads();
    for (int s = 128; s > 0; s >>= 1) { if (t < s) red[t] += red[t + s]; __syncthreads(); }
    const float inv = 1.0f / red[0];
    for (int l = t; l < L_; l += 256) out[(size_t)l * R_] *= inv;
}

__global__ __launch_bounds__(256) void compress_part(
    const float* __restrict__ pAlpha, const float* __restrict__ x,
    float* __restrict__ parts)
{
    __shared__ float As[16][64];
    __shared__ float Bs[16][64];
    const int tid = threadIdx.x;
    const int tx = tid & 15, ty = tid >> 4;
    const int n0 = blockIdx.x * 64;
    const int ks = blockIdx.y;
    const int b  = blockIdx.z;
    const float* pa = pAlpha + (size_t)b * L_ * R_;
    const float* xb = x + (size_t)b * L_ * C_;
    float acc[4][4] = {};
    const int kbeg = ks * (L_ / 4), kend = kbeg + L_ / 4;
    for (int k0 = kbeg; k0 < kend; k0 += 16) {
#pragma unroll
        for (int s = 0; s < 4; ++s) {
            int idx = tid + s * 256;
            int kk = idx >> 6, m = idx & 63;
            As[kk][m] = pa[(size_t)(k0 + kk) * R_ + m];
        }
#pragma unroll
        for (int s = 0; s < 4; ++s) {
            int idx = tid + s * 256;
            int kk = idx >> 6, n = idx & 63;
            Bs[kk][n] = xb[(size_t)(k0 + kk) * C_ + n0 + n];
        }
        __syncthreads();
#pragma unroll
        for (int kk = 0; kk < 16; ++kk) {
            float av[4], bv[4];
            *(float4*)av = *(const float4*)&As[kk][ty * 4];
            *(float4*)bv = *(const float4*)&Bs[kk][tx * 4];
#pragma unroll
            for (int i = 0; i < 4; ++i)
#pragma unroll
                for (int j = 0; j < 4; ++j) acc[i][j] += av[i] * bv[j];
        }
        __syncthreads();
    }
#pragma unroll
    for (int i = 0; i < 4; ++i)
#pragma unroll
        for (int j = 0; j < 4; ++j)
            parts[((((size_t)ks * B_ + b) * R_) + ty * 4 + i) * C_ + n0 + tx * 4 + j] = acc[i][j];
}

__global__ __launch_bounds__(256) void compress_reduce(const float* __restrict__ parts,
                                                       float* __restrict__ px)
{
    const size_t i = (size_t)blockIdx.x * 256 + threadIdx.x;
    constexpr size_t S = (size_t)B_ * R_ * C_;
    px[i] = parts[i] + parts[i + S] + parts[i + 2 * S] + parts[i + 3 * S];
}

__global__ __launch_bounds__(256) void qkv_gemm(
    const float* __restrict__ px,
    const float* __restrict__ Wq, const float* __restrict__ bq,
    const float* __restrict__ Wk, const float* __restrict__ bk,
    const float* __restrict__ Wv, const float* __restrict__ bv,
    float* __restrict__ q, float* __restrict__ k, float* __restrict__ v)
{
    __shared__ float As[16][68];
    __shared__ float Bs[16][64];
    const int tid = threadIdx.x;
    const int tx = tid & 15, ty = tid >> 4;
    const int bx = blockIdx.x;
    const int m0 = blockIdx.y * 64;
    const float* W; const float* bias; float* dst; int Nloc, ncol0;
    if (bx == 0)      { W = Wq; bias = bq; dst = q; Nloc = 64;   ncol0 = 0; }
    else if (bx == 1) { W = Wk; bias = bk; dst = k; Nloc = 64;   ncol0 = 0; }
    else              { W = Wv; bias = bv; dst = v; Nloc = H_;   ncol0 = (bx - 2) * 64; }

    float acc[4][4] = {};
    for (int k0 = 0; k0 < C_; k0 += 16) {
#pragma unroll
        for (int s = 0; s < 4; ++s) {
            int idx = tid + s * 256;
            int am = idx >> 4, ak = idx & 15;
            As[ak][am] = px[(size_t)(m0 + am) * C_ + k0 + ak];
        }
#pragma unroll
        for (int s = 0; s < 4; ++s) {
            int idx = tid + s * 256;
            int kk = idx >> 6, bn = idx & 63;
            Bs[kk][bn] = W[(size_t)(k0 + kk) * Nloc + ncol0 + bn];
        }
        __syncthreads();
#pragma unroll
        for (int kk = 0; kk < 16; ++kk) {
            float av[4], bv4[4];
            *(float4*)av = *(const float4*)&As[kk][ty * 4];
            *(float4*)bv4 = *(const float4*)&Bs[kk][tx * 4];
#pragma unroll
            for (int i = 0; i < 4; ++i)
#pragma unroll
                for (int j = 0; j < 4; ++j) acc[i][j] += av[i] * bv4[j];
        }
        __syncthreads();
    }
#pragma unroll
    for (int i = 0; i < 4; ++i) {
        int m = m0 + ty * 4 + i;
#pragma unroll
        for (int j = 0; j < 4; ++j) {
            int n = ncol0 + tx * 4 + j;
            dst[(size_t)m * Nloc + n] = siluf(acc[i][j] + bias[n]);
        }
    }
}

template <int MODE>
__global__ __launch_bounds__(256) void attn_z(const float* __restrict__ alpha,
                                              const float* __restrict__ v,
                                              float* __restrict__ zsF,
                                              ushort* __restrict__ zsT)
{
    const int b = blockIdx.x >> 6, r = blockIdx.x & 63;
    const int t = threadIdx.x;
    __shared__ float al[R_];
    if (t < R_) al[t] = alpha[((size_t)b * R_ + r) * R_ + t];
    __syncthreads();
    float acc[4] = {};
    for (int s = 0; s < R_; ++s) {
        float a = al[s];
        const float* vr = v + ((size_t)b * R_ + s) * H_;
#pragma unroll
        for (int j = 0; j < 4; ++j) acc[j] += a * vr[t + j * 256];
    }
#pragma unroll
    for (int j = 0; j < 4; ++j) {
        const int h = t + j * 256;
        if (MODE == 0) zsF[((size_t)b * R_ + r) * H_ + h] = acc[j];
        else           zsT[((size_t)b * H_ + h) * R_ + r] = bfbits(acc[j]);
    }
}

__global__ __launch_bounds__(64) void attn_scores(
    const float* __restrict__ q, const float* __restrict__ k,
    const float* __restrict__ preS, float* __restrict__ alpha)
{
    const int b = blockIdx.x >> 6, r = blockIdx.x & 63;
    const int s = threadIdx.x;
    const float* qr = q + ((size_t)b * R_ + r) * DK_;
    const float* ks = k + ((size_t)b * R_ + s) * DK_;
    float acc = 0.f;
#pragma unroll
    for (int d = 0; d < DK_; ++d) acc += qr[d] * ks[d];
    acc = acc * 0.125f + preS[((size_t)b * R_ + r) * R_ + s];
    float mx = acc;
#pragma unroll
    for (int o = 32; o > 0; o >>= 1) mx = fmaxf(mx, __shfl_xor(mx, o, 64));
    float e = __expf(acc - mx);
    float sm = e;
#pragma unroll
    for (int o = 32; o > 0; o >>= 1) sm += __shfl_xor(sm, o, 64);
    alpha[((size_t)b * R_ + r) * R_ + s] = e / sm;
}

extern "C" void kernel_launch(void* const* d_in, const int* in_sizes, int n_in,
                              void* d_out, int out_size, void* d_ws, size_t ws_size,
                              hipStream_t stream)
{
    using bf16 = __hip_bfloat16;
    const float* x      = (const float*)d_in[0];
    const int*  maskPAD = (const int*)d_in[1];
    const float* preS   = (const float*)d_in[2];
    const float* Wp     = (const float*)d_in[3];
    const float* bp     = (const float*)d_in[4];
    const float* Wq     = (const float*)d_in[5];
    const float* bq     = (const float*)d_in[6];
    const float* Wk     = (const float*)d_in[7];
    const float* bk     = (const float*)d_in[8];
    const float* Wv     = (const float*)d_in[9];
    const float* bv     = (const float*)d_in[10];
    const float* Wu     = (const float*)d_in[11];
    const float* bu     = (const float*)d_in[12];
    const float* Wo     = (const float*)d_in[13];
    const float* bo     = (const float*)d_in[14];
    const float* gamma  = (const float*)d_in[15];
    const float* beta   = (const float*)d_in[16];
    float* out          = (float*)d_out;

    char* ws = (char*)d_ws;
    const bool bigWS = ws_size >= (size_t)52 * 1024 * 1024;  // proven taken

    if (bigWS) {
        // layout: zg 33.5 MB | pool 18.2 MB | Wut | Wot | Wpt
        bf16* zg = (bf16*)ws;                                   // M*H bf16 (written by fused_gate_z)
        float* parts = (float*)ws;                              // 4 MB K-split parts (dead before zg)
        char* pool = ws + (size_t)M_ * H_ * 2;
        float* pScoreT = (float*)pool;                          // B*R*L f32 (4 MB)
        ushort* pALT   = (ushort*)(pScoreT + (size_t)B_ * R_ * L_);  // B*R*L bf16 (2 MB)
        ushort* pAR16  = pALT + (size_t)B_ * R_ * L_;           // M*R bf16 (2 MB)
        ushort* px16   = pAR16 + (size_t)M_ * R_;               // B*R*C bf16 (0.5 MB)
        ushort* qkv16  = px16 + (size_t)B_ * R_ * C_;           // B*R*1152 bf16 (1.19 MB)
        ushort* zsT16  = qkv16 + (size_t)B_ * R_ * NQKV_;       // B*H*R bf16 (1 MB)
        ushort* Wqkvt  = zsT16 + (size_t)B_ * H_ * R_;          // [1152, C] bf16 (1.13 MB)
        float*  bqkv   = (float*)(Wqkvt + (size_t)NQKV_ * C_);  // 4.6 KB
        bf16*  y       = (bf16*)pool;                           // pre-LN y (16.8 MB), pool dead
        ushort* Wut    = (ushort*)(pool + 18221568);            // [H, C] bf16
        ushort* Wot    = Wut + (size_t)C_ * H_;                 // [C, H] bf16
        ushort* Wpt    = Wot + (size_t)C_ * H_;                 // [R, C] bf16
        ushort* x16    = (ushort*)d_out;                        // [M, C] bf16 (dead before LN)
        ushort* xT16   = x16 + (size_t)M_ * C_;                 // [B, C, L] bf16 (in d_out)

        // 1) x -> bf16 (linear + per-batch transpose), weights -> bf16^T
        x_prep<<<dim3(C_ / 32, M_ / 32), 256, 0, stream>>>(x, x16, xT16);
        prep_w<<<1632, 256, 0, stream>>>(Wu, Wo, Wp, Wq, bq, Wk, bk, Wv, bv,
                                         Wut, Wot, Wpt, Wqkvt, bqkv);
        // 2) pScore GEMM (128x64 tile) + fused softmax over r
        pscore_gemm<<<M_ / 128, 256, 0, stream>>>(x16, Wpt, bp, maskPAD, pAR16, pScoreT);
        softmaxL2<<<B_ * R_, 256, 0, stream>>>(pScoreT, pALT);
        // 3) px = pALT @ x (MFMA, K-split x4) -> parts -> bf16
        compress_mfma<<<dim3(C_ / 256, B_, 4), 512, 0, stream>>>(pALT, xT16, parts);
        compress_reduce16<<<(B_ * R_ * C_) / 1024, 256, 0, stream>>>(parts, px16);
        // 4) q|k|v = silu(px @ Wqkv + b) in one MFMA GEMM (128^2, grid 36)
        mfma_gemm5<0><<<(NQKV_ / 128) * ((B_ * R_) / 128), 256, 0, stream>>>(
            px16, Wqkvt, bqkv, nullptr, nullptr, nullptr, qkv16, nullptr, nullptr,
            NQKV_, C_, NQKV_ / 128, 0);
        attn_fused<<<B_ * R_, 256, 0, stream>>>(qkv16, preS, zsT16);
        // 5) zg = silu(x@Wu+bu) * (pAR @ zsT)   [256x128 tile, 8 waves, 2-buf]
        fused_gate_z<<<(H_ / 128) * (M_ / 256), 512, 0, stream>>>(
            x16, Wut, bu, pAR16, zsT16, (ushort*)zg);
        // 6) y = x + zg @ Wo + bo   [256x128 tile, 8 waves, 2-buf, grid 256]
        gemm256<2><<<(C_ / 128) * (M_ / 256), 512, 0, stream>>>(
            (ushort*)zg, Wot, bo, x, (ushort*)y, C_, H_, C_ / 128);
        layernorm<<<M_, 256, 0, stream>>>((const ushort*)y, gamma, beta, out);
    } else {
        // ---- Compact plan (~23.4 MiB), SIMT per-batch (dead in practice) ----
        float* pScore = (float*)ws;
        float* pAL   = pScore + (size_t)M_ * R_;
        float* pAR   = pAL    + (size_t)M_ * R_;
        float* px    = pAR    + (size_t)M_ * R_;
        float* q     = px     + (size_t)B_ * R_ * C_;
        float* kk    = q      + (size_t)B_ * R_ * DK_;
        float* vv    = kk     + (size_t)B_ * R_ * DK_;
        float* alpha = vv     + (size_t)B_ * R_ * H_;
        float* zs    = alpha  + (size_t)B_ * R_ * R_;
        bf16* gate_b = (bf16*)(zs + (size_t)B_ * R_ * H_);
        bf16* y_b    = (bf16*)((char*)gate_b + (size_t)L_ * H_ * 2);

        gemm64<float, float, float, 0, 1><<<dim3(R_ / 64, M_ / 64), 256, 0, stream>>>(
            x, Wp, bp, maskPAD, (const float*)nullptr, pScore, nullptr, R_, C_, 0);
        softmaxL<<<B_ * R_, 256, 0, stream>>>(pScore, pAL);
        softmaxR<0><<<M_, 64, 0, stream>>>(pScore, pAR, nullptr);
        compress_part<<<dim3(C_ / 64, 4, B_), 256, 0, stream>>>(pAL, x, pScore);
        compress_reduce<<<(B_ * R_ * C_) / 256, 256, 0, stream>>>(pScore, px);
        qkv_gemm<<<dim3(2 + H_ / 64, (B_ * R_) / 64), 256, 0, stream>>>(
            px, Wq, bq, Wk, bk, Wv, bv, q, kk, vv);
        attn_scores<<<B_ * R_, 64, 0, stream>>>(q, kk, preS, alpha);
        attn_z<0><<<B_ * R_, 256, 0, stream>>>(alpha, vv, zs, nullptr);

        for (int b = 0; b < B_; ++b) {
            const float* xb = x + (size_t)b * L_ * C_;
            gemm64<float, float, float, 1, 0><<<dim3(H_ / 64, L_ / 64), 256, 0, stream>>>(
                xb, Wu, bu, nullptr, (const float*)nullptr, nullptr, gate_b, H_, C_, 0);
            gemm64<float, float, bf16, 0, 3><<<dim3(H_ / 64, L_ / 64), 256, 0, stream>>>(
                pAR + (size_t)b * L_ * R_, zs + (size_t)b * R_ * H_,
                nullptr, nullptr, gate_b, nullptr, gate_b, H_, R_, 0);
            gemm64<bf16, float, float, 0, 2><<<dim3(C_ / 64, L_ / 64), 256, 0, stream>>>(
                gate_b, Wo, bo, nullptr, xb, nullptr, y_b, C_, H_, 0);
            layernorm<<<L_, 256, 0, stream>>>((const ushort*)y_b, gamma, beta, out + (size_t)b * L_ * C_);
        }
    }
}

// Round 7
// 273.680 us; speedup vs baseline: 1.0435x; 1.0435x over previous
//
#include <hip/hip_runtime.h>
#include <hip/hip_bf16.h>

// Problem constants
constexpr int B_ = 8;
constexpr int L_ = 2048;
constexpr int C_ = 512;
constexpr int R_ = 64;
constexpr int DK_ = 64;
constexpr int H_ = 1024;   // 2*C
constexpr int M_ = B_ * L_;  // 16384
constexpr int NQKV_ = 1152;  // 64 + 64 + 1024 (q|k|v concat)
constexpr float NEG_ = -32767.0f;

__device__ __forceinline__ float toF(float x) { return x; }
__device__ __forceinline__ float toF(__hip_bfloat16 x) { return __bfloat162float(x); }
__device__ __forceinline__ float siluf(float v) { return v / (1.0f + __expf(-v)); }
__device__ __forceinline__ ushort bfbits(float f) {
    __hip_bfloat16 h = __float2bfloat16(f);
    union { __hip_bfloat16 h; ushort u; } cv; cv.h = h; return cv.u;
}
__device__ __forceinline__ float bf2f(ushort u) {
    union { uint u; float f; } cv; cv.u = (uint)u << 16; return cv.f;
}

typedef __attribute__((ext_vector_type(8))) short bf16x8;   // 8 bf16 (4 VGPRs)
typedef __attribute__((ext_vector_type(4))) float f32x4;    // 4 fp32 acc

#define GLOBAL_AS __attribute__((address_space(1)))
#define LDS_AS    __attribute__((address_space(3)))
__device__ __forceinline__ void glds16(const ushort* g, ushort* l) {
    __builtin_amdgcn_global_load_lds((const GLOBAL_AS void*)g, (LDS_AS void*)l, 16, 0, 0);
}

// counted-vmcnt + raw barrier helpers (T4): loads stay in flight across barriers.
#define VMCNT(n) asm volatile("s_waitcnt vmcnt(" #n ")" ::: "memory")
#define BARRIER() do { __builtin_amdgcn_s_barrier(); asm volatile("" ::: "memory"); } while (0)

// ---------------------------------------------------------------------------
// MFMA bf16 GEMM, 128x128 tile, BK=32, 4 waves (2x2 of 64x64).
// 3-buffer, 2-deep prefetch, counted vmcnt(4). Used ONLY for qkv (grid 36).
// EPI 0: silu(acc+bias[n]) -> bf16   [round-4 verified]
// ---------------------------------------------------------------------------
template <int EPI>
__global__ __launch_bounds__(256) void mfma_gemm5(
    const ushort* __restrict__ A, const ushort* __restrict__ Bt,
    const float* __restrict__ bias,
    const float* __restrict__ residF, const ushort* __restrict__ residB,
    const int* __restrict__ mask,
    ushort* __restrict__ outB, float* __restrict__ outF, float* __restrict__ outF2,
    int Ndim, int Kdim, int gridN, long bBatch)
{
    __shared__ ushort As[3][128 * 32];   // 3 x 8 KB
    __shared__ ushort Bs[3][128 * 32];

    const int i = blockIdx.x;
    const int G = gridDim.x >> 3;        // blocks per XCD
    const int gi = (gridDim.x & 7) ? i : ((i & 7) * G + (i >> 3));
    const int nt = gi % gridN, mt = gi / gridN;
    const int m0 = mt * 128, n0 = nt * 128;

    const int tid = threadIdx.x;
    const int lane = tid & 63, w = tid >> 6;
    const int wm = (w & 1) * 64, wn = (w >> 1) * 64;
    const int lr = lane & 15, lq = lane >> 4;

    const int sr = lane >> 2;
    const int sc = (lane & 3) * 8;
    const int s0 = w * 2, s1 = w * 2 + 1;

    const ushort* Bp = Bt + (bBatch ? (long)(m0 / L_) * bBatch : 0);
    int br0 = n0 + s0 * 16 + sr; if (br0 >= Ndim) br0 = Ndim - 1;   // clamp (N<128)
    int br1 = n0 + s1 * 16 + sr; if (br1 >= Ndim) br1 = Ndim - 1;
    const ushort* a0p = A  + (size_t)(m0 + s0 * 16 + sr) * Kdim + sc;
    const ushort* a1p = A  + (size_t)(m0 + s1 * 16 + sr) * Kdim + sc;
    const ushort* b0p = Bp + (size_t)br0 * Kdim + sc;
    const ushort* b1p = Bp + (size_t)br1 * Kdim + sc;
    const int lo0 = s0 * 512 + lane * 8;
    const int lo1 = s1 * 512 + lane * 8;

    f32x4 acc[4][4];
#pragma unroll
    for (int a = 0; a < 4; ++a)
#pragma unroll
        for (int b = 0; b < 4; ++b) acc[a][b] = (f32x4){0.f, 0.f, 0.f, 0.f};

    glds16(a0p, &As[0][lo0]);
    glds16(a1p, &As[0][lo1]);
    glds16(b0p, &Bs[0][lo0]);
    glds16(b1p, &Bs[0][lo1]);
    if (32 < Kdim) {
        glds16(a0p + 32, &As[1][lo0]);
        glds16(a1p + 32, &As[1][lo1]);
        glds16(b0p + 32, &Bs[1][lo0]);
        glds16(b1p + 32, &Bs[1][lo1]);
    }

    int cur = 0;
    for (int k0 = 0; k0 < Kdim; k0 += 32) {
        if (k0 + 32 < Kdim) VMCNT(4); else VMCNT(0);
        BARRIER();
        if (k0 + 64 < Kdim) {
            const int nx = cur ? cur - 1 : 2;   // (cur+2)%3
            glds16(a0p + k0 + 64, &As[nx][lo0]);
            glds16(a1p + k0 + 64, &As[nx][lo1]);
            glds16(b0p + k0 + 64, &Bs[nx][lo0]);
            glds16(b1p + k0 + 64, &Bs[nx][lo1]);
        }
        bf16x8 af[4], bf[4];
#pragma unroll
        for (int a = 0; a < 4; ++a)
            af[a] = *(const bf16x8*)&As[cur][(wm + a * 16 + lr) * 32 + lq * 8];
#pragma unroll
        for (int b = 0; b < 4; ++b)
            bf[b] = *(const bf16x8*)&Bs[cur][(wn + b * 16 + lr) * 32 + lq * 8];
#pragma unroll
        for (int a = 0; a < 4; ++a)
#pragma unroll
            for (int b = 0; b < 4; ++b)
                acc[a][b] = __builtin_amdgcn_mfma_f32_16x16x32_bf16(af[a], bf[b], acc[a][b], 0, 0, 0);
        cur = (cur == 2) ? 0 : cur + 1;
    }

#pragma unroll
    for (int a = 0; a < 4; ++a) {
#pragma unroll
        for (int b = 0; b < 4; ++b) {
            const int col = n0 + wn + b * 16 + lr;
            if (col < Ndim) {
                const float bn = (EPI == 3) ? 0.f : bias[col];
#pragma unroll
                for (int r = 0; r < 4; ++r) {
                    const int row = m0 + wm + a * 16 + lq * 4 + r;
                    float v = acc[a][b][r];
                    if (EPI == 0) {
                        v = siluf(v + bn);
                        outB[(size_t)row * Ndim + col] = bfbits(v);
                    } else if (EPI == 2) {
                        v += bn + residF[(size_t)row * Ndim + col];
                        outB[(size_t)row * Ndim + col] = bfbits(v);
                    } else {
                        v *= bf2f(residB[(size_t)row * Ndim + col]);
                        outB[(size_t)row * Ndim + col] = bfbits(v);
                    }
                }
            }
        }
    }
}

// ---------------------------------------------------------------------------
// 256x128-tile GEMM, 8 waves (4M x 2N of 64x64), BK=32, 2-buffer ping-pong
// __syncthreads. 48 KB LDS, grid 256 (Wo).
// NOTE: __launch_bounds__(512) with NO min-occupancy arg — round 6 showed
// (512,4) caps VGPR at 64 (arg behaves as blocks/CU) -> full spill,
// FETCH/WRITE tripled. Free allocation gives ~120 VGPR = 2 blocks/CU.
// EPI 2: acc+bias[n]+residF (fp32) -> bf16
// ---------------------------------------------------------------------------
template <int EPI>
__global__ __launch_bounds__(512) void gemm256(
    const ushort* __restrict__ A, const ushort* __restrict__ Bt,
    const float* __restrict__ bias, const float* __restrict__ residF,
    ushort* __restrict__ outB, int Ndim, int Kdim, int gridN)
{
    __shared__ ushort As[2][256 * 32];   // 2 x 16 KB
    __shared__ ushort Bs[2][128 * 32];   // 2 x 8 KB

    const int i = blockIdx.x;
    const int G = gridDim.x >> 3;
    const int gi = (gridDim.x & 7) ? i : ((i & 7) * G + (i >> 3));
    const int nt = gi % gridN, mt = gi / gridN;
    const int m0 = mt * 256, n0 = nt * 128;

    const int tid = threadIdx.x;
    const int lane = tid & 63, w = tid >> 6;       // 8 waves
    const int wm = (w & 3) * 64, wn = (w >> 2) * 64;
    const int lr = lane & 15, lq = lane >> 4;
    const int sr = lane >> 2, sc = (lane & 3) * 8;
    const int s0 = w * 2, s1 = w * 2 + 1;          // A segs (16 total)

    const ushort* a0p = A + (size_t)(m0 + s0 * 16 + sr) * Kdim + sc;
    const ushort* a1p = A + (size_t)(m0 + s1 * 16 + sr) * Kdim + sc;
    const ushort* b0p = Bt + (size_t)(n0 + w * 16 + sr) * Kdim + sc;  // B seg w (8 total)
    const int lo0 = s0 * 512 + lane * 8;
    const int lo1 = s1 * 512 + lane * 8;
    const int lob = w * 512 + lane * 8;

    f32x4 acc[4][4];
#pragma unroll
    for (int a = 0; a < 4; ++a)
#pragma unroll
        for (int b = 0; b < 4; ++b) acc[a][b] = (f32x4){0.f, 0.f, 0.f, 0.f};

    glds16(a0p, &As[0][lo0]);
    glds16(a1p, &As[0][lo1]);
    glds16(b0p, &Bs[0][lob]);

    int cur = 0;
    for (int k0 = 0; k0 < Kdim; k0 += 32) {
        __syncthreads();
        if (k0 + 32 < Kdim) {
            const int nx = cur ^ 1;
            glds16(a0p + k0 + 32, &As[nx][lo0]);
            glds16(a1p + k0 + 32, &As[nx][lo1]);
            glds16(b0p + k0 + 32, &Bs[nx][lob]);
        }
        bf16x8 af[4], bf[4];
#pragma unroll
        for (int a = 0; a < 4; ++a)
            af[a] = *(const bf16x8*)&As[cur][(wm + a * 16 + lr) * 32 + lq * 8];
#pragma unroll
        for (int b = 0; b < 4; ++b)
            bf[b] = *(const bf16x8*)&Bs[cur][(wn + b * 16 + lr) * 32 + lq * 8];
#pragma unroll
        for (int a = 0; a < 4; ++a)
#pragma unroll
            for (int b = 0; b < 4; ++b)
                acc[a][b] = __builtin_amdgcn_mfma_f32_16x16x32_bf16(af[a], bf[b], acc[a][b], 0, 0, 0);
        cur ^= 1;
    }

#pragma unroll
    for (int a = 0; a < 4; ++a) {
#pragma unroll
        for (int b = 0; b < 4; ++b) {
            const int col = n0 + wn + b * 16 + lr;
            const float bn = bias[col];
#pragma unroll
            for (int r = 0; r < 4; ++r) {
                const int row = m0 + wm + a * 16 + lq * 4 + r;
                float v = acc[a][b][r] + bn;
                if (EPI == 2) v += residF[(size_t)row * Ndim + col];
                else if (EPI == 0) v = siluf(v);
                outB[(size_t)row * Ndim + col] = bfbits(v);
            }
        }
    }
}

// ---------------------------------------------------------------------------
// pScore GEMM: tile 128(M) x 64(N), K=C=512, 4 waves each 32(M)x64(N).
// 3-buffer 2-deep prefetch, counted vmcnt(3). [round-4 verified]
// Fused epilogue: masked pScoreT[B,R,L] fp32 write + softmax over r -> bf16.
// ---------------------------------------------------------------------------
__global__ __launch_bounds__(256) void pscore_gemm(
    const ushort* __restrict__ x16, const ushort* __restrict__ Wpt,
    const float* __restrict__ bp, const int* __restrict__ mask,
    ushort* __restrict__ pAR16, float* __restrict__ pScoreT)
{
    __shared__ ushort As[3][128 * 32];   // 3 x 8 KB
    __shared__ ushort Bs[3][64 * 32];    // 3 x 4 KB

    const int i = blockIdx.x;
    const int G = gridDim.x >> 3;
    const int gi = (i & 7) * G + (i >> 3);   // grid = 128, %8==0
    const int m0 = gi * 128;

    const int tid = threadIdx.x;
    const int lane = tid & 63, w = tid >> 6;
    const int lr = lane & 15, lq = lane >> 4;
    const int sr = lane >> 2, sc = (lane & 3) * 8;
    const int s0 = w * 2, s1 = w * 2 + 1;

    const ushort* a0p = x16 + (size_t)(m0 + s0 * 16 + sr) * C_ + sc;
    const ushort* a1p = x16 + (size_t)(m0 + s1 * 16 + sr) * C_ + sc;
    const ushort* bwp = Wpt + (size_t)(w * 16 + sr) * C_ + sc;   // B seg w (rows 0..63)
    const int lo0 = s0 * 512 + lane * 8;
    const int lo1 = s1 * 512 + lane * 8;
    const int lob = w * 512 + lane * 8;

    f32x4 acc[2][4];
#pragma unroll
    for (int a = 0; a < 2; ++a)
#pragma unroll
        for (int b = 0; b < 4; ++b) acc[a][b] = (f32x4){0.f, 0.f, 0.f, 0.f};

    glds16(a0p, &As[0][lo0]);
    glds16(a1p, &As[0][lo1]);
    glds16(bwp, &Bs[0][lob]);
    glds16(a0p + 32, &As[1][lo0]);
    glds16(a1p + 32, &As[1][lo1]);
    glds16(bwp + 32, &Bs[1][lob]);

    int cur = 0;
    for (int k0 = 0; k0 < C_; k0 += 32) {
        if (k0 + 32 < C_) VMCNT(3); else VMCNT(0);
        BARRIER();
        if (k0 + 64 < C_) {
            const int nx = cur ? cur - 1 : 2;
            glds16(a0p + k0 + 64, &As[nx][lo0]);
            glds16(a1p + k0 + 64, &As[nx][lo1]);
            glds16(bwp + k0 + 64, &Bs[nx][lob]);
        }
        bf16x8 af[2], bf[4];
#pragma unroll
        for (int a = 0; a < 2; ++a)
            af[a] = *(const bf16x8*)&As[cur][(w * 32 + a * 16 + lr) * 32 + lq * 8];
#pragma unroll
        for (int b = 0; b < 4; ++b)
            bf[b] = *(const bf16x8*)&Bs[cur][(b * 16 + lr) * 32 + lq * 8];
#pragma unroll
        for (int a = 0; a < 2; ++a)
#pragma unroll
            for (int b = 0; b < 4; ++b)
                acc[a][b] = __builtin_amdgcn_mfma_f32_16x16x32_bf16(af[a], bf[b], acc[a][b], 0, 0, 0);
        cur = (cur == 2) ? 0 : cur + 1;
    }

    // epilogue: per row (16-lane group holds all 64 cols as 4x16)
#pragma unroll
    for (int a = 0; a < 2; ++a) {
#pragma unroll
        for (int r = 0; r < 4; ++r) {
            const int row = m0 + w * 32 + a * 16 + lq * 4 + r;
            const bool dead = (mask[row] == 0);
            const int bb = row >> 11, ll = row & (L_ - 1);
            float v[4];
            float mx = -3.4e38f;
#pragma unroll
            for (int b = 0; b < 4; ++b) {
                const int col = b * 16 + lr;
                float t = acc[a][b][r] + bp[col];
                if (dead) t = NEG_;
                v[b] = t;
                pScoreT[((size_t)bb * R_ + col) * L_ + ll] = t;
                mx = fmaxf(mx, t);
            }
#pragma unroll
            for (int o = 1; o < 16; o <<= 1) mx = fmaxf(mx, __shfl_xor(mx, o, 64));
            float e[4], s = 0.f;
#pragma unroll
            for (int b = 0; b < 4; ++b) { e[b] = __expf(v[b] - mx); s += e[b]; }
#pragma unroll
            for (int o = 1; o < 16; o <<= 1) s += __shfl_xor(s, o, 64);
            const float inv = 1.0f / s;
#pragma unroll
            for (int b = 0; b < 4; ++b)
                pAR16[(size_t)row * R_ + b * 16 + lr] = bfbits(e[b] * inv);
        }
    }
}

// ---------------------------------------------------------------------------
// Fused gate+expand: zg = silu(x@Wu + bu) * (pAR @ zsT[b]) over [M, H].
// 256x128 tile, 8 waves (4M x 2N), 18-tile stream (2 expand + 16 gate),
// 2-buffer ping-pong __syncthreads. 48 KB LDS, grid 512.
// __launch_bounds__(512) free VGPR (see gemm256 note — (512,4) spilled).
// ---------------------------------------------------------------------------
__global__ __launch_bounds__(512) void fused_gate_z(
    const ushort* __restrict__ x16, const ushort* __restrict__ Wut,
    const float* __restrict__ bu,
    const ushort* __restrict__ pAR, const ushort* __restrict__ zsT,
    ushort* __restrict__ zg)
{
    __shared__ ushort As[2][256 * 32];   // 2 x 16 KB
    __shared__ ushort Bs[2][128 * 32];   // 2 x 8 KB

    const int i = blockIdx.x;
    const int G = gridDim.x >> 3;        // grid = 512, %8==0
    const int gi = (i & 7) * G + (i >> 3);
    constexpr int gridN = H_ / 128;      // 8
    const int nt = gi % gridN, mt = gi / gridN;
    const int m0 = mt * 256, n0 = nt * 128;

    const int tid = threadIdx.x;
    const int lane = tid & 63, w = tid >> 6;   // 8 waves
    const int wm = (w & 3) * 64, wn = (w >> 2) * 64;
    const int lr = lane & 15, lq = lane >> 4;
    const int sr = lane >> 2, sc = (lane & 3) * 8;
    const int s0 = w * 2, s1 = w * 2 + 1;

    const int bidx = m0 >> 11;           // batch (2048 % 256 == 0)
    const ushort* a0p = x16 + (size_t)(m0 + s0 * 16 + sr) * C_ + sc;
    const ushort* a1p = x16 + (size_t)(m0 + s1 * 16 + sr) * C_ + sc;
    const ushort* b0p = Wut + (size_t)(n0 + w * 16 + sr) * C_ + sc;
    const ushort* zb  = zsT + (size_t)bidx * H_ * R_;
    const ushort* c0p = pAR + (size_t)(m0 + s0 * 16 + sr) * R_ + sc;
    const ushort* c1p = pAR + (size_t)(m0 + s1 * 16 + sr) * R_ + sc;
    const ushort* d0p = zb + (size_t)(n0 + w * 16 + sr) * R_ + sc;
    const int lo0 = s0 * 512 + lane * 8;
    const int lo1 = s1 * 512 + lane * 8;
    const int lob = w * 512 + lane * 8;

    // tile t: t<2 -> expand (pAR/zsT, k=t*32); t>=2 -> gate (x16/Wut, k=(t-2)*32)
    auto stage = [&](int t, int bsel) {
        if (t < 2) {
            const int off = t * 32;
            glds16(c0p + off, &As[bsel][lo0]);
            glds16(c1p + off, &As[bsel][lo1]);
            glds16(d0p + off, &Bs[bsel][lob]);
        } else {
            const int off = (t - 2) * 32;
            glds16(a0p + off, &As[bsel][lo0]);
            glds16(a1p + off, &As[bsel][lo1]);
            glds16(b0p + off, &Bs[bsel][lob]);
        }
    };

    f32x4 acc[4][4];
#pragma unroll
    for (int a = 0; a < 4; ++a)
#pragma unroll
        for (int b = 0; b < 4; ++b) acc[a][b] = (f32x4){0.f, 0.f, 0.f, 0.f};

    uint pk[4][4][2];

    stage(0, 0);

    int cur = 0;
    for (int t = 0; t < 18; ++t) {
        __syncthreads();
        if (t + 1 < 18) stage(t + 1, cur ^ 1);
        bf16x8 af[4], bf[4];
#pragma unroll
        for (int a = 0; a < 4; ++a)
            af[a] = *(const bf16x8*)&As[cur][(wm + a * 16 + lr) * 32 + lq * 8];
#pragma unroll
        for (int b = 0; b < 4; ++b)
            bf[b] = *(const bf16x8*)&Bs[cur][(wn + b * 16 + lr) * 32 + lq * 8];
#pragma unroll
        for (int a = 0; a < 4; ++a)
#pragma unroll
            for (int b = 0; b < 4; ++b)
                acc[a][b] = __builtin_amdgcn_mfma_f32_16x16x32_bf16(af[a], bf[b], acc[a][b], 0, 0, 0);
        if (t == 1) {
            // expand done: pack to bf16 (matches old zg path precision), reset acc
#pragma unroll
            for (int a = 0; a < 4; ++a)
#pragma unroll
                for (int b = 0; b < 4; ++b) {
                    pk[a][b][0] = (uint)bfbits(acc[a][b][0]) | ((uint)bfbits(acc[a][b][1]) << 16);
                    pk[a][b][1] = (uint)bfbits(acc[a][b][2]) | ((uint)bfbits(acc[a][b][3]) << 16);
                    acc[a][b] = (f32x4){0.f, 0.f, 0.f, 0.f};
                }
        }
        cur ^= 1;
    }

    // epilogue: zg = silu(gate) * expand
#pragma unroll
    for (int a = 0; a < 4; ++a) {
#pragma unroll
        for (int b = 0; b < 4; ++b) {
            const int col = n0 + wn + b * 16 + lr;
            const float bn = bu[col];
#pragma unroll
            for (int r = 0; r < 4; ++r) {
                const int row = m0 + wm + a * 16 + lq * 4 + r;
                const ushort zu = (ushort)((r & 1) ? (pk[a][b][r >> 1] >> 16)
                                                   : (pk[a][b][r >> 1] & 0xffff));
                const float v = siluf(acc[a][b][r] + bn) * bf2f(zu);
                zg[(size_t)row * H_ + col] = bfbits(v);
            }
        }
    }
}

// x fp32 [B,L,C] -> x16 bf16 [M,C] (linear) + xT16 bf16 [B,C,L] (transposed).
__global__ __launch_bounds__(256) void x_prep(const float* __restrict__ x,
                                              ushort* __restrict__ x16,
                                              ushort* __restrict__ xT16)
{
    __shared__ float tile[32][33];
    const int tx = threadIdx.x & 31, ty = threadIdx.x >> 5;   // 32x8
    const int c0 = blockIdx.x * 32, l0 = blockIdx.y * 32;
#pragma unroll
    for (int i = 0; i < 32; i += 8) {
        const float v = x[(size_t)(l0 + ty + i) * C_ + c0 + tx];
        tile[ty + i][tx] = v;
        x16[(size_t)(l0 + ty + i) * C_ + c0 + tx] = bfbits(v);
    }
    __syncthreads();
    const int bb = l0 >> 11, ll0 = l0 & (L_ - 1);
#pragma unroll
    for (int i = 0; i < 32; i += 8)
        xT16[((size_t)bb * C_ + c0 + ty + i) * L_ + ll0 + tx] = bfbits(tile[tx][ty + i]);
}

// All weight transposes in ONE launch: Wu^T, Wo^T, Wp^T, Wq|Wk|Wv -> Wqkvt.
__global__ __launch_bounds__(256) void prep_w(
    const float* __restrict__ Wu, const float* __restrict__ Wo, const float* __restrict__ Wp,
    const float* __restrict__ Wq, const float* __restrict__ bq,
    const float* __restrict__ Wk, const float* __restrict__ bk,
    const float* __restrict__ Wv, const float* __restrict__ bv,
    ushort* __restrict__ Wut, ushort* __restrict__ Wot, ushort* __restrict__ Wpt,
    ushort* __restrict__ Wqkvt, float* __restrict__ bqkv)
{
    int id = blockIdx.x;
    const float* W; ushort* Wt; const float* bsrc = nullptr;
    int K, Nloc, n0, k0, nn0;
    if (id < 512) {                 // Wu [512,1024] -> Wut [1024,512]
        W = Wu; Wt = Wut; K = 512; Nloc = 1024;
        n0 = (id & 31) * 32; k0 = (id >> 5) * 32; nn0 = n0;
    } else if (id < 1024) {         // Wo [1024,512] -> Wot [512,1024]
        id -= 512; W = Wo; Wt = Wot; K = 1024; Nloc = 512;
        n0 = (id & 15) * 32; k0 = (id >> 4) * 32; nn0 = n0;
    } else if (id < 1056) {         // Wp [512,64] -> Wpt [64,512]
        id -= 1024; W = Wp; Wt = Wpt; K = 512; Nloc = 64;
        n0 = (id & 1) * 32; k0 = (id >> 1) * 32; nn0 = n0;
    } else {                        // qkv: 36 x 16 tiles over [1152,512]
        id -= 1056; K = 512; Wt = Wqkvt;
        n0 = (id % 36) * 32; k0 = (id / 36) * 32;
        if (n0 < 64)       { W = Wq; bsrc = bq; Nloc = 64;   nn0 = n0; }
        else if (n0 < 128) { W = Wk; bsrc = bk; Nloc = 64;   nn0 = n0 - 64; }
        else               { W = Wv; bsrc = bv; Nloc = 1024; nn0 = n0 - 128; }
    }
    __shared__ float tile[32][33];
    const int tx = threadIdx.x & 31, ty = threadIdx.x >> 5;
#pragma unroll
    for (int i = 0; i < 32; i += 8)
        tile[ty + i][tx] = W[(size_t)(k0 + ty + i) * Nloc + nn0 + tx];
    __syncthreads();
#pragma unroll
    for (int i = 0; i < 32; i += 8)
        Wt[(size_t)(n0 + ty + i) * K + k0 + tx] = bfbits(tile[tx][ty + i]);
    if (bsrc && k0 == 0 && threadIdx.x < 32) bqkv[n0 + threadIdx.x] = bsrc[nn0 + threadIdx.x];
}

// coalesced softmax over L on pScoreT[B,R,L] rows -> pALT[B,R,L] bf16
__global__ __launch_bounds__(256) void softmaxL2(const float* __restrict__ pScoreT,
                                                 ushort* __restrict__ pALT)
{
    const size_t br = blockIdx.x;
    const float* row = pScoreT + br * L_;
    ushort* orow = pALT + br * L_;
    const int t = threadIdx.x;
    __shared__ float red[256];

    float v[8];
    float mx = -3.4e38f;
#pragma unroll
    for (int j = 0; j < 8; ++j) { v[j] = row[t + j * 256]; mx = fmaxf(mx, v[j]); }
    red[t] = mx; __syncthreads();
    for (int s = 128; s > 0; s >>= 1) { if (t < s) red[t] = fmaxf(red[t], red[t + s]); __syncthreads(); }
    mx = red[0]; __syncthreads();

    float e[8], sum = 0.f;
#pragma unroll
    for (int j = 0; j < 8; ++j) { e[j] = __expf(v[j] - mx); sum += e[j]; }
    red[t] = sum; __syncthreads();
    for (int s = 128; s > 0; s >>= 1) { if (t < s) red[t] += red[t + s]; __syncthreads(); }
    const float inv = 1.0f / red[0];
#pragma unroll
    for (int j = 0; j < 8; ++j) orow[t + j * 256] = bfbits(e[j] * inv);
}

// px parts: K-split MFMA compress. parts[ks][b][r][c] over K-chunk ks of L.
// Tile 64x256, BK=32, 8 waves; grid dim3(C/256, B, 4). [round-4 verified]
__global__ __launch_bounds__(512) void compress_mfma(
    const ushort* __restrict__ pALT, const ushort* __restrict__ xT,
    float* __restrict__ parts)
{
    __shared__ ushort As[3][64 * 32];    // 3 x 4 KB
    __shared__ ushort Bs[3][256 * 32];   // 3 x 16 KB

    const int bidx = blockIdx.y;
    const int n0 = blockIdx.x * 256;
    const int ks = blockIdx.z;
    const int kbeg = ks * (L_ / 4), kend = kbeg + L_ / 4;
    const int tid = threadIdx.x;
    const int lane = tid & 63, w = tid >> 6;          // 8 waves
    const int lr = lane & 15, lq = lane >> 4;
    const int sr = lane >> 2, sc = (lane & 3) * 8;
    const int wm = (w & 1) * 32, wn = (w >> 1) * 64;

    const ushort* Ab = pALT + (size_t)bidx * R_ * L_;
    const ushort* Bb = xT + (size_t)bidx * C_ * L_;

    const int aseg = (w >= 4) ? (w - 4) : 0;
    const ushort* ap = Ab + (size_t)(aseg * 16 + sr) * L_ + sc;
    const int alo = aseg * 512 + lane * 8;
    const ushort* b0p = Bb + (size_t)(n0 + (w * 2) * 16 + sr) * L_ + sc;
    const ushort* b1p = Bb + (size_t)(n0 + (w * 2 + 1) * 16 + sr) * L_ + sc;
    const int blo0 = (w * 2) * 512 + lane * 8;
    const int blo1 = (w * 2 + 1) * 512 + lane * 8;

    auto stage = [&](int k0, int bsel) {
        if (w >= 4) glds16(ap + k0, &As[bsel][alo]);
        glds16(b0p + k0, &Bs[bsel][blo0]);
        glds16(b1p + k0, &Bs[bsel][blo1]);
    };

    f32x4 acc[2][4];
#pragma unroll
    for (int a = 0; a < 2; ++a)
#pragma unroll
        for (int b = 0; b < 4; ++b) acc[a][b] = (f32x4){0.f, 0.f, 0.f, 0.f};

    stage(kbeg, 0);
    stage(kbeg + 32, 1);

    int cur = 0;
    for (int k0 = kbeg; k0 < kend; k0 += 32) {
        if (k0 + 32 < kend) {
            if (w >= 4) VMCNT(3); else VMCNT(2);
        } else {
            VMCNT(0);
        }
        BARRIER();
        if (k0 + 64 < kend) stage(k0 + 64, cur ? cur - 1 : 2);
        bf16x8 af[2], bf[4];
#pragma unroll
        for (int a = 0; a < 2; ++a)
            af[a] = *(const bf16x8*)&As[cur][(wm + a * 16 + lr) * 32 + lq * 8];
#pragma unroll
        for (int b = 0; b < 4; ++b)
            bf[b] = *(const bf16x8*)&Bs[cur][(wn + b * 16 + lr) * 32 + lq * 8];
#pragma unroll
        for (int a = 0; a < 2; ++a)
#pragma unroll
            for (int b = 0; b < 4; ++b)
                acc[a][b] = __builtin_amdgcn_mfma_f32_16x16x32_bf16(af[a], bf[b], acc[a][b], 0, 0, 0);
        cur = (cur == 2) ? 0 : cur + 1;
    }
#pragma unroll
    for (int a = 0; a < 2; ++a)
#pragma unroll
        for (int b = 0; b < 4; ++b)
#pragma unroll
            for (int r = 0; r < 4; ++r) {
                const int row = wm + a * 16 + lq * 4 + r;
                const int col = n0 + wn + b * 16 + lr;
                parts[(((size_t)ks * B_ + bidx) * R_ + row) * C_ + col] = acc[a][b][r];
            }
}

// reduce 4 K-split parts -> px16 bf16
__global__ __launch_bounds__(256) void compress_reduce16(const float* __restrict__ parts,
                                                         ushort* __restrict__ px16)
{
    const size_t i = ((size_t)blockIdx.x * 256 + threadIdx.x) * 4;
    constexpr size_t S = (size_t)B_ * R_ * C_;
    const float4 a = *(const float4*)(parts + i);
    const float4 b = *(const float4*)(parts + i + S);
    const float4 c = *(const float4*)(parts + i + 2 * S);
    const float4 d = *(const float4*)(parts + i + 3 * S);
    ushort4 o;
    o.x = bfbits(a.x + b.x + c.x + d.x);
    o.y = bfbits(a.y + b.y + c.y + d.y);
    o.z = bfbits(a.z + b.z + c.z + d.z);
    o.w = bfbits(a.w + b.w + c.w + d.w);
    *(ushort4*)(px16 + i) = o;
}

// fused scores+softmax+z from bf16 qkv16 [B*R, 1152] (q|k|v concat)
__global__ __launch_bounds__(256) void attn_fused(
    const ushort* __restrict__ qkv, const float* __restrict__ preS,
    ushort* __restrict__ zsT)
{
    const int b = blockIdx.x >> 6, r = blockIdx.x & 63;
    const int t = threadIdx.x;
    __shared__ float al[R_];
    if (t < 64) {
        const ushort* qr = qkv + (size_t)(b * R_ + r) * NQKV_;
        const ushort* ks = qkv + (size_t)(b * R_ + t) * NQKV_ + 64;
        float acc = 0.f;
#pragma unroll
        for (int d = 0; d < DK_; d += 4) {
            const ushort4 qa = *(const ushort4*)(qr + d);
            const ushort4 ka = *(const ushort4*)(ks + d);
            acc += bf2f(qa.x) * bf2f(ka.x) + bf2f(qa.y) * bf2f(ka.y)
                 + bf2f(qa.z) * bf2f(ka.z) + bf2f(qa.w) * bf2f(ka.w);
        }
        acc = acc * 0.125f + preS[((size_t)b * R_ + r) * R_ + t];
        float mx = acc;
#pragma unroll
        for (int o = 32; o > 0; o >>= 1) mx = fmaxf(mx, __shfl_xor(mx, o, 64));
        float e = __expf(acc - mx);
        float sm = e;
#pragma unroll
        for (int o = 32; o > 0; o >>= 1) sm += __shfl_xor(sm, o, 64);
        al[t] = e / sm;
    }
    __syncthreads();
    float acc[4] = {};
    for (int s = 0; s < R_; ++s) {
        const float a = al[s];
        const ushort* vr = qkv + (size_t)(b * R_ + s) * NQKV_ + 128;
#pragma unroll
        for (int j = 0; j < 4; ++j) acc[j] += a * bf2f(vr[t + j * 256]);
    }
#pragma unroll
    for (int j = 0; j < 4; ++j) {
        const int h = t + j * 256;
        zsT[((size_t)b * H_ + h) * R_ + r] = bfbits(acc[j]);
    }
}

// Row layernorm of bf16 y -> fp32 out. Vectorized: ushort2 loads, float2 I/O.
__global__ __launch_bounds__(256) void layernorm(const ushort* __restrict__ y,
                                                 const float* __restrict__ gamma,
                                                 const float* __restrict__ beta,
                                                 float* __restrict__ out)
{
    const size_t m = blockIdx.x;
    const int t = threadIdx.x;
    const ushort2 p = *(const ushort2*)(y + m * C_ + 2 * t);
    float v0 = bf2f(p.x), v1 = bf2f(p.y);
    __shared__ float rs[256], rq[256];
    rs[t] = v0 + v1;
    rq[t] = v0 * v0 + v1 * v1;
    __syncthreads();
    for (int o = 128; o > 0; o >>= 1) {
        if (t < o) { rs[t] += rs[t + o]; rq[t] += rq[t + o]; }
        __syncthreads();
    }
    const float mu = rs[0] * (1.0f / C_);
    const float var = rq[0] * (1.0f / C_) - mu * mu;
    const float inv = rsqrtf(var + 1e-5f);
    const float2 g = *(const float2*)(gamma + 2 * t);
    const float2 be = *(const float2*)(beta + 2 * t);
    float2 o;
    o.x = (v0 - mu) * inv * g.x + be.x;
    o.y = (v1 - mu) * inv * g.y + be.y;
    *(float2*)(out + m * C_ + 2 * t) = o;
}

// ---- compact-path SIMT kernels (dead in practice, kept for safety) ----
template <typename AT, typename BT, typename RT, int ACT, int EPI>
__global__ __launch_bounds__(256) void gemm64(
    const AT* __restrict__ A, const BT* __restrict__ Bw,
    const float* __restrict__ bias, const int* __restrict__ mask,
    const RT* resid, float* __restrict__ outF, __hip_bfloat16* outB,
    int Ndim, int Kdim, long bBatchStride)
{
    __shared__ float As[16][68];
    __shared__ float Bs[16][64];
    const int tid = threadIdx.x;
    const int tx = tid & 15, ty = tid >> 4;
    const int n0 = blockIdx.x * 64, m0 = blockIdx.y * 64;
    const BT* Bp = Bw + (bBatchStride ? (long)(m0 / L_) * bBatchStride : 0);
    float acc[4][4] = {};
    for (int k0 = 0; k0 < Kdim; k0 += 16) {
#pragma unroll
        for (int s = 0; s < 4; ++s) {
            int idx = tid + s * 256;
            int am = idx >> 4, ak = idx & 15;
            As[ak][am] = toF(A[(size_t)(m0 + am) * Kdim + k0 + ak]);
        }
#pragma unroll
        for (int s = 0; s < 4; ++s) {
            int idx = tid + s * 256;
            int bk = idx >> 6, bn = idx & 63;
            Bs[bk][bn] = toF(Bp[(size_t)(k0 + bk) * Ndim + n0 + bn]);
        }
        __syncthreads();
#pragma unroll
        for (int kk = 0; kk < 16; ++kk) {
            float av[4], bv[4];
            *(float4*)av = *(const float4*)&As[kk][ty * 4];
            *(float4*)bv = *(const float4*)&Bs[kk][tx * 4];
#pragma unroll
            for (int i = 0; i < 4; ++i)
#pragma unroll
                for (int j = 0; j < 4; ++j) acc[i][j] += av[i] * bv[j];
        }
        __syncthreads();
    }
#pragma unroll
    for (int i = 0; i < 4; ++i) {
        int m = m0 + ty * 4 + i;
#pragma unroll
        for (int j = 0; j < 4; ++j) {
            int n = n0 + tx * 4 + j;
            float val = acc[i][j];
            if (EPI != 3) val += bias[n];
            if (ACT) val = siluf(val);
            if (EPI == 0) outB[(size_t)m * Ndim + n] = __float2bfloat16(val);
            else if (EPI == 1) { if (mask[m] == 0) val = NEG_; outF[(size_t)m * Ndim + n] = val; }
            else if (EPI == 2) { val += toF(resid[(size_t)m * Ndim + n]); outB[(size_t)m * Ndim + n] = __float2bfloat16(val); }
            else { val *= toF(resid[(size_t)m * Ndim + n]); outB[(size_t)m * Ndim + n] = __float2bfloat16(val); }
        }
    }
}

template <int OUT>
__global__ __launch_bounds__(64) void softmaxR(const float* __restrict__ pScore,
                                               float* __restrict__ outF,
                                               ushort* __restrict__ outU)
{
    const size_t m = blockIdx.x;
    const int t = threadIdx.x;
    float v = pScore[m * R_ + t];
    float mx = v;
#pragma unroll
    for (int o = 32; o > 0; o >>= 1) mx = fmaxf(mx, __shfl_xor(mx, o, 64));
    float e = __expf(v - mx);
    float s = e;
#pragma unroll
    for (int o = 32; o > 0; o >>= 1) s += __shfl_xor(s, o, 64);
    if (OUT == 0) outF[m * R_ + t] = e / s;
    else          outU[m * R_ + t] = bfbits(e / s);
}

__global__ __launch_bounds__(256) void softmaxL(const float* __restrict__ pScore,
                                                float* __restrict__ pAlpha)
{
    const int b = blockIdx.x >> 6, r = blockIdx.x & 63;
    const int t = threadIdx.x;
    const float* base = pScore + (size_t)b * L_ * R_ + r;
    float* out = pAlpha + (size_t)b * L_ * R_ + r;
    __shared__ float red[256];
    float mx = -3.4e38f;
    for (int l = t; l < L_; l += 256) mx = fmaxf(mx, base[(size_t)l * R_]);
    red[t] = mx; __syncthreads();
    for (int s = 128; s > 0; s >>= 1) { if (t < s) red[t] = fmaxf(red[t], red[t + s]); __syncthreads(); }
    mx = red[0]; __syncthreads();
    float sum = 0.f;
    for (int l = t; l < L_; l += 256) {
        float e = __expf(base[(size_t)l * R_] - mx);
        out[(size_t)l * R_] = e; sum += e;
    }
    red[t] = sum; __syncthreads();
    for (int s = 128; s > 0; s >>= 1) { if (t < s) red[t] += red[t + s]; __syncthreads(); }
    const float inv = 1.0f / red[0];
    for (int l = t; l < L_; l += 256) out[(size_t)l * R_] *= inv;
}

__global__ __launch_bounds__(256) void compress_part(
    const float* __restrict__ pAlpha, const float* __restrict__ x,
    float* __restrict__ parts)
{
    __shared__ float As[16][64];
    __shared__ float Bs[16][64];
    const int tid = threadIdx.x;
    const int tx = tid & 15, ty = tid >> 4;
    const int n0 = blockIdx.x * 64;
    const int ks = blockIdx.y;
    const int b  = blockIdx.z;
    const float* pa = pAlpha + (size_t)b * L_ * R_;
    const float* xb = x + (size_t)b * L_ * C_;
    float acc[4][4] = {};
    const int kbeg = ks * (L_ / 4), kend = kbeg + L_ / 4;
    for (int k0 = kbeg; k0 < kend; k0 += 16) {
#pragma unroll
        for (int s = 0; s < 4; ++s) {
            int idx = tid + s * 256;
            int kk = idx >> 6, m = idx & 63;
            As[kk][m] = pa[(size_t)(k0 + kk) * R_ + m];
        }
#pragma unroll
        for (int s = 0; s < 4; ++s) {
            int idx = tid + s * 256;
            int kk = idx >> 6, n = idx & 63;
            Bs[kk][n] = xb[(size_t)(k0 + kk) * C_ + n0 + n];
        }
        __syncthreads();
#pragma unroll
        for (int kk = 0; kk < 16; ++kk) {
            float av[4], bv[4];
            *(float4*)av = *(const float4*)&As[kk][ty * 4];
            *(float4*)bv = *(const float4*)&Bs[kk][tx * 4];
#pragma unroll
            for (int i = 0; i < 4; ++i)
#pragma unroll
                for (int j = 0; j < 4; ++j) acc[i][j] += av[i] * bv[j];
        }
        __syncthreads();
    }
#pragma unroll
    for (int i = 0; i < 4; ++i)
#pragma unroll
        for (int j = 0; j < 4; ++j)
            parts[((((size_t)ks * B_ + b) * R_) + ty * 4 + i) * C_ + n0 + tx * 4 + j] = acc[i][j];
}

__global__ __launch_bounds__(256) void compress_reduce(const float* __restrict__ parts,
                                                       float* __restrict__ px)
{
    const size_t i = (size_t)blockIdx.x * 256 + threadIdx.x;
    constexpr size_t S = (size_t)B_ * R_ * C_;
    px[i] = parts[i] + parts[i + S] + parts[i + 2 * S] + parts[i + 3 * S];
}

__global__ __launch_bounds__(256) void qkv_gemm(
    const float* __restrict__ px,
    const float* __restrict__ Wq, const float* __restrict__ bq,
    const float* __restrict__ Wk, const float* __restrict__ bk,
    const float* __restrict__ Wv, const float* __restrict__ bv,
    float* __restrict__ q, float* __restrict__ k, float* __restrict__ v)
{
    __shared__ float As[16][68];
    __shared__ float Bs[16][64];
    const int tid = threadIdx.x;
    const int tx = tid & 15, ty = tid >> 4;
    const int bx = blockIdx.x;
    const int m0 = blockIdx.y * 64;
    const float* W; const float* bias; float* dst; int Nloc, ncol0;
    if (bx == 0)      { W = Wq; bias = bq; dst = q; Nloc = 64;   ncol0 = 0; }
    else if (bx == 1) { W = Wk; bias = bk; dst = k; Nloc = 64;   ncol0 = 0; }
    else              { W = Wv; bias = bv; dst = v; Nloc = H_;   ncol0 = (bx - 2) * 64; }

    float acc[4][4] = {};
    for (int k0 = 0; k0 < C_; k0 += 16) {
#pragma unroll
        for (int s = 0; s < 4; ++s) {
            int idx = tid + s * 256;
            int am = idx >> 4, ak = idx & 15;
            As[ak][am] = px[(size_t)(m0 + am) * C_ + k0 + ak];
        }
#pragma unroll
        for (int s = 0; s < 4; ++s) {
            int idx = tid + s * 256;
            int kk = idx >> 6, bn = idx & 63;
            Bs[kk][bn] = W[(size_t)(k0 + kk) * Nloc + ncol0 + bn];
        }
        __syncthreads();
#pragma unroll
        for (int kk = 0; kk < 16; ++kk) {
            float av[4], bv4[4];
            *(float4*)av = *(const float4*)&As[kk][ty * 4];
            *(float4*)bv4 = *(const float4*)&Bs[kk][tx * 4];
#pragma unroll
            for (int i = 0; i < 4; ++i)
#pragma unroll
                for (int j = 0; j < 4; ++j) acc[i][j] += av[i] * bv4[j];
        }
        __syncthreads();
    }
#pragma unroll
    for (int i = 0; i < 4; ++i) {
        int m = m0 + ty * 4 + i;
#pragma unroll
        for (int j = 0; j < 4; ++j) {
            int n = ncol0 + tx * 4 + j;
            dst[(size_t)m * Nloc + n] = siluf(acc[i][j] + bias[n]);
        }
    }
}

template <int MODE>
__global__ __launch_bounds__(256) void attn_z(const float* __restrict__ alpha,
                                              const float* __restrict__ v,
                                              float* __restrict__ zsF,
                                              ushort* __restrict__ zsT)
{
    const int b = blockIdx.x >> 6, r = blockIdx.x & 63;
    const int t = threadIdx.x;
    __shared__ float al[R_];
    if (t < R_) al[t] = alpha[((size_t)b * R_ + r) * R_ + t];
    __syncthreads();
    float acc[4] = {};
    for (int s = 0; s < R_; ++s) {
        float a = al[s];
        const float* vr = v + ((size_t)b * R_ + s) * H_;
#pragma unroll
        for (int j = 0; j < 4; ++j) acc[j] += a * vr[t + j * 256];
    }
#pragma unroll
    for (int j = 0; j < 4; ++j) {
        const int h = t + j * 256;
        if (MODE == 0) zsF[((size_t)b * R_ + r) * H_ + h] = acc[j];
        else           zsT[((size_t)b * H_ + h) * R_ + r] = bfbits(acc[j]);
    }
}

__global__ __launch_bounds__(64) void attn_scores(
    const float* __restrict__ q, const float* __restrict__ k,
    const float* __restrict__ preS, float* __restrict__ alpha)
{
    const int b = blockIdx.x >> 6, r = blockIdx.x & 63;
    const int s = threadIdx.x;
    const float* qr = q + ((size_t)b * R_ + r) * DK_;
    const float* ks = k + ((size_t)b * R_ + s) * DK_;
    float acc = 0.f;
#pragma unroll
    for (int d = 0; d < DK_; ++d) acc += qr[d] * ks[d];
    acc = acc * 0.125f + preS[((size_t)b * R_ + r) * R_ + s];
    float mx = acc;
#pragma unroll
    for (int o = 32; o > 0; o >>= 1) mx = fmaxf(mx, __shfl_xor(mx, o, 64));
    float e = __expf(acc - mx);
    float sm = e;
#pragma unroll
    for (int o = 32; o > 0; o >>= 1) sm += __shfl_xor(sm, o, 64);
    alpha[((size_t)b * R_ + r) * R_ + s] = e / sm;
}

extern "C" void kernel_launch(void* const* d_in, const int* in_sizes, int n_in,
                              void* d_out, int out_size, void* d_ws, size_t ws_size,
                              hipStream_t stream)
{
    using bf16 = __hip_bfloat16;
    const float* x      = (const float*)d_in[0];
    const int*  maskPAD = (const int*)d_in[1];
    const float* preS   = (const float*)d_in[2];
    const float* Wp     = (const float*)d_in[3];
    const float* bp     = (const float*)d_in[4];
    const float* Wq     = (const float*)d_in[5];
    const float* bq     = (const float*)d_in[6];
    const float* Wk     = (const float*)d_in[7];
    const float* bk     = (const float*)d_in[8];
    const float* Wv     = (const float*)d_in[9];
    const float* bv     = (const float*)d_in[10];
    const float* Wu     = (const float*)d_in[11];
    const float* bu     = (const float*)d_in[12];
    const float* Wo     = (const float*)d_in[13];
    const float* bo     = (const float*)d_in[14];
    const float* gamma  = (const float*)d_in[15];
    const float* beta   = (const float*)d_in[16];
    float* out          = (float*)d_out;

    char* ws = (char*)d_ws;
    const bool bigWS = ws_size >= (size_t)52 * 1024 * 1024;  // proven taken

    if (bigWS) {
        // layout: zg 33.5 MB | pool 18.2 MB | Wut | Wot | Wpt
        bf16* zg = (bf16*)ws;                                   // M*H bf16 (written by fused_gate_z)
        float* parts = (float*)ws;                              // 4 MB K-split parts (dead before zg)
        char* pool = ws + (size_t)M_ * H_ * 2;
        float* pScoreT = (float*)pool;                          // B*R*L f32 (4 MB)
        ushort* pALT   = (ushort*)(pScoreT + (size_t)B_ * R_ * L_);  // B*R*L bf16 (2 MB)
        ushort* pAR16  = pALT + (size_t)B_ * R_ * L_;           // M*R bf16 (2 MB)
        ushort* px16   = pAR16 + (size_t)M_ * R_;               // B*R*C bf16 (0.5 MB)
        ushort* qkv16  = px16 + (size_t)B_ * R_ * C_;           // B*R*1152 bf16 (1.19 MB)
        ushort* zsT16  = qkv16 + (size_t)B_ * R_ * NQKV_;       // B*H*R bf16 (1 MB)
        ushort* Wqkvt  = zsT16 + (size_t)B_ * H_ * R_;          // [1152, C] bf16 (1.13 MB)
        float*  bqkv   = (float*)(Wqkvt + (size_t)NQKV_ * C_);  // 4.6 KB
        bf16*  y       = (bf16*)pool;                           // pre-LN y (16.8 MB), pool dead
        ushort* Wut    = (ushort*)(pool + 18221568);            // [H, C] bf16
        ushort* Wot    = Wut + (size_t)C_ * H_;                 // [C, H] bf16
        ushort* Wpt    = Wot + (size_t)C_ * H_;                 // [R, C] bf16
        ushort* x16    = (ushort*)d_out;                        // [M, C] bf16 (dead before LN)
        ushort* xT16   = x16 + (size_t)M_ * C_;                 // [B, C, L] bf16 (in d_out)

        // 1) x -> bf16 (linear + per-batch transpose), weights -> bf16^T
        x_prep<<<dim3(C_ / 32, M_ / 32), 256, 0, stream>>>(x, x16, xT16);
        prep_w<<<1632, 256, 0, stream>>>(Wu, Wo, Wp, Wq, bq, Wk, bk, Wv, bv,
                                         Wut, Wot, Wpt, Wqkvt, bqkv);
        // 2) pScore GEMM (128x64 tile) + fused softmax over r
        pscore_gemm<<<M_ / 128, 256, 0, stream>>>(x16, Wpt, bp, maskPAD, pAR16, pScoreT);
        softmaxL2<<<B_ * R_, 256, 0, stream>>>(pScoreT, pALT);
        // 3) px = pALT @ x (MFMA, K-split x4) -> parts -> bf16
        compress_mfma<<<dim3(C_ / 256, B_, 4), 512, 0, stream>>>(pALT, xT16, parts);
        compress_reduce16<<<(B_ * R_ * C_) / 1024, 256, 0, stream>>>(parts, px16);
        // 4) q|k|v = silu(px @ Wqkv + b) in one MFMA GEMM (128^2, grid 36)
        mfma_gemm5<0><<<(NQKV_ / 128) * ((B_ * R_) / 128), 256, 0, stream>>>(
            px16, Wqkvt, bqkv, nullptr, nullptr, nullptr, qkv16, nullptr, nullptr,
            NQKV_, C_, NQKV_ / 128, 0);
        attn_fused<<<B_ * R_, 256, 0, stream>>>(qkv16, preS, zsT16);
        // 5) zg = silu(x@Wu+bu) * (pAR @ zsT)   [256x128 tile, 8 waves, 2-buf]
        fused_gate_z<<<(H_ / 128) * (M_ / 256), 512, 0, stream>>>(
            x16, Wut, bu, pAR16, zsT16, (ushort*)zg);
        // 6) y = x + zg @ Wo + bo   [256x128 tile, 8 waves, 2-buf, grid 256]
        gemm256<2><<<(C_ / 128) * (M_ / 256), 512, 0, stream>>>(
            (ushort*)zg, Wot, bo, x, (ushort*)y, C_, H_, C_ / 128);
        layernorm<<<M_, 256, 0, stream>>>((const ushort*)y, gamma, beta, out);
    } else {
        // ---- Compact plan (~23.4 MiB), SIMT per-batch (dead in practice) ----
        float* pScore = (float*)ws;
        float* pAL   = pScore + (size_t)M_ * R_;
        float* pAR   = pAL    + (size_t)M_ * R_;
        float* px    = pAR    + (size_t)M_ * R_;
        float* q     = px     + (size_t)B_ * R_ * C_;
        float* kk    = q      + (size_t)B_ * R_ * DK_;
        float* vv    = kk     + (size_t)B_ * R_ * DK_;
        float* alpha = vv     + (size_t)B_ * R_ * H_;
        float* zs    = alpha  + (size_t)B_ * R_ * R_;
        bf16* gate_b = (bf16*)(zs + (size_t)B_ * R_ * H_);
        bf16* y_b    = (bf16*)((char*)gate_b + (size_t)L_ * H_ * 2);

        gemm64<float, float, float, 0, 1><<<dim3(R_ / 64, M_ / 64), 256, 0, stream>>>(
            x, Wp, bp, maskPAD, (const float*)nullptr, pScore, nullptr, R_, C_, 0);
        softmaxL<<<B_ * R_, 256, 0, stream>>>(pScore, pAL);
        softmaxR<0><<<M_, 64, 0, stream>>>(pScore, pAR, nullptr);
        compress_part<<<dim3(C_ / 64, 4, B_), 256, 0, stream>>>(pAL, x, pScore);
        compress_reduce<<<(B_ * R_ * C_) / 256, 256, 0, stream>>>(pScore, px);
        qkv_gemm<<<dim3(2 + H_ / 64, (B_ * R_) / 64), 256, 0, stream>>>(
            px, Wq, bq, Wk, bk, Wv, bv, q, kk, vv);
        attn_scores<<<B_ * R_, 64, 0, stream>>>(q, kk, preS, alpha);
        attn_z<0><<<B_ * R_, 256, 0, stream>>>(alpha, vv, zs, nullptr);

        for (int b = 0; b < B_; ++b) {
            const float* xb = x + (size_t)b * L_ * C_;
            gemm64<float, float, float, 1, 0><<<dim3(H_ / 64, L_ / 64), 256, 0, stream>>>(
                xb, Wu, bu, nullptr, (const float*)nullptr, nullptr, gate_b, H_, C_, 0);
            gemm64<float, float, bf16, 0, 3><<<dim3(H_ / 64, L_ / 64), 256, 0, stream>>>(
                pAR + (size_t)b * L_ * R_, zs + (size_t)b * R_ * H_,
                nullptr, nullptr, gate_b, nullptr, gate_b, H_, R_, 0);
            gemm64<bf16, float, float, 0, 2><<<dim3(C_ / 64, L_ / 64), 256, 0, stream>>>(
                gate_b, Wo, bo, nullptr, xb, nullptr, y_b, C_, H_, 0);
            layernorm<<<L_, 256, 0, stream>>>((const ushort*)y_b, gamma, beta, out + (size_t)b * L_ * C_);
        }
    }
}

// Round 8
// 256.389 us; speedup vs baseline: 1.1138x; 1.0674x over previous
//
#include <hip/hip_runtime.h>
#include <hip/hip_bf16.h>

// Problem constants
constexpr int B_ = 8;
constexpr int L_ = 2048;
constexpr int C_ = 512;
constexpr int R_ = 64;
constexpr int DK_ = 64;
constexpr int H_ = 1024;   // 2*C
constexpr int M_ = B_ * L_;  // 16384
constexpr int NQKV_ = 1152;  // 64 + 64 + 1024 (q|k|v concat)
constexpr float NEG_ = -32767.0f;

__device__ __forceinline__ float toF(float x) { return x; }
__device__ __forceinline__ float toF(__hip_bfloat16 x) { return __bfloat162float(x); }
__device__ __forceinline__ float siluf(float v) { return v / (1.0f + __expf(-v)); }
__device__ __forceinline__ ushort bfbits(float f) {
    __hip_bfloat16 h = __float2bfloat16(f);
    union { __hip_bfloat16 h; ushort u; } cv; cv.h = h; return cv.u;
}
__device__ __forceinline__ float bf2f(ushort u) {
    union { uint u; float f; } cv; cv.u = (uint)u << 16; return cv.f;
}

typedef __attribute__((ext_vector_type(8))) short bf16x8;   // 8 bf16 (4 VGPRs)
typedef __attribute__((ext_vector_type(4))) float f32x4;    // 4 fp32 acc

#define GLOBAL_AS __attribute__((address_space(1)))
#define LDS_AS    __attribute__((address_space(3)))
__device__ __forceinline__ void glds16(const ushort* g, ushort* l) {
    __builtin_amdgcn_global_load_lds((const GLOBAL_AS void*)g, (LDS_AS void*)l, 16, 0, 0);
}

// counted-vmcnt + raw barrier helpers (T4): loads stay in flight across barriers.
#define VMCNT(n) asm volatile("s_waitcnt vmcnt(" #n ")" ::: "memory")
#define BARRIER() do { __builtin_amdgcn_s_barrier(); asm volatile("" ::: "memory"); } while (0)

// ---------------------------------------------------------------------------
// MFMA bf16 GEMM, 128x128 tile, BK=32, 4 waves (2x2 of 64x64).
// 3-buffer, 2-deep prefetch, counted vmcnt(4). Used for qkv (grid 36) and
// Wo (EPI 2, grid 512 = 2 blocks/CU).   [round-4 verified]
// EPI 0: silu(acc+bias[n]) -> bf16
// EPI 2: acc+bias[n]+residF (fp32) -> bf16
// ---------------------------------------------------------------------------
template <int EPI>
__global__ __launch_bounds__(256) void mfma_gemm5(
    const ushort* __restrict__ A, const ushort* __restrict__ Bt,
    const float* __restrict__ bias,
    const float* __restrict__ residF, const ushort* __restrict__ residB,
    const int* __restrict__ mask,
    ushort* __restrict__ outB, float* __restrict__ outF, float* __restrict__ outF2,
    int Ndim, int Kdim, int gridN, long bBatch)
{
    __shared__ ushort As[3][128 * 32];   // 3 x 8 KB
    __shared__ ushort Bs[3][128 * 32];

    const int i = blockIdx.x;
    const int G = gridDim.x >> 3;        // blocks per XCD
    const int gi = (gridDim.x & 7) ? i : ((i & 7) * G + (i >> 3));
    const int nt = gi % gridN, mt = gi / gridN;
    const int m0 = mt * 128, n0 = nt * 128;

    const int tid = threadIdx.x;
    const int lane = tid & 63, w = tid >> 6;
    const int wm = (w & 1) * 64, wn = (w >> 1) * 64;
    const int lr = lane & 15, lq = lane >> 4;

    const int sr = lane >> 2;
    const int sc = (lane & 3) * 8;
    const int s0 = w * 2, s1 = w * 2 + 1;

    const ushort* Bp = Bt + (bBatch ? (long)(m0 / L_) * bBatch : 0);
    int br0 = n0 + s0 * 16 + sr; if (br0 >= Ndim) br0 = Ndim - 1;   // clamp (N<128)
    int br1 = n0 + s1 * 16 + sr; if (br1 >= Ndim) br1 = Ndim - 1;
    const ushort* a0p = A  + (size_t)(m0 + s0 * 16 + sr) * Kdim + sc;
    const ushort* a1p = A  + (size_t)(m0 + s1 * 16 + sr) * Kdim + sc;
    const ushort* b0p = Bp + (size_t)br0 * Kdim + sc;
    const ushort* b1p = Bp + (size_t)br1 * Kdim + sc;
    const int lo0 = s0 * 512 + lane * 8;
    const int lo1 = s1 * 512 + lane * 8;

    f32x4 acc[4][4];
#pragma unroll
    for (int a = 0; a < 4; ++a)
#pragma unroll
        for (int b = 0; b < 4; ++b) acc[a][b] = (f32x4){0.f, 0.f, 0.f, 0.f};

    glds16(a0p, &As[0][lo0]);
    glds16(a1p, &As[0][lo1]);
    glds16(b0p, &Bs[0][lo0]);
    glds16(b1p, &Bs[0][lo1]);
    if (32 < Kdim) {
        glds16(a0p + 32, &As[1][lo0]);
        glds16(a1p + 32, &As[1][lo1]);
        glds16(b0p + 32, &Bs[1][lo0]);
        glds16(b1p + 32, &Bs[1][lo1]);
    }

    int cur = 0;
    for (int k0 = 0; k0 < Kdim; k0 += 32) {
        if (k0 + 32 < Kdim) VMCNT(4); else VMCNT(0);
        BARRIER();
        if (k0 + 64 < Kdim) {
            const int nx = cur ? cur - 1 : 2;   // (cur+2)%3
            glds16(a0p + k0 + 64, &As[nx][lo0]);
            glds16(a1p + k0 + 64, &As[nx][lo1]);
            glds16(b0p + k0 + 64, &Bs[nx][lo0]);
            glds16(b1p + k0 + 64, &Bs[nx][lo1]);
        }
        bf16x8 af[4], bf[4];
#pragma unroll
        for (int a = 0; a < 4; ++a)
            af[a] = *(const bf16x8*)&As[cur][(wm + a * 16 + lr) * 32 + lq * 8];
#pragma unroll
        for (int b = 0; b < 4; ++b)
            bf[b] = *(const bf16x8*)&Bs[cur][(wn + b * 16 + lr) * 32 + lq * 8];
#pragma unroll
        for (int a = 0; a < 4; ++a)
#pragma unroll
            for (int b = 0; b < 4; ++b)
                acc[a][b] = __builtin_amdgcn_mfma_f32_16x16x32_bf16(af[a], bf[b], acc[a][b], 0, 0, 0);
        cur = (cur == 2) ? 0 : cur + 1;
    }

#pragma unroll
    for (int a = 0; a < 4; ++a) {
#pragma unroll
        for (int b = 0; b < 4; ++b) {
            const int col = n0 + wn + b * 16 + lr;
            if (col < Ndim) {
                const float bn = (EPI == 3) ? 0.f : bias[col];
#pragma unroll
                for (int r = 0; r < 4; ++r) {
                    const int row = m0 + wm + a * 16 + lq * 4 + r;
                    float v = acc[a][b][r];
                    if (EPI == 0) {
                        v = siluf(v + bn);
                        outB[(size_t)row * Ndim + col] = bfbits(v);
                    } else if (EPI == 2) {
                        v += bn + residF[(size_t)row * Ndim + col];
                        outB[(size_t)row * Ndim + col] = bfbits(v);
                    } else {
                        v *= bf2f(residB[(size_t)row * Ndim + col]);
                        outB[(size_t)row * Ndim + col] = bfbits(v);
                    }
                }
            }
        }
    }
}

// ---------------------------------------------------------------------------
// pScore GEMM: tile 64(M) x 64(N), K=C=512, 4 waves each 16(M)x64(N).
// grid 256 (1 block/CU, was 0.5). 3-buffer counted vmcnt(2) (2 glds/wave).
// Fused epilogue: masked pScoreT[B,R,L] fp32 write + softmax over r -> bf16.
// ---------------------------------------------------------------------------
__global__ __launch_bounds__(256) void pscore_gemm(
    const ushort* __restrict__ x16, const ushort* __restrict__ Wpt,
    const float* __restrict__ bp, const int* __restrict__ mask,
    ushort* __restrict__ pAR16, float* __restrict__ pScoreT)
{
    __shared__ ushort As[3][64 * 32];   // 3 x 4 KB
    __shared__ ushort Bs[3][64 * 32];   // 3 x 4 KB

    const int i = blockIdx.x;
    const int G = gridDim.x >> 3;
    const int gi = (i & 7) * G + (i >> 3);   // grid = 256, %8==0
    const int m0 = gi * 64;

    const int tid = threadIdx.x;
    const int lane = tid & 63, w = tid >> 6;
    const int lr = lane & 15, lq = lane >> 4;
    const int sr = lane >> 2, sc = (lane & 3) * 8;

    const ushort* ap  = x16 + (size_t)(m0 + w * 16 + sr) * C_ + sc;   // A seg w
    const ushort* bwp = Wpt + (size_t)(w * 16 + sr) * C_ + sc;        // B seg w
    const int loa = w * 512 + lane * 8;

    f32x4 acc[4];
#pragma unroll
    for (int b = 0; b < 4; ++b) acc[b] = (f32x4){0.f, 0.f, 0.f, 0.f};

    glds16(ap, &As[0][loa]);
    glds16(bwp, &Bs[0][loa]);
    glds16(ap + 32, &As[1][loa]);
    glds16(bwp + 32, &Bs[1][loa]);

    int cur = 0;
    for (int k0 = 0; k0 < C_; k0 += 32) {
        if (k0 + 32 < C_) VMCNT(2); else VMCNT(0);
        BARRIER();
        if (k0 + 64 < C_) {
            const int nx = cur ? cur - 1 : 2;
            glds16(ap + k0 + 64, &As[nx][loa]);
            glds16(bwp + k0 + 64, &Bs[nx][loa]);
        }
        bf16x8 af, bf[4];
        af = *(const bf16x8*)&As[cur][(w * 16 + lr) * 32 + lq * 8];
#pragma unroll
        for (int b = 0; b < 4; ++b)
            bf[b] = *(const bf16x8*)&Bs[cur][(b * 16 + lr) * 32 + lq * 8];
#pragma unroll
        for (int b = 0; b < 4; ++b)
            acc[b] = __builtin_amdgcn_mfma_f32_16x16x32_bf16(af, bf[b], acc[b], 0, 0, 0);
        cur = (cur == 2) ? 0 : cur + 1;
    }

    // epilogue: per row (16-lane group holds all 64 cols as 4x16)
#pragma unroll
    for (int r = 0; r < 4; ++r) {
        const int row = m0 + w * 16 + lq * 4 + r;
        const bool dead = (mask[row] == 0);
        const int bb = row >> 11, ll = row & (L_ - 1);
        float v[4];
        float mx = -3.4e38f;
#pragma unroll
        for (int b = 0; b < 4; ++b) {
            const int col = b * 16 + lr;
            float t = acc[b][r] + bp[col];
            if (dead) t = NEG_;
            v[b] = t;
            pScoreT[((size_t)bb * R_ + col) * L_ + ll] = t;
            mx = fmaxf(mx, t);
        }
#pragma unroll
        for (int o = 1; o < 16; o <<= 1) mx = fmaxf(mx, __shfl_xor(mx, o, 64));
        float e[4], s = 0.f;
#pragma unroll
        for (int b = 0; b < 4; ++b) { e[b] = __expf(v[b] - mx); s += e[b]; }
#pragma unroll
        for (int o = 1; o < 16; o <<= 1) s += __shfl_xor(s, o, 64);
        const float inv = 1.0f / s;
#pragma unroll
        for (int b = 0; b < 4; ++b)
            pAR16[(size_t)row * R_ + b * 16 + lr] = bfbits(e[b] * inv);
    }
}

// ---------------------------------------------------------------------------
// Fused gate+expand: zg = silu(x@Wu + bu) * (pAR @ zsT[b]) over [M, H].
// 256x128 tile, 8 waves (4M x 2N), 18-tile stream (2 expand + 16 gate),
// 2-buffer ping-pong __syncthreads. 48 KB LDS, grid 512.
// [round-7 measured: 43.4 us, VGPR 92, no spill — kept byte-identical]
// ---------------------------------------------------------------------------
__global__ __launch_bounds__(512) void fused_gate_z(
    const ushort* __restrict__ x16, const ushort* __restrict__ Wut,
    const float* __restrict__ bu,
    const ushort* __restrict__ pAR, const ushort* __restrict__ zsT,
    ushort* __restrict__ zg)
{
    __shared__ ushort As[2][256 * 32];   // 2 x 16 KB
    __shared__ ushort Bs[2][128 * 32];   // 2 x 8 KB

    const int i = blockIdx.x;
    const int G = gridDim.x >> 3;        // grid = 512, %8==0
    const int gi = (i & 7) * G + (i >> 3);
    constexpr int gridN = H_ / 128;      // 8
    const int nt = gi % gridN, mt = gi / gridN;
    const int m0 = mt * 256, n0 = nt * 128;

    const int tid = threadIdx.x;
    const int lane = tid & 63, w = tid >> 6;   // 8 waves
    const int wm = (w & 3) * 64, wn = (w >> 2) * 64;
    const int lr = lane & 15, lq = lane >> 4;
    const int sr = lane >> 2, sc = (lane & 3) * 8;
    const int s0 = w * 2, s1 = w * 2 + 1;

    const int bidx = m0 >> 11;           // batch (2048 % 256 == 0)
    const ushort* a0p = x16 + (size_t)(m0 + s0 * 16 + sr) * C_ + sc;
    const ushort* a1p = x16 + (size_t)(m0 + s1 * 16 + sr) * C_ + sc;
    const ushort* b0p = Wut + (size_t)(n0 + w * 16 + sr) * C_ + sc;
    const ushort* zb  = zsT + (size_t)bidx * H_ * R_;
    const ushort* c0p = pAR + (size_t)(m0 + s0 * 16 + sr) * R_ + sc;
    const ushort* c1p = pAR + (size_t)(m0 + s1 * 16 + sr) * R_ + sc;
    const ushort* d0p = zb + (size_t)(n0 + w * 16 + sr) * R_ + sc;
    const int lo0 = s0 * 512 + lane * 8;
    const int lo1 = s1 * 512 + lane * 8;
    const int lob = w * 512 + lane * 8;

    // tile t: t<2 -> expand (pAR/zsT, k=t*32); t>=2 -> gate (x16/Wut, k=(t-2)*32)
    auto stage = [&](int t, int bsel) {
        if (t < 2) {
            const int off = t * 32;
            glds16(c0p + off, &As[bsel][lo0]);
            glds16(c1p + off, &As[bsel][lo1]);
            glds16(d0p + off, &Bs[bsel][lob]);
        } else {
            const int off = (t - 2) * 32;
            glds16(a0p + off, &As[bsel][lo0]);
            glds16(a1p + off, &As[bsel][lo1]);
            glds16(b0p + off, &Bs[bsel][lob]);
        }
    };

    f32x4 acc[4][4];
#pragma unroll
    for (int a = 0; a < 4; ++a)
#pragma unroll
        for (int b = 0; b < 4; ++b) acc[a][b] = (f32x4){0.f, 0.f, 0.f, 0.f};

    uint pk[4][4][2];

    stage(0, 0);

    int cur = 0;
    for (int t = 0; t < 18; ++t) {
        __syncthreads();
        if (t + 1 < 18) stage(t + 1, cur ^ 1);
        bf16x8 af[4], bf[4];
#pragma unroll
        for (int a = 0; a < 4; ++a)
            af[a] = *(const bf16x8*)&As[cur][(wm + a * 16 + lr) * 32 + lq * 8];
#pragma unroll
        for (int b = 0; b < 4; ++b)
            bf[b] = *(const bf16x8*)&Bs[cur][(wn + b * 16 + lr) * 32 + lq * 8];
#pragma unroll
        for (int a = 0; a < 4; ++a)
#pragma unroll
            for (int b = 0; b < 4; ++b)
                acc[a][b] = __builtin_amdgcn_mfma_f32_16x16x32_bf16(af[a], bf[b], acc[a][b], 0, 0, 0);
        if (t == 1) {
            // expand done: pack to bf16 (matches old zg path precision), reset acc
#pragma unroll
            for (int a = 0; a < 4; ++a)
#pragma unroll
                for (int b = 0; b < 4; ++b) {
                    pk[a][b][0] = (uint)bfbits(acc[a][b][0]) | ((uint)bfbits(acc[a][b][1]) << 16);
                    pk[a][b][1] = (uint)bfbits(acc[a][b][2]) | ((uint)bfbits(acc[a][b][3]) << 16);
                    acc[a][b] = (f32x4){0.f, 0.f, 0.f, 0.f};
                }
        }
        cur ^= 1;
    }

    // epilogue: zg = silu(gate) * expand
#pragma unroll
    for (int a = 0; a < 4; ++a) {
#pragma unroll
        for (int b = 0; b < 4; ++b) {
            const int col = n0 + wn + b * 16 + lr;
            const float bn = bu[col];
#pragma unroll
            for (int r = 0; r < 4; ++r) {
                const int row = m0 + wm + a * 16 + lq * 4 + r;
                const ushort zu = (ushort)((r & 1) ? (pk[a][b][r >> 1] >> 16)
                                                   : (pk[a][b][r >> 1] & 0xffff));
                const float v = siluf(acc[a][b][r] + bn) * bf2f(zu);
                zg[(size_t)row * H_ + col] = bfbits(v);
            }
        }
    }
}

// ---------------------------------------------------------------------------
// Merged prep: blocks [0, 8192): x fp32 [B,L,C] -> x16 [M,C] + xT16 [B,C,L];
// blocks [8192, 9824): weight transposes Wu^T/Wo^T/Wp^T/Wqkv^T + bqkv concat.
// ---------------------------------------------------------------------------
__global__ __launch_bounds__(256) void xw_prep(
    const float* __restrict__ x, ushort* __restrict__ x16, ushort* __restrict__ xT16,
    const float* __restrict__ Wu, const float* __restrict__ Wo, const float* __restrict__ Wp,
    const float* __restrict__ Wq, const float* __restrict__ bq,
    const float* __restrict__ Wk, const float* __restrict__ bk,
    const float* __restrict__ Wv, const float* __restrict__ bv,
    ushort* __restrict__ Wut, ushort* __restrict__ Wot, ushort* __restrict__ Wpt,
    ushort* __restrict__ Wqkvt, float* __restrict__ bqkv)
{
    __shared__ float tile[32][33];
    const int tx = threadIdx.x & 31, ty = threadIdx.x >> 5;   // 32x8
    int id = blockIdx.x;

    if (id < 8192) {   // x part: 16 x 512 tiles of 32x32
        const int c0 = (id & 15) * 32, l0 = (id >> 4) * 32;
#pragma unroll
        for (int i = 0; i < 32; i += 8) {
            const float v = x[(size_t)(l0 + ty + i) * C_ + c0 + tx];
            tile[ty + i][tx] = v;
            x16[(size_t)(l0 + ty + i) * C_ + c0 + tx] = bfbits(v);
        }
        __syncthreads();
        const int bb = l0 >> 11, ll0 = l0 & (L_ - 1);
#pragma unroll
        for (int i = 0; i < 32; i += 8)
            xT16[((size_t)bb * C_ + c0 + ty + i) * L_ + ll0 + tx] = bfbits(tile[tx][ty + i]);
        return;
    }
    id -= 8192;

    const float* W; ushort* Wt; const float* bsrc = nullptr;
    int K, Nloc, n0, k0, nn0;
    if (id < 512) {                 // Wu [512,1024] -> Wut [1024,512]
        W = Wu; Wt = Wut; K = 512; Nloc = 1024;
        n0 = (id & 31) * 32; k0 = (id >> 5) * 32; nn0 = n0;
    } else if (id < 1024) {         // Wo [1024,512] -> Wot [512,1024]
        id -= 512; W = Wo; Wt = Wot; K = 1024; Nloc = 512;
        n0 = (id & 15) * 32; k0 = (id >> 4) * 32; nn0 = n0;
    } else if (id < 1056) {         // Wp [512,64] -> Wpt [64,512]
        id -= 1024; W = Wp; Wt = Wpt; K = 512; Nloc = 64;
        n0 = (id & 1) * 32; k0 = (id >> 1) * 32; nn0 = n0;
    } else {                        // qkv: 36 x 16 tiles over [1152,512]
        id -= 1056; K = 512; Wt = Wqkvt;
        n0 = (id % 36) * 32; k0 = (id / 36) * 32;
        if (n0 < 64)       { W = Wq; bsrc = bq; Nloc = 64;   nn0 = n0; }
        else if (n0 < 128) { W = Wk; bsrc = bk; Nloc = 64;   nn0 = n0 - 64; }
        else               { W = Wv; bsrc = bv; Nloc = 1024; nn0 = n0 - 128; }
    }
#pragma unroll
    for (int i = 0; i < 32; i += 8)
        tile[ty + i][tx] = W[(size_t)(k0 + ty + i) * Nloc + nn0 + tx];
    __syncthreads();
#pragma unroll
    for (int i = 0; i < 32; i += 8)
        Wt[(size_t)(n0 + ty + i) * K + k0 + tx] = bfbits(tile[tx][ty + i]);
    if (bsrc && k0 == 0 && threadIdx.x < 32) bqkv[n0 + threadIdx.x] = bsrc[nn0 + threadIdx.x];
}

// coalesced softmax over L on pScoreT[B,R,L] rows -> pALT[B,R,L] bf16
__global__ __launch_bounds__(256) void softmaxL2(const float* __restrict__ pScoreT,
                                                 ushort* __restrict__ pALT)
{
    const size_t br = blockIdx.x;
    const float* row = pScoreT + br * L_;
    ushort* orow = pALT + br * L_;
    const int t = threadIdx.x;
    __shared__ float red[256];

    float v[8];
    float mx = -3.4e38f;
#pragma unroll
    for (int j = 0; j < 8; ++j) { v[j] = row[t + j * 256]; mx = fmaxf(mx, v[j]); }
    red[t] = mx; __syncthreads();
    for (int s = 128; s > 0; s >>= 1) { if (t < s) red[t] = fmaxf(red[t], red[t + s]); __syncthreads(); }
    mx = red[0]; __syncthreads();

    float e[8], sum = 0.f;
#pragma unroll
    for (int j = 0; j < 8; ++j) { e[j] = __expf(v[j] - mx); sum += e[j]; }
    red[t] = sum; __syncthreads();
    for (int s = 128; s > 0; s >>= 1) { if (t < s) red[t] += red[t + s]; __syncthreads(); }
    const float inv = 1.0f / red[0];
#pragma unroll
    for (int j = 0; j < 8; ++j) orow[t + j * 256] = bfbits(e[j] * inv);
}

// px parts: K-split(8) MFMA compress. Tile 64(M=R) x 128(N), BK=32, 4 waves
// (each 32x64), grid dim3(C/128=4, B=8, 8) = 256 blocks (1/CU; was 64).
// 3-buffer counted vmcnt(3) — uniform 3 glds/wave.
__global__ __launch_bounds__(256) void compress_mfma(
    const ushort* __restrict__ pALT, const ushort* __restrict__ xT,
    float* __restrict__ parts)
{
    __shared__ ushort As[3][64 * 32];    // 3 x 4 KB
    __shared__ ushort Bs[3][128 * 32];   // 3 x 8 KB

    const int bidx = blockIdx.y;
    const int n0 = blockIdx.x * 128;
    const int ks = blockIdx.z;
    const int kbeg = ks * (L_ / 8), kend = kbeg + L_ / 8;
    const int tid = threadIdx.x;
    const int lane = tid & 63, w = tid >> 6;          // 4 waves
    const int lr = lane & 15, lq = lane >> 4;
    const int sr = lane >> 2, sc = (lane & 3) * 8;
    const int wm = (w & 1) * 32, wn = (w >> 1) * 64;

    const ushort* Ab = pALT + (size_t)bidx * R_ * L_;
    const ushort* Bb = xT + (size_t)bidx * C_ * L_;

    const ushort* ap  = Ab + (size_t)(w * 16 + sr) * L_ + sc;              // A seg w (4)
    const ushort* b0p = Bb + (size_t)(n0 + (2 * w) * 16 + sr) * L_ + sc;   // B segs 2w, 2w+1
    const ushort* b1p = Bb + (size_t)(n0 + (2 * w + 1) * 16 + sr) * L_ + sc;
    const int alo  = w * 512 + lane * 8;
    const int blo0 = (2 * w) * 512 + lane * 8;
    const int blo1 = (2 * w + 1) * 512 + lane * 8;

    auto stage = [&](int k0, int bsel) {
        glds16(ap + k0, &As[bsel][alo]);
        glds16(b0p + k0, &Bs[bsel][blo0]);
        glds16(b1p + k0, &Bs[bsel][blo1]);
    };

    f32x4 acc[2][4];
#pragma unroll
    for (int a = 0; a < 2; ++a)
#pragma unroll
        for (int b = 0; b < 4; ++b) acc[a][b] = (f32x4){0.f, 0.f, 0.f, 0.f};

    stage(kbeg, 0);
    stage(kbeg + 32, 1);

    int cur = 0;
    for (int k0 = kbeg; k0 < kend; k0 += 32) {
        if (k0 + 32 < kend) VMCNT(3); else VMCNT(0);
        BARRIER();
        if (k0 + 64 < kend) stage(k0 + 64, cur ? cur - 1 : 2);
        bf16x8 af[2], bf[4];
#pragma unroll
        for (int a = 0; a < 2; ++a)
            af[a] = *(const bf16x8*)&As[cur][(wm + a * 16 + lr) * 32 + lq * 8];
#pragma unroll
        for (int b = 0; b < 4; ++b)
            bf[b] = *(const bf16x8*)&Bs[cur][(wn + b * 16 + lr) * 32 + lq * 8];
#pragma unroll
        for (int a = 0; a < 2; ++a)
#pragma unroll
            for (int b = 0; b < 4; ++b)
                acc[a][b] = __builtin_amdgcn_mfma_f32_16x16x32_bf16(af[a], bf[b], acc[a][b], 0, 0, 0);
        cur = (cur == 2) ? 0 : cur + 1;
    }
#pragma unroll
    for (int a = 0; a < 2; ++a)
#pragma unroll
        for (int b = 0; b < 4; ++b)
#pragma unroll
            for (int r = 0; r < 4; ++r) {
                const int row = wm + a * 16 + lq * 4 + r;
                const int col = n0 + wn + b * 16 + lr;
                parts[(((size_t)ks * B_ + bidx) * R_ + row) * C_ + col] = acc[a][b][r];
            }
}

// reduce 8 K-split parts -> px16 bf16
__global__ __launch_bounds__(256) void compress_reduce16(const float* __restrict__ parts,
                                                         ushort* __restrict__ px16)
{
    const size_t i = ((size_t)blockIdx.x * 256 + threadIdx.x) * 4;
    constexpr size_t S = (size_t)B_ * R_ * C_;
    float4 s = *(const float4*)(parts + i);
#pragma unroll
    for (int k = 1; k < 8; ++k) {
        const float4 p = *(const float4*)(parts + i + (size_t)k * S);
        s.x += p.x; s.y += p.y; s.z += p.z; s.w += p.w;
    }
    ushort4 o;
    o.x = bfbits(s.x); o.y = bfbits(s.y); o.z = bfbits(s.z); o.w = bfbits(s.w);
    *(ushort4*)(px16 + i) = o;
}

// fused scores+softmax+z from bf16 qkv16 [B*R, 1152] (q|k|v concat)
__global__ __launch_bounds__(256) void attn_fused(
    const ushort* __restrict__ qkv, const float* __restrict__ preS,
    ushort* __restrict__ zsT)
{
    const int b = blockIdx.x >> 6, r = blockIdx.x & 63;
    const int t = threadIdx.x;
    __shared__ float al[R_];
    if (t < 64) {
        const ushort* qr = qkv + (size_t)(b * R_ + r) * NQKV_;
        const ushort* ks = qkv + (size_t)(b * R_ + t) * NQKV_ + 64;
        float acc = 0.f;
#pragma unroll
        for (int d = 0; d < DK_; d += 4) {
            const ushort4 qa = *(const ushort4*)(qr + d);
            const ushort4 ka = *(const ushort4*)(ks + d);
            acc += bf2f(qa.x) * bf2f(ka.x) + bf2f(qa.y) * bf2f(ka.y)
                 + bf2f(qa.z) * bf2f(ka.z) + bf2f(qa.w) * bf2f(ka.w);
        }
        acc = acc * 0.125f + preS[((size_t)b * R_ + r) * R_ + t];
        float mx = acc;
#pragma unroll
        for (int o = 32; o > 0; o >>= 1) mx = fmaxf(mx, __shfl_xor(mx, o, 64));
        float e = __expf(acc - mx);
        float sm = e;
#pragma unroll
        for (int o = 32; o > 0; o >>= 1) sm += __shfl_xor(sm, o, 64);
        al[t] = e / sm;
    }
    __syncthreads();
    float acc[4] = {};
    for (int s = 0; s < R_; ++s) {
        const float a = al[s];
        const ushort* vr = qkv + (size_t)(b * R_ + s) * NQKV_ + 128;
#pragma unroll
        for (int j = 0; j < 4; ++j) acc[j] += a * bf2f(vr[t + j * 256]);
    }
#pragma unroll
    for (int j = 0; j < 4; ++j) {
        const int h = t + j * 256;
        zsT[((size_t)b * H_ + h) * R_ + r] = bfbits(acc[j]);
    }
}

// Row layernorm, wave-per-row: 4 rows/block, shuffle-only reduce (no LDS).
// Each lane: 8 contiguous bf16 (ushort4 x2); grid = rows/4.
__global__ __launch_bounds__(256) void layernorm(const ushort* __restrict__ y,
                                                 const float* __restrict__ gamma,
                                                 const float* __restrict__ beta,
                                                 float* __restrict__ out)
{
    const int w = threadIdx.x >> 6, lane = threadIdx.x & 63;
    const size_t m = (size_t)blockIdx.x * 4 + w;
    const ushort* yr = y + m * C_ + lane * 8;
    const ushort4 p0 = *(const ushort4*)(yr);
    const ushort4 p1 = *(const ushort4*)(yr + 4);
    float v[8] = { bf2f(p0.x), bf2f(p0.y), bf2f(p0.z), bf2f(p0.w),
                   bf2f(p1.x), bf2f(p1.y), bf2f(p1.z), bf2f(p1.w) };
    float s = 0.f, q = 0.f;
#pragma unroll
    for (int j = 0; j < 8; ++j) { s += v[j]; q += v[j] * v[j]; }
#pragma unroll
    for (int o = 32; o > 0; o >>= 1) {
        s += __shfl_xor(s, o, 64);
        q += __shfl_xor(q, o, 64);
    }
    const float mu = s * (1.0f / C_);
    const float var = q * (1.0f / C_) - mu * mu;
    const float inv = rsqrtf(var + 1e-5f);
    const float4 g0 = *(const float4*)(gamma + lane * 8);
    const float4 g1 = *(const float4*)(gamma + lane * 8 + 4);
    const float4 b0 = *(const float4*)(beta + lane * 8);
    const float4 b1 = *(const float4*)(beta + lane * 8 + 4);
    float4 o0, o1;
    o0.x = (v[0] - mu) * inv * g0.x + b0.x;
    o0.y = (v[1] - mu) * inv * g0.y + b0.y;
    o0.z = (v[2] - mu) * inv * g0.z + b0.z;
    o0.w = (v[3] - mu) * inv * g0.w + b0.w;
    o1.x = (v[4] - mu) * inv * g1.x + b1.x;
    o1.y = (v[5] - mu) * inv * g1.y + b1.y;
    o1.z = (v[6] - mu) * inv * g1.z + b1.z;
    o1.w = (v[7] - mu) * inv * g1.w + b1.w;
    *(float4*)(out + m * C_ + lane * 8) = o0;
    *(float4*)(out + m * C_ + lane * 8 + 4) = o1;
}

// ---- compact-path SIMT kernels (dead in practice, kept for safety) ----
template <typename AT, typename BT, typename RT, int ACT, int EPI>
__global__ __launch_bounds__(256) void gemm64(
    const AT* __restrict__ A, const BT* __restrict__ Bw,
    const float* __restrict__ bias, const int* __restrict__ mask,
    const RT* resid, float* __restrict__ outF, __hip_bfloat16* outB,
    int Ndim, int Kdim, long bBatchStride)
{
    __shared__ float As[16][68];
    __shared__ float Bs[16][64];
    const int tid = threadIdx.x;
    const int tx = tid & 15, ty = tid >> 4;
    const int n0 = blockIdx.x * 64, m0 = blockIdx.y * 64;
    const BT* Bp = Bw + (bBatchStride ? (long)(m0 / L_) * bBatchStride : 0);
    float acc[4][4] = {};
    for (int k0 = 0; k0 < Kdim; k0 += 16) {
#pragma unroll
        for (int s = 0; s < 4; ++s) {
            int idx = tid + s * 256;
            int am = idx >> 4, ak = idx & 15;
            As[ak][am] = toF(A[(size_t)(m0 + am) * Kdim + k0 + ak]);
        }
#pragma unroll
        for (int s = 0; s < 4; ++s) {
            int idx = tid + s * 256;
            int bk = idx >> 6, bn = idx & 63;
            Bs[bk][bn] = toF(Bp[(size_t)(k0 + bk) * Ndim + n0 + bn]);
        }
        __syncthreads();
#pragma unroll
        for (int kk = 0; kk < 16; ++kk) {
            float av[4], bv[4];
            *(float4*)av = *(const float4*)&As[kk][ty * 4];
            *(float4*)bv = *(const float4*)&Bs[kk][tx * 4];
#pragma unroll
            for (int i = 0; i < 4; ++i)
#pragma unroll
                for (int j = 0; j < 4; ++j) acc[i][j] += av[i] * bv[j];
        }
        __syncthreads();
    }
#pragma unroll
    for (int i = 0; i < 4; ++i) {
        int m = m0 + ty * 4 + i;
#pragma unroll
        for (int j = 0; j < 4; ++j) {
            int n = n0 + tx * 4 + j;
            float val = acc[i][j];
            if (EPI != 3) val += bias[n];
            if (ACT) val = siluf(val);
            if (EPI == 0) outB[(size_t)m * Ndim + n] = __float2bfloat16(val);
            else if (EPI == 1) { if (mask[m] == 0) val = NEG_; outF[(size_t)m * Ndim + n] = val; }
            else if (EPI == 2) { val += toF(resid[(size_t)m * Ndim + n]); outB[(size_t)m * Ndim + n] = __float2bfloat16(val); }
            else { val *= toF(resid[(size_t)m * Ndim + n]); outB[(size_t)m * Ndim + n] = __float2bfloat16(val); }
        }
    }
}

template <int OUT>
__global__ __launch_bounds__(64) void softmaxR(const float* __restrict__ pScore,
                                               float* __restrict__ outF,
                                               ushort* __restrict__ outU)
{
    const size_t m = blockIdx.x;
    const int t = threadIdx.x;
    float v = pScore[m * R_ + t];
    float mx = v;
#pragma unroll
    for (int o = 32; o > 0; o >>= 1) mx = fmaxf(mx, __shfl_xor(mx, o, 64));
    float e = __expf(v - mx);
    float s = e;
#pragma unroll
    for (int o = 32; o > 0; o >>= 1) s += __shfl_xor(s, o, 64);
    if (OUT == 0) outF[m * R_ + t] = e / s;
    else          outU[m * R_ + t] = bfbits(e / s);
}

__global__ __launch_bounds__(256) void softmaxL(const float* __restrict__ pScore,
                                                float* __restrict__ pAlpha)
{
    const int b = blockIdx.x >> 6, r = blockIdx.x & 63;
    const int t = threadIdx.x;
    const float* base = pScore + (size_t)b * L_ * R_ + r;
    float* out = pAlpha + (size_t)b * L_ * R_ + r;
    __shared__ float red[256];
    float mx = -3.4e38f;
    for (int l = t; l < L_; l += 256) mx = fmaxf(mx, base[(size_t)l * R_]);
    red[t] = mx; __syncthreads();
    for (int s = 128; s > 0; s >>= 1) { if (t < s) red[t] = fmaxf(red[t], red[t + s]); __syncthreads(); }
    mx = red[0]; __syncthreads();
    float sum = 0.f;
    for (int l = t; l < L_; l += 256) {
        float e = __expf(base[(size_t)l * R_] - mx);
        out[(size_t)l * R_] = e; sum += e;
    }
    red[t] = sum; __syncthreads();
    for (int s = 128; s > 0; s >>= 1) { if (t < s) red[t] += red[t + s]; __syncthreads(); }
    const float inv = 1.0f / red[0];
    for (int l = t; l < L_; l += 256) out[(size_t)l * R_] *= inv;
}

__global__ __launch_bounds__(256) void compress_part(
    const float* __restrict__ pAlpha, const float* __restrict__ x,
    float* __restrict__ parts)
{
    __shared__ float As[16][64];
    __shared__ float Bs[16][64];
    const int tid = threadIdx.x;
    const int tx = tid & 15, ty = tid >> 4;
    const int n0 = blockIdx.x * 64;
    const int ks = blockIdx.y;
    const int b  = blockIdx.z;
    const float* pa = pAlpha + (size_t)b * L_ * R_;
    const float* xb = x + (size_t)b * L_ * C_;
    float acc[4][4] = {};
    const int kbeg = ks * (L_ / 4), kend = kbeg + L_ / 4;
    for (int k0 = kbeg; k0 < kend; k0 += 16) {
#pragma unroll
        for (int s = 0; s < 4; ++s) {
            int idx = tid + s * 256;
            int kk = idx >> 6, m = idx & 63;
            As[kk][m] = pa[(size_t)(k0 + kk) * R_ + m];
        }
#pragma unroll
        for (int s = 0; s < 4; ++s) {
            int idx = tid + s * 256;
            int kk = idx >> 6, n = idx & 63;
            Bs[kk][n] = xb[(size_t)(k0 + kk) * C_ + n0 + n];
        }
        __syncthreads();
#pragma unroll
        for (int kk = 0; kk < 16; ++kk) {
            float av[4], bv[4];
            *(float4*)av = *(const float4*)&As[kk][ty * 4];
            *(float4*)bv = *(const float4*)&Bs[kk][tx * 4];
#pragma unroll
            for (int i = 0; i < 4; ++i)
#pragma unroll
                for (int j = 0; j < 4; ++j) acc[i][j] += av[i] * bv[j];
        }
        __syncthreads();
    }
#pragma unroll
    for (int i = 0; i < 4; ++i)
#pragma unroll
        for (int j = 0; j < 4; ++j)
            parts[((((size_t)ks * B_ + b) * R_) + ty * 4 + i) * C_ + n0 + tx * 4 + j] = acc[i][j];
}

__global__ __launch_bounds__(256) void compress_reduce(const float* __restrict__ parts,
                                                       float* __restrict__ px)
{
    const size_t i = (size_t)blockIdx.x * 256 + threadIdx.x;
    constexpr size_t S = (size_t)B_ * R_ * C_;
    px[i] = parts[i] + parts[i + S] + parts[i + 2 * S] + parts[i + 3 * S];
}

__global__ __launch_bounds__(256) void qkv_gemm(
    const float* __restrict__ px,
    const float* __restrict__ Wq, const float* __restrict__ bq,
    const float* __restrict__ Wk, const float* __restrict__ bk,
    const float* __restrict__ Wv, const float* __restrict__ bv,
    float* __restrict__ q, float* __restrict__ k, float* __restrict__ v)
{
    __shared__ float As[16][68];
    __shared__ float Bs[16][64];
    const int tid = threadIdx.x;
    const int tx = tid & 15, ty = tid >> 4;
    const int bx = blockIdx.x;
    const int m0 = blockIdx.y * 64;
    const float* W; const float* bias; float* dst; int Nloc, ncol0;
    if (bx == 0)      { W = Wq; bias = bq; dst = q; Nloc = 64;   ncol0 = 0; }
    else if (bx == 1) { W = Wk; bias = bk; dst = k; Nloc = 64;   ncol0 = 0; }
    else              { W = Wv; bias = bv; dst = v; Nloc = H_;   ncol0 = (bx - 2) * 64; }

    float acc[4][4] = {};
    for (int k0 = 0; k0 < C_; k0 += 16) {
#pragma unroll
        for (int s = 0; s < 4; ++s) {
            int idx = tid + s * 256;
            int am = idx >> 4, ak = idx & 15;
            As[ak][am] = px[(size_t)(m0 + am) * C_ + k0 + ak];
        }
#pragma unroll
        for (int s = 0; s < 4; ++s) {
            int idx = tid + s * 256;
            int kk = idx >> 6, bn = idx & 63;
            Bs[kk][bn] = W[(size_t)(k0 + kk) * Nloc + ncol0 + bn];
        }
        __syncthreads();
#pragma unroll
        for (int kk = 0; kk < 16; ++kk) {
            float av[4], bv4[4];
            *(float4*)av = *(const float4*)&As[kk][ty * 4];
            *(float4*)bv4 = *(const float4*)&Bs[kk][tx * 4];
#pragma unroll
            for (int i = 0; i < 4; ++i)
#pragma unroll
                for (int j = 0; j < 4; ++j) acc[i][j] += av[i] * bv4[j];
        }
        __syncthreads();
    }
#pragma unroll
    for (int i = 0; i < 4; ++i) {
        int m = m0 + ty * 4 + i;
#pragma unroll
        for (int j = 0; j < 4; ++j) {
            int n = ncol0 + tx * 4 + j;
            dst[(size_t)m * Nloc + n] = siluf(acc[i][j] + bias[n]);
        }
    }
}

template <int MODE>
__global__ __launch_bounds__(256) void attn_z(const float* __restrict__ alpha,
                                              const float* __restrict__ v,
                                              float* __restrict__ zsF,
                                              ushort* __restrict__ zsT)
{
    const int b = blockIdx.x >> 6, r = blockIdx.x & 63;
    const int t = threadIdx.x;
    __shared__ float al[R_];
    if (t < R_) al[t] = alpha[((size_t)b * R_ + r) * R_ + t];
    __syncthreads();
    float acc[4] = {};
    for (int s = 0; s < R_; ++s) {
        float a = al[s];
        const float* vr = v + ((size_t)b * R_ + s) * H_;
#pragma unroll
        for (int j = 0; j < 4; ++j) acc[j] += a * vr[t + j * 256];
    }
#pragma unroll
    for (int j = 0; j < 4; ++j) {
        const int h = t + j * 256;
        if (MODE == 0) zsF[((size_t)b * R_ + r) * H_ + h] = acc[j];
        else           zsT[((size_t)b * H_ + h) * R_ + r] = bfbits(acc[j]);
    }
}

__global__ __launch_bounds__(64) void attn_scores(
    const float* __restrict__ q, const float* __restrict__ k,
    const float* __restrict__ preS, float* __restrict__ alpha)
{
    const int b = blockIdx.x >> 6, r = blockIdx.x & 63;
    const int s = threadIdx.x;
    const float* qr = q + ((size_t)b * R_ + r) * DK_;
    const float* ks = k + ((size_t)b * R_ + s) * DK_;
    float acc = 0.f;
#pragma unroll
    for (int d = 0; d < DK_; ++d) acc += qr[d] * ks[d];
    acc = acc * 0.125f + preS[((size_t)b * R_ + r) * R_ + s];
    float mx = acc;
#pragma unroll
    for (int o = 32; o > 0; o >>= 1) mx = fmaxf(mx, __shfl_xor(mx, o, 64));
    float e = __expf(acc - mx);
    float sm = e;
#pragma unroll
    for (int o = 32; o > 0; o >>= 1) sm += __shfl_xor(sm, o, 64);
    alpha[((size_t)b * R_ + r) * R_ + s] = e / sm;
}

extern "C" void kernel_launch(void* const* d_in, const int* in_sizes, int n_in,
                              void* d_out, int out_size, void* d_ws, size_t ws_size,
                              hipStream_t stream)
{
    using bf16 = __hip_bfloat16;
    const float* x      = (const float*)d_in[0];
    const int*  maskPAD = (const int*)d_in[1];
    const float* preS   = (const float*)d_in[2];
    const float* Wp     = (const float*)d_in[3];
    const float* bp     = (const float*)d_in[4];
    const float* Wq     = (const float*)d_in[5];
    const float* bq     = (const float*)d_in[6];
    const float* Wk     = (const float*)d_in[7];
    const float* bk     = (const float*)d_in[8];
    const float* Wv     = (const float*)d_in[9];
    const float* bv     = (const float*)d_in[10];
    const float* Wu     = (const float*)d_in[11];
    const float* bu     = (const float*)d_in[12];
    const float* Wo     = (const float*)d_in[13];
    const float* bo     = (const float*)d_in[14];
    const float* gamma  = (const float*)d_in[15];
    const float* beta   = (const float*)d_in[16];
    float* out          = (float*)d_out;

    char* ws = (char*)d_ws;
    const bool bigWS = ws_size >= (size_t)52 * 1024 * 1024;  // proven taken

    if (bigWS) {
        // layout: zg 33.5 MB | pool 18.2 MB | Wut | Wot | Wpt
        bf16* zg = (bf16*)ws;                                   // M*H bf16 (written by fused_gate_z)
        float* parts = (float*)ws;                              // 8 MB K-split parts (dead before zg)
        char* pool = ws + (size_t)M_ * H_ * 2;
        float* pScoreT = (float*)pool;                          // B*R*L f32 (4 MB)
        ushort* pALT   = (ushort*)(pScoreT + (size_t)B_ * R_ * L_);  // B*R*L bf16 (2 MB)
        ushort* pAR16  = pALT + (size_t)B_ * R_ * L_;           // M*R bf16 (2 MB)
        ushort* px16   = pAR16 + (size_t)M_ * R_;               // B*R*C bf16 (0.5 MB)
        ushort* qkv16  = px16 + (size_t)B_ * R_ * C_;           // B*R*1152 bf16 (1.19 MB)
        ushort* zsT16  = qkv16 + (size_t)B_ * R_ * NQKV_;       // B*H*R bf16 (1 MB)
        ushort* Wqkvt  = zsT16 + (size_t)B_ * H_ * R_;          // [1152, C] bf16 (1.13 MB)
        float*  bqkv   = (float*)(Wqkvt + (size_t)NQKV_ * C_);  // 4.6 KB
        bf16*  y       = (bf16*)pool;                           // pre-LN y (16.8 MB), pool dead
        ushort* Wut    = (ushort*)(pool + 18221568);            // [H, C] bf16
        ushort* Wot    = Wut + (size_t)C_ * H_;                 // [C, H] bf16
        ushort* Wpt    = Wot + (size_t)C_ * H_;                 // [R, C] bf16
        ushort* x16    = (ushort*)d_out;                        // [M, C] bf16 (dead before LN)
        ushort* xT16   = x16 + (size_t)M_ * C_;                 // [B, C, L] bf16 (in d_out)

        // 1) x -> bf16 (linear + transpose) + all weight transposes, ONE launch
        xw_prep<<<8192 + 1632, 256, 0, stream>>>(
            x, x16, xT16, Wu, Wo, Wp, Wq, bq, Wk, bk, Wv, bv,
            Wut, Wot, Wpt, Wqkvt, bqkv);
        // 2) pScore GEMM (64x64 tile, grid 256) + fused softmax over r
        pscore_gemm<<<M_ / 64, 256, 0, stream>>>(x16, Wpt, bp, maskPAD, pAR16, pScoreT);
        softmaxL2<<<B_ * R_, 256, 0, stream>>>(pScoreT, pALT);
        // 3) px = pALT @ x (MFMA, K-split x8, grid 256) -> parts -> bf16
        compress_mfma<<<dim3(C_ / 128, B_, 8), 256, 0, stream>>>(pALT, xT16, parts);
        compress_reduce16<<<(B_ * R_ * C_) / 1024, 256, 0, stream>>>(parts, px16);
        // 4) q|k|v = silu(px @ Wqkv + b) in one MFMA GEMM (128^2, grid 36)
        mfma_gemm5<0><<<(NQKV_ / 128) * ((B_ * R_) / 128), 256, 0, stream>>>(
            px16, Wqkvt, bqkv, nullptr, nullptr, nullptr, qkv16, nullptr, nullptr,
            NQKV_, C_, NQKV_ / 128, 0);
        attn_fused<<<B_ * R_, 256, 0, stream>>>(qkv16, preS, zsT16);
        // 5) zg = silu(x@Wu+bu) * (pAR @ zsT)   [256x128 tile, 8 waves, 2-buf]
        fused_gate_z<<<(H_ / 128) * (M_ / 256), 512, 0, stream>>>(
            x16, Wut, bu, pAR16, zsT16, (ushort*)zg);
        // 6) y = x + zg @ Wo + bo   [128^2 3-buf counted, grid 512 = 2/CU]
        mfma_gemm5<2><<<(C_ / 128) * (M_ / 128), 256, 0, stream>>>(
            (ushort*)zg, Wot, bo, x, nullptr, nullptr, (ushort*)y, nullptr, nullptr,
            C_, H_, C_ / 128, 0);
        layernorm<<<M_ / 4, 256, 0, stream>>>((const ushort*)y, gamma, beta, out);
    } else {
        // ---- Compact plan (~23.4 MiB), SIMT per-batch (dead in practice) ----
        float* pScore = (float*)ws;
        float* pAL   = pScore + (size_t)M_ * R_;
        float* pAR   = pAL    + (size_t)M_ * R_;
        float* px    = pAR    + (size_t)M_ * R_;
        float* q     = px     + (size_t)B_ * R_ * C_;
        float* kk    = q      + (size_t)B_ * R_ * DK_;
        float* vv    = kk     + (size_t)B_ * R_ * DK_;
        float* alpha = vv     + (size_t)B_ * R_ * H_;
        float* zs    = alpha  + (size_t)B_ * R_ * R_;
        bf16* gate_b = (bf16*)(zs + (size_t)B_ * R_ * H_);
        bf16* y_b    = (bf16*)((char*)gate_b + (size_t)L_ * H_ * 2);

        gemm64<float, float, float, 0, 1><<<dim3(R_ / 64, M_ / 64), 256, 0, stream>>>(
            x, Wp, bp, maskPAD, (const float*)nullptr, pScore, nullptr, R_, C_, 0);
        softmaxL<<<B_ * R_, 256, 0, stream>>>(pScore, pAL);
        softmaxR<0><<<M_, 64, 0, stream>>>(pScore, pAR, nullptr);
        compress_part<<<dim3(C_ / 64, 4, B_), 256, 0, stream>>>(pAL, x, pScore);
        compress_reduce<<<(B_ * R_ * C_) / 256, 256, 0, stream>>>(pScore, px);
        qkv_gemm<<<dim3(2 + H_ / 64, (B_ * R_) / 64), 256, 0, stream>>>(
            px, Wq, bq, Wk, bk, Wv, bv, q, kk, vv);
        attn_scores<<<B_ * R_, 64, 0, stream>>>(q, kk, preS, alpha);
        attn_z<0><<<B_ * R_, 256, 0, stream>>>(alpha, vv, zs, nullptr);

        for (int b = 0; b < B_; ++b) {
            const float* xb = x + (size_t)b * L_ * C_;
            gemm64<float, float, float, 1, 0><<<dim3(H_ / 64, L_ / 64), 256, 0, stream>>>(
                xb, Wu, bu, nullptr, (const float*)nullptr, nullptr, gate_b, H_, C_, 0);
            gemm64<float, float, bf16, 0, 3><<<dim3(H_ / 64, L_ / 64), 256, 0, stream>>>(
                pAR + (size_t)b * L_ * R_, zs + (size_t)b * R_ * H_,
                nullptr, nullptr, gate_b, nullptr, gate_b, H_, R_, 0);
            gemm64<bf16, float, float, 0, 2><<<dim3(C_ / 64, L_ / 64), 256, 0, stream>>>(
                gate_b, Wo, bo, nullptr, xb, nullptr, y_b, C_, H_, 0);
            layernorm<<<L_ / 4, 256, 0, stream>>>((const ushort*)y_b, gamma, beta, out + (size_t)b * L_ * C_);
        }
    }
}

// Round 9
// 246.735 us; speedup vs baseline: 1.1574x; 1.0391x over previous
//
#include <hip/hip_runtime.h>
#include <hip/hip_bf16.h>

// Problem constants
constexpr int B_ = 8;
constexpr int L_ = 2048;
constexpr int C_ = 512;
constexpr int R_ = 64;
constexpr int DK_ = 64;
constexpr int H_ = 1024;   // 2*C
constexpr int M_ = B_ * L_;  // 16384
constexpr int NQKV_ = 1152;  // 64 + 64 + 1024 (q|k|v concat)
constexpr float NEG_ = -32767.0f;

__device__ __forceinline__ float toF(float x) { return x; }
__device__ __forceinline__ float toF(__hip_bfloat16 x) { return __bfloat162float(x); }
__device__ __forceinline__ float siluf(float v) { return v / (1.0f + __expf(-v)); }
__device__ __forceinline__ ushort bfbits(float f) {
    __hip_bfloat16 h = __float2bfloat16(f);
    union { __hip_bfloat16 h; ushort u; } cv; cv.h = h; return cv.u;
}
__device__ __forceinline__ float bf2f(ushort u) {
    union { uint u; float f; } cv; cv.u = (uint)u << 16; return cv.f;
}

typedef __attribute__((ext_vector_type(8))) short bf16x8;   // 8 bf16 (4 VGPRs)
typedef __attribute__((ext_vector_type(4))) float f32x4;    // 4 fp32 acc

#define GLOBAL_AS __attribute__((address_space(1)))
#define LDS_AS    __attribute__((address_space(3)))
__device__ __forceinline__ void glds16(const ushort* g, ushort* l) {
    __builtin_amdgcn_global_load_lds((const GLOBAL_AS void*)g, (LDS_AS void*)l, 16, 0, 0);
}

// counted-vmcnt + raw barrier helpers (T4): loads stay in flight across barriers.
#define VMCNT(n) asm volatile("s_waitcnt vmcnt(" #n ")" ::: "memory")
#define BARRIER() do { __builtin_amdgcn_s_barrier(); asm volatile("" ::: "memory"); } while (0)

// ---------------------------------------------------------------------------
// MFMA bf16 GEMM, 128x128 tile, BK=32, 4 waves (2x2 of 64x64).
// 3-buffer, 2-deep prefetch, counted vmcnt(4). Used for Wo (EPI 2, grid 512).
// ---------------------------------------------------------------------------
template <int EPI>
__global__ __launch_bounds__(256) void mfma_gemm5(
    const ushort* __restrict__ A, const ushort* __restrict__ Bt,
    const float* __restrict__ bias,
    const float* __restrict__ residF, const ushort* __restrict__ residB,
    const int* __restrict__ mask,
    ushort* __restrict__ outB, float* __restrict__ outF, float* __restrict__ outF2,
    int Ndim, int Kdim, int gridN, long bBatch)
{
    __shared__ ushort As[3][128 * 32];   // 3 x 8 KB
    __shared__ ushort Bs[3][128 * 32];

    const int i = blockIdx.x;
    const int G = gridDim.x >> 3;        // blocks per XCD
    const int gi = (gridDim.x & 7) ? i : ((i & 7) * G + (i >> 3));
    const int nt = gi % gridN, mt = gi / gridN;
    const int m0 = mt * 128, n0 = nt * 128;

    const int tid = threadIdx.x;
    const int lane = tid & 63, w = tid >> 6;
    const int wm = (w & 1) * 64, wn = (w >> 1) * 64;
    const int lr = lane & 15, lq = lane >> 4;

    const int sr = lane >> 2;
    const int sc = (lane & 3) * 8;
    const int s0 = w * 2, s1 = w * 2 + 1;

    const ushort* Bp = Bt + (bBatch ? (long)(m0 / L_) * bBatch : 0);
    int br0 = n0 + s0 * 16 + sr; if (br0 >= Ndim) br0 = Ndim - 1;   // clamp (N<128)
    int br1 = n0 + s1 * 16 + sr; if (br1 >= Ndim) br1 = Ndim - 1;
    const ushort* a0p = A  + (size_t)(m0 + s0 * 16 + sr) * Kdim + sc;
    const ushort* a1p = A  + (size_t)(m0 + s1 * 16 + sr) * Kdim + sc;
    const ushort* b0p = Bp + (size_t)br0 * Kdim + sc;
    const ushort* b1p = Bp + (size_t)br1 * Kdim + sc;
    const int lo0 = s0 * 512 + lane * 8;
    const int lo1 = s1 * 512 + lane * 8;

    f32x4 acc[4][4];
#pragma unroll
    for (int a = 0; a < 4; ++a)
#pragma unroll
        for (int b = 0; b < 4; ++b) acc[a][b] = (f32x4){0.f, 0.f, 0.f, 0.f};

    glds16(a0p, &As[0][lo0]);
    glds16(a1p, &As[0][lo1]);
    glds16(b0p, &Bs[0][lo0]);
    glds16(b1p, &Bs[0][lo1]);
    if (32 < Kdim) {
        glds16(a0p + 32, &As[1][lo0]);
        glds16(a1p + 32, &As[1][lo1]);
        glds16(b0p + 32, &Bs[1][lo0]);
        glds16(b1p + 32, &Bs[1][lo1]);
    }

    int cur = 0;
    for (int k0 = 0; k0 < Kdim; k0 += 32) {
        if (k0 + 32 < Kdim) VMCNT(4); else VMCNT(0);
        BARRIER();
        if (k0 + 64 < Kdim) {
            const int nx = cur ? cur - 1 : 2;   // (cur+2)%3
            glds16(a0p + k0 + 64, &As[nx][lo0]);
            glds16(a1p + k0 + 64, &As[nx][lo1]);
            glds16(b0p + k0 + 64, &Bs[nx][lo0]);
            glds16(b1p + k0 + 64, &Bs[nx][lo1]);
        }
        bf16x8 af[4], bf[4];
#pragma unroll
        for (int a = 0; a < 4; ++a)
            af[a] = *(const bf16x8*)&As[cur][(wm + a * 16 + lr) * 32 + lq * 8];
#pragma unroll
        for (int b = 0; b < 4; ++b)
            bf[b] = *(const bf16x8*)&Bs[cur][(wn + b * 16 + lr) * 32 + lq * 8];
#pragma unroll
        for (int a = 0; a < 4; ++a)
#pragma unroll
            for (int b = 0; b < 4; ++b)
                acc[a][b] = __builtin_amdgcn_mfma_f32_16x16x32_bf16(af[a], bf[b], acc[a][b], 0, 0, 0);
        cur = (cur == 2) ? 0 : cur + 1;
    }

#pragma unroll
    for (int a = 0; a < 4; ++a) {
#pragma unroll
        for (int b = 0; b < 4; ++b) {
            const int col = n0 + wn + b * 16 + lr;
            if (col < Ndim) {
                const float bn = (EPI == 3) ? 0.f : bias[col];
#pragma unroll
                for (int r = 0; r < 4; ++r) {
                    const int row = m0 + wm + a * 16 + lq * 4 + r;
                    float v = acc[a][b][r];
                    if (EPI == 0) {
                        v = siluf(v + bn);
                        outB[(size_t)row * Ndim + col] = bfbits(v);
                    } else if (EPI == 2) {
                        v += bn + residF[(size_t)row * Ndim + col];
                        outB[(size_t)row * Ndim + col] = bfbits(v);
                    } else {
                        v *= bf2f(residB[(size_t)row * Ndim + col]);
                        outB[(size_t)row * Ndim + col] = bfbits(v);
                    }
                }
            }
        }
    }
}

// ---------------------------------------------------------------------------
// pScore GEMM: tile 64(M) x 64(N), K=C=512, 4 waves each 16(M)x64(N).
// grid 256 (1 block/CU). 3-buffer counted vmcnt(2).
// Fused epilogue:
//  - r-softmax (max-sub, 16-lane shfl) -> pAR16 bf16     [dead rows -> 1/64]
//  - L-path: pALT = bf16(exp(score)) UNNORMALIZED (scores are O(1); masked
//    rows exp(-32767)=0), plus per-column exp-sum atomics into sums[B*R].
//    Normalization applied later in compress_reduce16. Replaces softmaxL2.
// ---------------------------------------------------------------------------
__global__ __launch_bounds__(256) void pscore_gemm(
    const ushort* __restrict__ x16, const ushort* __restrict__ Wpt,
    const float* __restrict__ bp, const int* __restrict__ mask,
    ushort* __restrict__ pAR16, ushort* __restrict__ pALT,
    float* __restrict__ sums)
{
    __shared__ ushort As[3][64 * 32];   // 3 x 4 KB
    __shared__ ushort Bs[3][64 * 32];   // 3 x 4 KB

    const int i = blockIdx.x;
    const int G = gridDim.x >> 3;
    const int gi = (i & 7) * G + (i >> 3);   // grid = 256, %8==0
    const int m0 = gi * 64;

    const int tid = threadIdx.x;
    const int lane = tid & 63, w = tid >> 6;
    const int lr = lane & 15, lq = lane >> 4;
    const int sr = lane >> 2, sc = (lane & 3) * 8;

    const ushort* ap  = x16 + (size_t)(m0 + w * 16 + sr) * C_ + sc;   // A seg w
    const ushort* bwp = Wpt + (size_t)(w * 16 + sr) * C_ + sc;        // B seg w
    const int loa = w * 512 + lane * 8;

    f32x4 acc[4];
#pragma unroll
    for (int b = 0; b < 4; ++b) acc[b] = (f32x4){0.f, 0.f, 0.f, 0.f};

    glds16(ap, &As[0][loa]);
    glds16(bwp, &Bs[0][loa]);
    glds16(ap + 32, &As[1][loa]);
    glds16(bwp + 32, &Bs[1][loa]);

    int cur = 0;
    for (int k0 = 0; k0 < C_; k0 += 32) {
        if (k0 + 32 < C_) VMCNT(2); else VMCNT(0);
        BARRIER();
        if (k0 + 64 < C_) {
            const int nx = cur ? cur - 1 : 2;
            glds16(ap + k0 + 64, &As[nx][loa]);
            glds16(bwp + k0 + 64, &Bs[nx][loa]);
        }
        bf16x8 af, bf[4];
        af = *(const bf16x8*)&As[cur][(w * 16 + lr) * 32 + lq * 8];
#pragma unroll
        for (int b = 0; b < 4; ++b)
            bf[b] = *(const bf16x8*)&Bs[cur][(b * 16 + lr) * 32 + lq * 8];
#pragma unroll
        for (int b = 0; b < 4; ++b)
            acc[b] = __builtin_amdgcn_mfma_f32_16x16x32_bf16(af, bf[b], acc[b], 0, 0, 0);
        cur = (cur == 2) ? 0 : cur + 1;
    }

    // epilogue
    const int bb = m0 >> 11;   // batch uniform per block (64 | 2048)
    float colsum[4] = {0.f, 0.f, 0.f, 0.f};
#pragma unroll
    for (int r = 0; r < 4; ++r) {
        const int row = m0 + w * 16 + lq * 4 + r;
        const bool dead = (mask[row] == 0);
        const int ll = row & (L_ - 1);
        float v[4];
        float mx = -3.4e38f;
#pragma unroll
        for (int b = 0; b < 4; ++b) {
            const int col = b * 16 + lr;
            float t = acc[b][r] + bp[col];
            if (dead) t = NEG_;
            v[b] = t;
            mx = fmaxf(mx, t);
            const float eL = __expf(t);          // 0 for dead rows
            colsum[b] += eL;
            pALT[((size_t)bb * R_ + col) * L_ + ll] = bfbits(eL);
        }
        // r-softmax (keeps max-sub: dead rows give uniform 1/64 like ref)
#pragma unroll
        for (int o = 1; o < 16; o <<= 1) mx = fmaxf(mx, __shfl_xor(mx, o, 64));
        float e[4], s = 0.f;
#pragma unroll
        for (int b = 0; b < 4; ++b) { e[b] = __expf(v[b] - mx); s += e[b]; }
#pragma unroll
        for (int o = 1; o < 16; o <<= 1) s += __shfl_xor(s, o, 64);
        const float inv = 1.0f / s;
#pragma unroll
        for (int b = 0; b < 4; ++b)
            pAR16[(size_t)row * R_ + b * 16 + lr] = bfbits(e[b] * inv);
    }
    // per-column exp-sum: reduce over lq (rows within wave), then atomics
#pragma unroll
    for (int b = 0; b < 4; ++b) {
        colsum[b] += __shfl_xor(colsum[b], 16, 64);
        colsum[b] += __shfl_xor(colsum[b], 32, 64);
    }
    if (lq == 0) {
#pragma unroll
        for (int b = 0; b < 4; ++b)
            atomicAdd(&sums[bb * R_ + b * 16 + lr], colsum[b]);
    }
}

// ---------------------------------------------------------------------------
// qkv GEMM: tile 64(M) x 64(N), K=C=512, grid 8 x 18 = 144 blocks.
// Same verified geometry as pscore_gemm; silu epilogue to qkv16 [B*R, 1152].
// ---------------------------------------------------------------------------
__global__ __launch_bounds__(256) void qkv64(
    const ushort* __restrict__ px16, const ushort* __restrict__ Wqkvt,
    const float* __restrict__ bqkv, ushort* __restrict__ qkv16)
{
    __shared__ ushort As[3][64 * 32];
    __shared__ ushort Bs[3][64 * 32];

    const int nt = blockIdx.x % 18, mt = blockIdx.x / 18;
    const int m0 = mt * 64, n0 = nt * 64;

    const int tid = threadIdx.x;
    const int lane = tid & 63, w = tid >> 6;
    const int lr = lane & 15, lq = lane >> 4;
    const int sr = lane >> 2, sc = (lane & 3) * 8;

    const ushort* ap  = px16 + (size_t)(m0 + w * 16 + sr) * C_ + sc;
    const ushort* bwp = Wqkvt + (size_t)(n0 + w * 16 + sr) * C_ + sc;
    const int loa = w * 512 + lane * 8;

    f32x4 acc[4];
#pragma unroll
    for (int b = 0; b < 4; ++b) acc[b] = (f32x4){0.f, 0.f, 0.f, 0.f};

    glds16(ap, &As[0][loa]);
    glds16(bwp, &Bs[0][loa]);
    glds16(ap + 32, &As[1][loa]);
    glds16(bwp + 32, &Bs[1][loa]);

    int cur = 0;
    for (int k0 = 0; k0 < C_; k0 += 32) {
        if (k0 + 32 < C_) VMCNT(2); else VMCNT(0);
        BARRIER();
        if (k0 + 64 < C_) {
            const int nx = cur ? cur - 1 : 2;
            glds16(ap + k0 + 64, &As[nx][loa]);
            glds16(bwp + k0 + 64, &Bs[nx][loa]);
        }
        bf16x8 af, bf[4];
        af = *(const bf16x8*)&As[cur][(w * 16 + lr) * 32 + lq * 8];
#pragma unroll
        for (int b = 0; b < 4; ++b)
            bf[b] = *(const bf16x8*)&Bs[cur][(b * 16 + lr) * 32 + lq * 8];
#pragma unroll
        for (int b = 0; b < 4; ++b)
            acc[b] = __builtin_amdgcn_mfma_f32_16x16x32_bf16(af, bf[b], acc[b], 0, 0, 0);
        cur = (cur == 2) ? 0 : cur + 1;
    }

#pragma unroll
    for (int r = 0; r < 4; ++r) {
        const int row = m0 + w * 16 + lq * 4 + r;
#pragma unroll
        for (int b = 0; b < 4; ++b) {
            const int col = n0 + b * 16 + lr;
            qkv16[(size_t)row * NQKV_ + col] = bfbits(siluf(acc[b][r] + bqkv[col]));
        }
    }
}

// ---------------------------------------------------------------------------
// Fused gate+expand: zg = silu(x@Wu + bu) * (pAR @ zsT[b]) over [M, H].
// 256x128 tile, 8 waves (4M x 2N), 18-tile stream (2 expand + 16 gate),
// 2-buffer ping-pong __syncthreads. 48 KB LDS, grid 512.
// [round-7 measured: 43.4 us, VGPR 92, no spill — kept byte-identical]
// ---------------------------------------------------------------------------
__global__ __launch_bounds__(512) void fused_gate_z(
    const ushort* __restrict__ x16, const ushort* __restrict__ Wut,
    const float* __restrict__ bu,
    const ushort* __restrict__ pAR, const ushort* __restrict__ zsT,
    ushort* __restrict__ zg)
{
    __shared__ ushort As[2][256 * 32];   // 2 x 16 KB
    __shared__ ushort Bs[2][128 * 32];   // 2 x 8 KB

    const int i = blockIdx.x;
    const int G = gridDim.x >> 3;        // grid = 512, %8==0
    const int gi = (i & 7) * G + (i >> 3);
    constexpr int gridN = H_ / 128;      // 8
    const int nt = gi % gridN, mt = gi / gridN;
    const int m0 = mt * 256, n0 = nt * 128;

    const int tid = threadIdx.x;
    const int lane = tid & 63, w = tid >> 6;   // 8 waves
    const int wm = (w & 3) * 64, wn = (w >> 2) * 64;
    const int lr = lane & 15, lq = lane >> 4;
    const int sr = lane >> 2, sc = (lane & 3) * 8;
    const int s0 = w * 2, s1 = w * 2 + 1;

    const int bidx = m0 >> 11;           // batch (2048 % 256 == 0)
    const ushort* a0p = x16 + (size_t)(m0 + s0 * 16 + sr) * C_ + sc;
    const ushort* a1p = x16 + (size_t)(m0 + s1 * 16 + sr) * C_ + sc;
    const ushort* b0p = Wut + (size_t)(n0 + w * 16 + sr) * C_ + sc;
    const ushort* zb  = zsT + (size_t)bidx * H_ * R_;
    const ushort* c0p = pAR + (size_t)(m0 + s0 * 16 + sr) * R_ + sc;
    const ushort* c1p = pAR + (size_t)(m0 + s1 * 16 + sr) * R_ + sc;
    const ushort* d0p = zb + (size_t)(n0 + w * 16 + sr) * R_ + sc;
    const int lo0 = s0 * 512 + lane * 8;
    const int lo1 = s1 * 512 + lane * 8;
    const int lob = w * 512 + lane * 8;

    // tile t: t<2 -> expand (pAR/zsT, k=t*32); t>=2 -> gate (x16/Wut, k=(t-2)*32)
    auto stage = [&](int t, int bsel) {
        if (t < 2) {
            const int off = t * 32;
            glds16(c0p + off, &As[bsel][lo0]);
            glds16(c1p + off, &As[bsel][lo1]);
            glds16(d0p + off, &Bs[bsel][lob]);
        } else {
            const int off = (t - 2) * 32;
            glds16(a0p + off, &As[bsel][lo0]);
            glds16(a1p + off, &As[bsel][lo1]);
            glds16(b0p + off, &Bs[bsel][lob]);
        }
    };

    f32x4 acc[4][4];
#pragma unroll
    for (int a = 0; a < 4; ++a)
#pragma unroll
        for (int b = 0; b < 4; ++b) acc[a][b] = (f32x4){0.f, 0.f, 0.f, 0.f};

    uint pk[4][4][2];

    stage(0, 0);

    int cur = 0;
    for (int t = 0; t < 18; ++t) {
        __syncthreads();
        if (t + 1 < 18) stage(t + 1, cur ^ 1);
        bf16x8 af[4], bf[4];
#pragma unroll
        for (int a = 0; a < 4; ++a)
            af[a] = *(const bf16x8*)&As[cur][(wm + a * 16 + lr) * 32 + lq * 8];
#pragma unroll
        for (int b = 0; b < 4; ++b)
            bf[b] = *(const bf16x8*)&Bs[cur][(wn + b * 16 + lr) * 32 + lq * 8];
#pragma unroll
        for (int a = 0; a < 4; ++a)
#pragma unroll
            for (int b = 0; b < 4; ++b)
                acc[a][b] = __builtin_amdgcn_mfma_f32_16x16x32_bf16(af[a], bf[b], acc[a][b], 0, 0, 0);
        if (t == 1) {
            // expand done: pack to bf16 (matches old zg path precision), reset acc
#pragma unroll
            for (int a = 0; a < 4; ++a)
#pragma unroll
                for (int b = 0; b < 4; ++b) {
                    pk[a][b][0] = (uint)bfbits(acc[a][b][0]) | ((uint)bfbits(acc[a][b][1]) << 16);
                    pk[a][b][1] = (uint)bfbits(acc[a][b][2]) | ((uint)bfbits(acc[a][b][3]) << 16);
                    acc[a][b] = (f32x4){0.f, 0.f, 0.f, 0.f};
                }
        }
        cur ^= 1;
    }

    // epilogue: zg = silu(gate) * expand
#pragma unroll
    for (int a = 0; a < 4; ++a) {
#pragma unroll
        for (int b = 0; b < 4; ++b) {
            const int col = n0 + wn + b * 16 + lr;
            const float bn = bu[col];
#pragma unroll
            for (int r = 0; r < 4; ++r) {
                const int row = m0 + wm + a * 16 + lq * 4 + r;
                const ushort zu = (ushort)((r & 1) ? (pk[a][b][r >> 1] >> 16)
                                                   : (pk[a][b][r >> 1] & 0xffff));
                const float v = siluf(acc[a][b][r] + bn) * bf2f(zu);
                zg[(size_t)row * H_ + col] = bfbits(v);
            }
        }
    }
}

// ---------------------------------------------------------------------------
// Merged prep: blocks [0, 8192): x fp32 -> x16 + xT16; [8192, 9824): weight
// transposes; block 9824: zero sums[B*R] for pscore atomics.
// ---------------------------------------------------------------------------
__global__ __launch_bounds__(256) void xw_prep(
    const float* __restrict__ x, ushort* __restrict__ x16, ushort* __restrict__ xT16,
    const float* __restrict__ Wu, const float* __restrict__ Wo, const float* __restrict__ Wp,
    const float* __restrict__ Wq, const float* __restrict__ bq,
    const float* __restrict__ Wk, const float* __restrict__ bk,
    const float* __restrict__ Wv, const float* __restrict__ bv,
    ushort* __restrict__ Wut, ushort* __restrict__ Wot, ushort* __restrict__ Wpt,
    ushort* __restrict__ Wqkvt, float* __restrict__ bqkv, float* __restrict__ sums)
{
    __shared__ float tile[32][33];
    const int tx = threadIdx.x & 31, ty = threadIdx.x >> 5;   // 32x8
    int id = blockIdx.x;

    if (id == 8192 + 1632) {   // zero sums (512 floats)
        sums[threadIdx.x] = 0.f;
        sums[threadIdx.x + 256] = 0.f;
        return;
    }

    if (id < 8192) {   // x part: 16 x 512 tiles of 32x32
        const int c0 = (id & 15) * 32, l0 = (id >> 4) * 32;
#pragma unroll
        for (int i = 0; i < 32; i += 8) {
            const float v = x[(size_t)(l0 + ty + i) * C_ + c0 + tx];
            tile[ty + i][tx] = v;
            x16[(size_t)(l0 + ty + i) * C_ + c0 + tx] = bfbits(v);
        }
        __syncthreads();
        const int bb = l0 >> 11, ll0 = l0 & (L_ - 1);
#pragma unroll
        for (int i = 0; i < 32; i += 8)
            xT16[((size_t)bb * C_ + c0 + ty + i) * L_ + ll0 + tx] = bfbits(tile[tx][ty + i]);
        return;
    }
    id -= 8192;

    const float* W; ushort* Wt; const float* bsrc = nullptr;
    int K, Nloc, n0, k0, nn0;
    if (id < 512) {                 // Wu [512,1024] -> Wut [1024,512]
        W = Wu; Wt = Wut; K = 512; Nloc = 1024;
        n0 = (id & 31) * 32; k0 = (id >> 5) * 32; nn0 = n0;
    } else if (id < 1024) {         // Wo [1024,512] -> Wot [512,1024]
        id -= 512; W = Wo; Wt = Wot; K = 1024; Nloc = 512;
        n0 = (id & 15) * 32; k0 = (id >> 4) * 32; nn0 = n0;
    } else if (id < 1056) {         // Wp [512,64] -> Wpt [64,512]
        id -= 1024; W = Wp; Wt = Wpt; K = 512; Nloc = 64;
        n0 = (id & 1) * 32; k0 = (id >> 1) * 32; nn0 = n0;
    } else {                        // qkv: 36 x 16 tiles over [1152,512]
        id -= 1056; K = 512; Wt = Wqkvt;
        n0 = (id % 36) * 32; k0 = (id / 36) * 32;
        if (n0 < 64)       { W = Wq; bsrc = bq; Nloc = 64;   nn0 = n0; }
        else if (n0 < 128) { W = Wk; bsrc = bk; Nloc = 64;   nn0 = n0 - 64; }
        else               { W = Wv; bsrc = bv; Nloc = 1024; nn0 = n0 - 128; }
    }
#pragma unroll
    for (int i = 0; i < 32; i += 8)
        tile[ty + i][tx] = W[(size_t)(k0 + ty + i) * Nloc + nn0 + tx];
    __syncthreads();
#pragma unroll
    for (int i = 0; i < 32; i += 8)
        Wt[(size_t)(n0 + ty + i) * K + k0 + tx] = bfbits(tile[tx][ty + i]);
    if (bsrc && k0 == 0 && threadIdx.x < 32) bqkv[n0 + threadIdx.x] = bsrc[nn0 + threadIdx.x];
}

// px parts: K-split(8) MFMA compress. Tile 64(M=R) x 128(N), BK=32, 4 waves,
// grid dim3(C/128=4, B=8, 8) = 256 blocks. 3-buffer counted vmcnt(3).
// A = pALT (unnormalized exp bf16) — normalization applied in reduce.
__global__ __launch_bounds__(256) void compress_mfma(
    const ushort* __restrict__ pALT, const ushort* __restrict__ xT,
    float* __restrict__ parts)
{
    __shared__ ushort As[3][64 * 32];    // 3 x 4 KB
    __shared__ ushort Bs[3][128 * 32];   // 3 x 8 KB

    const int bidx = blockIdx.y;
    const int n0 = blockIdx.x * 128;
    const int ks = blockIdx.z;
    const int kbeg = ks * (L_ / 8), kend = kbeg + L_ / 8;
    const int tid = threadIdx.x;
    const int lane = tid & 63, w = tid >> 6;          // 4 waves
    const int lr = lane & 15, lq = lane >> 4;
    const int sr = lane >> 2, sc = (lane & 3) * 8;
    const int wm = (w & 1) * 32, wn = (w >> 1) * 64;

    const ushort* Ab = pALT + (size_t)bidx * R_ * L_;
    const ushort* Bb = xT + (size_t)bidx * C_ * L_;

    const ushort* ap  = Ab + (size_t)(w * 16 + sr) * L_ + sc;              // A seg w (4)
    const ushort* b0p = Bb + (size_t)(n0 + (2 * w) * 16 + sr) * L_ + sc;   // B segs 2w, 2w+1
    const ushort* b1p = Bb + (size_t)(n0 + (2 * w + 1) * 16 + sr) * L_ + sc;
    const int alo  = w * 512 + lane * 8;
    const int blo0 = (2 * w) * 512 + lane * 8;
    const int blo1 = (2 * w + 1) * 512 + lane * 8;

    auto stage = [&](int k0, int bsel) {
        glds16(ap + k0, &As[bsel][alo]);
        glds16(b0p + k0, &Bs[bsel][blo0]);
        glds16(b1p + k0, &Bs[bsel][blo1]);
    };

    f32x4 acc[2][4];
#pragma unroll
    for (int a = 0; a < 2; ++a)
#pragma unroll
        for (int b = 0; b < 4; ++b) acc[a][b] = (f32x4){0.f, 0.f, 0.f, 0.f};

    stage(kbeg, 0);
    stage(kbeg + 32, 1);

    int cur = 0;
    for (int k0 = kbeg; k0 < kend; k0 += 32) {
        if (k0 + 32 < kend) VMCNT(3); else VMCNT(0);
        BARRIER();
        if (k0 + 64 < kend) stage(k0 + 64, cur ? cur - 1 : 2);
        bf16x8 af[2], bf[4];
#pragma unroll
        for (int a = 0; a < 2; ++a)
            af[a] = *(const bf16x8*)&As[cur][(wm + a * 16 + lr) * 32 + lq * 8];
#pragma unroll
        for (int b = 0; b < 4; ++b)
            bf[b] = *(const bf16x8*)&Bs[cur][(wn + b * 16 + lr) * 32 + lq * 8];
#pragma unroll
        for (int a = 0; a < 2; ++a)
#pragma unroll
            for (int b = 0; b < 4; ++b)
                acc[a][b] = __builtin_amdgcn_mfma_f32_16x16x32_bf16(af[a], bf[b], acc[a][b], 0, 0, 0);
        cur = (cur == 2) ? 0 : cur + 1;
    }
#pragma unroll
    for (int a = 0; a < 2; ++a)
#pragma unroll
        for (int b = 0; b < 4; ++b)
#pragma unroll
            for (int r = 0; r < 4; ++r) {
                const int row = wm + a * 16 + lq * 4 + r;
                const int col = n0 + wn + b * 16 + lr;
                parts[(((size_t)ks * B_ + bidx) * R_ + row) * C_ + col] = acc[a][b][r];
            }
}

// reduce 8 K-split parts -> px16 bf16, applying 1/sums[row] (L-softmax norm)
__global__ __launch_bounds__(256) void compress_reduce16(const float* __restrict__ parts,
                                                         const float* __restrict__ sums,
                                                         ushort* __restrict__ px16)
{
    const size_t i = ((size_t)blockIdx.x * 256 + threadIdx.x) * 4;
    constexpr size_t S = (size_t)B_ * R_ * C_;
    float4 s = *(const float4*)(parts + i);
#pragma unroll
    for (int k = 1; k < 8; ++k) {
        const float4 p = *(const float4*)(parts + i + (size_t)k * S);
        s.x += p.x; s.y += p.y; s.z += p.z; s.w += p.w;
    }
    const float inv = 1.0f / sums[i / C_];
    ushort4 o;
    o.x = bfbits(s.x * inv); o.y = bfbits(s.y * inv);
    o.z = bfbits(s.z * inv); o.w = bfbits(s.w * inv);
    *(ushort4*)(px16 + i) = o;
}

// fused scores+softmax+z from bf16 qkv16 [B*R, 1152] (q|k|v concat)
__global__ __launch_bounds__(256) void attn_fused(
    const ushort* __restrict__ qkv, const float* __restrict__ preS,
    ushort* __restrict__ zsT)
{
    const int b = blockIdx.x >> 6, r = blockIdx.x & 63;
    const int t = threadIdx.x;
    __shared__ float al[R_];
    if (t < 64) {
        const ushort* qr = qkv + (size_t)(b * R_ + r) * NQKV_;
        const ushort* ks = qkv + (size_t)(b * R_ + t) * NQKV_ + 64;
        float acc = 0.f;
#pragma unroll
        for (int d = 0; d < DK_; d += 4) {
            const ushort4 qa = *(const ushort4*)(qr + d);
            const ushort4 ka = *(const ushort4*)(ks + d);
            acc += bf2f(qa.x) * bf2f(ka.x) + bf2f(qa.y) * bf2f(ka.y)
                 + bf2f(qa.z) * bf2f(ka.z) + bf2f(qa.w) * bf2f(ka.w);
        }
        acc = acc * 0.125f + preS[((size_t)b * R_ + r) * R_ + t];
        float mx = acc;
#pragma unroll
        for (int o = 32; o > 0; o >>= 1) mx = fmaxf(mx, __shfl_xor(mx, o, 64));
        float e = __expf(acc - mx);
        float sm = e;
#pragma unroll
        for (int o = 32; o > 0; o >>= 1) sm += __shfl_xor(sm, o, 64);
        al[t] = e / sm;
    }
    __syncthreads();
    float acc[4] = {};
    for (int s = 0; s < R_; ++s) {
        const float a = al[s];
        const ushort* vr = qkv + (size_t)(b * R_ + s) * NQKV_ + 128;
#pragma unroll
        for (int j = 0; j < 4; ++j) acc[j] += a * bf2f(vr[t + j * 256]);
    }
#pragma unroll
    for (int j = 0; j < 4; ++j) {
        const int h = t + j * 256;
        zsT[((size_t)b * H_ + h) * R_ + r] = bfbits(acc[j]);
    }
}

// Row layernorm, wave-per-row: 4 rows/block, shuffle-only reduce (no LDS).
__global__ __launch_bounds__(256) void layernorm(const ushort* __restrict__ y,
                                                 const float* __restrict__ gamma,
                                                 const float* __restrict__ beta,
                                                 float* __restrict__ out)
{
    const int w = threadIdx.x >> 6, lane = threadIdx.x & 63;
    const size_t m = (size_t)blockIdx.x * 4 + w;
    const ushort* yr = y + m * C_ + lane * 8;
    const ushort4 p0 = *(const ushort4*)(yr);
    const ushort4 p1 = *(const ushort4*)(yr + 4);
    float v[8] = { bf2f(p0.x), bf2f(p0.y), bf2f(p0.z), bf2f(p0.w),
                   bf2f(p1.x), bf2f(p1.y), bf2f(p1.z), bf2f(p1.w) };
    float s = 0.f, q = 0.f;
#pragma unroll
    for (int j = 0; j < 8; ++j) { s += v[j]; q += v[j] * v[j]; }
#pragma unroll
    for (int o = 32; o > 0; o >>= 1) {
        s += __shfl_xor(s, o, 64);
        q += __shfl_xor(q, o, 64);
    }
    const float mu = s * (1.0f / C_);
    const float var = q * (1.0f / C_) - mu * mu;
    const float inv = rsqrtf(var + 1e-5f);
    const float4 g0 = *(const float4*)(gamma + lane * 8);
    const float4 g1 = *(const float4*)(gamma + lane * 8 + 4);
    const float4 b0 = *(const float4*)(beta + lane * 8);
    const float4 b1 = *(const float4*)(beta + lane * 8 + 4);
    float4 o0, o1;
    o0.x = (v[0] - mu) * inv * g0.x + b0.x;
    o0.y = (v[1] - mu) * inv * g0.y + b0.y;
    o0.z = (v[2] - mu) * inv * g0.z + b0.z;
    o0.w = (v[3] - mu) * inv * g0.w + b0.w;
    o1.x = (v[4] - mu) * inv * g1.x + b1.x;
    o1.y = (v[5] - mu) * inv * g1.y + b1.y;
    o1.z = (v[6] - mu) * inv * g1.z + b1.z;
    o1.w = (v[7] - mu) * inv * g1.w + b1.w;
    *(float4*)(out + m * C_ + lane * 8) = o0;
    *(float4*)(out + m * C_ + lane * 8 + 4) = o1;
}

// ---- compact-path SIMT kernels (dead in practice, kept for safety) ----
template <typename AT, typename BT, typename RT, int ACT, int EPI>
__global__ __launch_bounds__(256) void gemm64(
    const AT* __restrict__ A, const BT* __restrict__ Bw,
    const float* __restrict__ bias, const int* __restrict__ mask,
    const RT* resid, float* __restrict__ outF, __hip_bfloat16* outB,
    int Ndim, int Kdim, long bBatchStride)
{
    __shared__ float As[16][68];
    __shared__ float Bs[16][64];
    const int tid = threadIdx.x;
    const int tx = tid & 15, ty = tid >> 4;
    const int n0 = blockIdx.x * 64, m0 = blockIdx.y * 64;
    const BT* Bp = Bw + (bBatchStride ? (long)(m0 / L_) * bBatchStride : 0);
    float acc[4][4] = {};
    for (int k0 = 0; k0 < Kdim; k0 += 16) {
#pragma unroll
        for (int s = 0; s < 4; ++s) {
            int idx = tid + s * 256;
            int am = idx >> 4, ak = idx & 15;
            As[ak][am] = toF(A[(size_t)(m0 + am) * Kdim + k0 + ak]);
        }
#pragma unroll
        for (int s = 0; s < 4; ++s) {
            int idx = tid + s * 256;
            int bk = idx >> 6, bn = idx & 63;
            Bs[bk][bn] = toF(Bp[(size_t)(k0 + bk) * Ndim + n0 + bn]);
        }
        __syncthreads();
#pragma unroll
        for (int kk = 0; kk < 16; ++kk) {
            float av[4], bv[4];
            *(float4*)av = *(const float4*)&As[kk][ty * 4];
            *(float4*)bv = *(const float4*)&Bs[kk][tx * 4];
#pragma unroll
            for (int i = 0; i < 4; ++i)
#pragma unroll
                for (int j = 0; j < 4; ++j) acc[i][j] += av[i] * bv[j];
        }
        __syncthreads();
    }
#pragma unroll
    for (int i = 0; i < 4; ++i) {
        int m = m0 + ty * 4 + i;
#pragma unroll
        for (int j = 0; j < 4; ++j) {
            int n = n0 + tx * 4 + j;
            float val = acc[i][j];
            if (EPI != 3) val += bias[n];
            if (ACT) val = siluf(val);
            if (EPI == 0) outB[(size_t)m * Ndim + n] = __float2bfloat16(val);
            else if (EPI == 1) { if (mask[m] == 0) val = NEG_; outF[(size_t)m * Ndim + n] = val; }
            else if (EPI == 2) { val += toF(resid[(size_t)m * Ndim + n]); outB[(size_t)m * Ndim + n] = __float2bfloat16(val); }
            else { val *= toF(resid[(size_t)m * Ndim + n]); outB[(size_t)m * Ndim + n] = __float2bfloat16(val); }
        }
    }
}

template <int OUT>
__global__ __launch_bounds__(64) void softmaxR(const float* __restrict__ pScore,
                                               float* __restrict__ outF,
                                               ushort* __restrict__ outU)
{
    const size_t m = blockIdx.x;
    const int t = threadIdx.x;
    float v = pScore[m * R_ + t];
    float mx = v;
#pragma unroll
    for (int o = 32; o > 0; o >>= 1) mx = fmaxf(mx, __shfl_xor(mx, o, 64));
    float e = __expf(v - mx);
    float s = e;
#pragma unroll
    for (int o = 32; o > 0; o >>= 1) s += __shfl_xor(s, o, 64);
    if (OUT == 0) outF[m * R_ + t] = e / s;
    else          outU[m * R_ + t] = bfbits(e / s);
}

__global__ __launch_bounds__(256) void softmaxL(const float* __restrict__ pScore,
                                                float* __restrict__ pAlpha)
{
    const int b = blockIdx.x >> 6, r = blockIdx.x & 63;
    const int t = threadIdx.x;
    const float* base = pScore + (size_t)b * L_ * R_ + r;
    float* out = pAlpha + (size_t)b * L_ * R_ + r;
    __shared__ float red[256];
    float mx = -3.4e38f;
    for (int l = t; l < L_; l += 256) mx = fmaxf(mx, base[(size_t)l * R_]);
    red[t] = mx; __syncthreads();
    for (int s = 128; s > 0; s >>= 1) { if (t < s) red[t] = fmaxf(red[t], red[t + s]); __syncthreads(); }
    mx = red[0]; __syncthreads();
    float sum = 0.f;
    for (int l = t; l < L_; l += 256) {
        float e = __expf(base[(size_t)l * R_] - mx);
        out[(size_t)l * R_] = e; sum += e;
    }
    red[t] = sum; __syncthreads();
    for (int s = 128; s > 0; s >>= 1) { if (t < s) red[t] += red[t + s]; __syncthreads(); }
    const float inv = 1.0f / red[0];
    for (int l = t; l < L_; l += 256) out[(size_t)l * R_] *= inv;
}

__global__ __launch_bounds__(256) void compress_part(
    const float* __restrict__ pAlpha, const float* __restrict__ x,
    float* __restrict__ parts)
{
    __shared__ float As[16][64];
    __shared__ float Bs[16][64];
    const int tid = threadIdx.x;
    const int tx = tid & 15, ty = tid >> 4;
    const int n0 = blockIdx.x * 64;
    const int ks = blockIdx.y;
    const int b  = blockIdx.z;
    const float* pa = pAlpha + (size_t)b * L_ * R_;
    const float* xb = x + (size_t)b * L_ * C_;
    float acc[4][4] = {};
    const int kbeg = ks * (L_ / 4), kend = kbeg + L_ / 4;
    for (int k0 = kbeg; k0 < kend; k0 += 16) {
#pragma unroll
        for (int s = 0; s < 4; ++s) {
            int idx = tid + s * 256;
            int kk = idx >> 6, m = idx & 63;
            As[kk][m] = pa[(size_t)(k0 + kk) * R_ + m];
        }
#pragma unroll
        for (int s = 0; s < 4; ++s) {
            int idx = tid + s * 256;
            int kk = idx >> 6, n = idx & 63;
            Bs[kk][n] = xb[(size_t)(k0 + kk) * C_ + n0 + n];
        }
        __syncthreads();
#pragma unroll
        for (int kk = 0; kk < 16; ++kk) {
            float av[4], bv[4];
            *(float4*)av = *(const float4*)&As[kk][ty * 4];
            *(float4*)bv = *(const float4*)&Bs[kk][tx * 4];
#pragma unroll
            for (int i = 0; i < 4; ++i)
#pragma unroll
                for (int j = 0; j < 4; ++j) acc[i][j] += av[i] * bv[j];
        }
        __syncthreads();
    }
#pragma unroll
    for (int i = 0; i < 4; ++i)
#pragma unroll
        for (int j = 0; j < 4; ++j)
            parts[((((size_t)ks * B_ + b) * R_) + ty * 4 + i) * C_ + n0 + tx * 4 + j] = acc[i][j];
}

__global__ __launch_bounds__(256) void compress_reduce(const float* __restrict__ parts,
                                                       float* __restrict__ px)
{
    const size_t i = (size_t)blockIdx.x * 256 + threadIdx.x;
    constexpr size_t S = (size_t)B_ * R_ * C_;
    px[i] = parts[i] + parts[i + S] + parts[i + 2 * S] + parts[i + 3 * S];
}

__global__ __launch_bounds__(256) void qkv_gemm(
    const float* __restrict__ px,
    const float* __restrict__ Wq, const float* __restrict__ bq,
    const float* __restrict__ Wk, const float* __restrict__ bk,
    const float* __restrict__ Wv, const float* __restrict__ bv,
    float* __restrict__ q, float* __restrict__ k, float* __restrict__ v)
{
    __shared__ float As[16][68];
    __shared__ float Bs[16][64];
    const int tid = threadIdx.x;
    const int tx = tid & 15, ty = tid >> 4;
    const int bx = blockIdx.x;
    const int m0 = blockIdx.y * 64;
    const float* W; const float* bias; float* dst; int Nloc, ncol0;
    if (bx == 0)      { W = Wq; bias = bq; dst = q; Nloc = 64;   ncol0 = 0; }
    else if (bx == 1) { W = Wk; bias = bk; dst = k; Nloc = 64;   ncol0 = 0; }
    else              { W = Wv; bias = bv; dst = v; Nloc = H_;   ncol0 = (bx - 2) * 64; }

    float acc[4][4] = {};
    for (int k0 = 0; k0 < C_; k0 += 16) {
#pragma unroll
        for (int s = 0; s < 4; ++s) {
            int idx = tid + s * 256;
            int am = idx >> 4, ak = idx & 15;
            As[ak][am] = px[(size_t)(m0 + am) * C_ + k0 + ak];
        }
#pragma unroll
        for (int s = 0; s < 4; ++s) {
            int idx = tid + s * 256;
            int kk = idx >> 6, bn = idx & 63;
            Bs[kk][bn] = W[(size_t)(k0 + kk) * Nloc + ncol0 + bn];
        }
        __syncthreads();
#pragma unroll
        for (int kk = 0; kk < 16; ++kk) {
            float av[4], bv4[4];
            *(float4*)av = *(const float4*)&As[kk][ty * 4];
            *(float4*)bv4 = *(const float4*)&Bs[kk][tx * 4];
#pragma unroll
            for (int i = 0; i < 4; ++i)
#pragma unroll
                for (int j = 0; j < 4; ++j) acc[i][j] += av[i] * bv4[j];
        }
        __syncthreads();
    }
#pragma unroll
    for (int i = 0; i < 4; ++i) {
        int m = m0 + ty * 4 + i;
#pragma unroll
        for (int j = 0; j < 4; ++j) {
            int n = ncol0 + tx * 4 + j;
            dst[(size_t)m * Nloc + n] = siluf(acc[i][j] + bias[n]);
        }
    }
}

template <int MODE>
__global__ __launch_bounds__(256) void attn_z(const float* __restrict__ alpha,
                                              const float* __restrict__ v,
                                              float* __restrict__ zsF,
                                              ushort* __restrict__ zsT)
{
    const int b = blockIdx.x >> 6, r = blockIdx.x & 63;
    const int t = threadIdx.x;
    __shared__ float al[R_];
    if (t < R_) al[t] = alpha[((size_t)b * R_ + r) * R_ + t];
    __syncthreads();
    float acc[4] = {};
    for (int s = 0; s < R_; ++s) {
        float a = al[s];
        const float* vr = v + ((size_t)b * R_ + s) * H_;
#pragma unroll
        for (int j = 0; j < 4; ++j) acc[j] += a * vr[t + j * 256];
    }
#pragma unroll
    for (int j = 0; j < 4; ++j) {
        const int h = t + j * 256;
        if (MODE == 0) zsF[((size_t)b * R_ + r) * H_ + h] = acc[j];
        else           zsT[((size_t)b * H_ + h) * R_ + r] = bfbits(acc[j]);
    }
}

__global__ __launch_bounds__(64) void attn_scores(
    const float* __restrict__ q, const float* __restrict__ k,
    const float* __restrict__ preS, float* __restrict__ alpha)
{
    const int b = blockIdx.x >> 6, r = blockIdx.x & 63;
    const int s = threadIdx.x;
    const float* qr = q + ((size_t)b * R_ + r) * DK_;
    const float* ks = k + ((size_t)b * R_ + s) * DK_;
    float acc = 0.f;
#pragma unroll
    for (int d = 0; d < DK_; ++d) acc += qr[d] * ks[d];
    acc = acc * 0.125f + preS[((size_t)b * R_ + r) * R_ + s];
    float mx = acc;
#pragma unroll
    for (int o = 32; o > 0; o >>= 1) mx = fmaxf(mx, __shfl_xor(mx, o, 64));
    float e = __expf(acc - mx);
    float sm = e;
#pragma unroll
    for (int o = 32; o > 0; o >>= 1) sm += __shfl_xor(sm, o, 64);
    alpha[((size_t)b * R_ + r) * R_ + s] = e / sm;
}

extern "C" void kernel_launch(void* const* d_in, const int* in_sizes, int n_in,
                              void* d_out, int out_size, void* d_ws, size_t ws_size,
                              hipStream_t stream)
{
    using bf16 = __hip_bfloat16;
    const float* x      = (const float*)d_in[0];
    const int*  maskPAD = (const int*)d_in[1];
    const float* preS   = (const float*)d_in[2];
    const float* Wp     = (const float*)d_in[3];
    const float* bp     = (const float*)d_in[4];
    const float* Wq     = (const float*)d_in[5];
    const float* bq     = (const float*)d_in[6];
    const float* Wk     = (const float*)d_in[7];
    const float* bk     = (const float*)d_in[8];
    const float* Wv     = (const float*)d_in[9];
    const float* bv     = (const float*)d_in[10];
    const float* Wu     = (const float*)d_in[11];
    const float* bu     = (const float*)d_in[12];
    const float* Wo     = (const float*)d_in[13];
    const float* bo     = (const float*)d_in[14];
    const float* gamma  = (const float*)d_in[15];
    const float* beta   = (const float*)d_in[16];
    float* out          = (float*)d_out;

    char* ws = (char*)d_ws;
    const bool bigWS = ws_size >= (size_t)52 * 1024 * 1024;  // proven taken

    if (bigWS) {
        // layout: zg 33.5 MB | pool 18.2 MB | Wut | Wot | Wpt
        bf16* zg = (bf16*)ws;                                   // M*H bf16 (written by fused_gate_z)
        float* parts = (float*)ws;                              // 8 MB K-split parts (dead before zg)
        char* pool = ws + (size_t)M_ * H_ * 2;
        ushort* pALT   = (ushort*)pool;                         // B*R*L bf16 exp (2 MB)
        ushort* pAR16  = pALT + (size_t)B_ * R_ * L_;           // M*R bf16 (2 MB)
        ushort* px16   = pAR16 + (size_t)M_ * R_;               // B*R*C bf16 (0.5 MB)
        ushort* qkv16  = px16 + (size_t)B_ * R_ * C_;           // B*R*1152 bf16 (1.19 MB)
        ushort* zsT16  = qkv16 + (size_t)B_ * R_ * NQKV_;       // B*H*R bf16 (1 MB)
        ushort* Wqkvt  = zsT16 + (size_t)B_ * H_ * R_;          // [1152, C] bf16 (1.13 MB)
        float*  bqkv   = (float*)(Wqkvt + (size_t)NQKV_ * C_);  // 4.6 KB
        float*  sums   = bqkv + NQKV_;                          // B*R exp-sums (2 KB)
        bf16*  y       = (bf16*)pool;                           // pre-LN y (16.8 MB), pool dead
        ushort* Wut    = (ushort*)(pool + 18221568);            // [H, C] bf16
        ushort* Wot    = Wut + (size_t)C_ * H_;                 // [C, H] bf16
        ushort* Wpt    = Wot + (size_t)C_ * H_;                 // [R, C] bf16
        ushort* x16    = (ushort*)d_out;                        // [M, C] bf16 (dead before LN)
        ushort* xT16   = x16 + (size_t)M_ * C_;                 // [B, C, L] bf16 (in d_out)

        // 1) prep: x->bf16 (+transpose), weight transposes, zero sums
        xw_prep<<<8192 + 1632 + 1, 256, 0, stream>>>(
            x, x16, xT16, Wu, Wo, Wp, Wq, bq, Wk, bk, Wv, bv,
            Wut, Wot, Wpt, Wqkvt, bqkv, sums);
        // 2) pScore GEMM + fused r-softmax + unnorm exp + col-sum atomics
        pscore_gemm<<<M_ / 64, 256, 0, stream>>>(x16, Wpt, bp, maskPAD,
                                                 pAR16, pALT, sums);
        // 3) px = (exp @ x) / sums  (MFMA K-split x8 -> parts -> scaled bf16)
        compress_mfma<<<dim3(C_ / 128, B_, 8), 256, 0, stream>>>(pALT, xT16, parts);
        compress_reduce16<<<(B_ * R_ * C_) / 1024, 256, 0, stream>>>(parts, sums, px16);
        // 4) q|k|v = silu(px @ Wqkv + b)  (64x64 tiles, grid 144)
        qkv64<<<(B_ * R_ / 64) * (NQKV_ / 64), 256, 0, stream>>>(px16, Wqkvt, bqkv, qkv16);
        attn_fused<<<B_ * R_, 256, 0, stream>>>(qkv16, preS, zsT16);
        // 5) zg = silu(x@Wu+bu) * (pAR @ zsT)   [256x128 tile, 8 waves, 2-buf]
        fused_gate_z<<<(H_ / 128) * (M_ / 256), 512, 0, stream>>>(
            x16, Wut, bu, pAR16, zsT16, (ushort*)zg);
        // 6) y = x + zg @ Wo + bo   [128^2 3-buf counted, grid 512 = 2/CU]
        mfma_gemm5<2><<<(C_ / 128) * (M_ / 128), 256, 0, stream>>>(
            (ushort*)zg, Wot, bo, x, nullptr, nullptr, (ushort*)y, nullptr, nullptr,
            C_, H_, C_ / 128, 0);
        layernorm<<<M_ / 4, 256, 0, stream>>>((const ushort*)y, gamma, beta, out);
    } else {
        // ---- Compact plan (~23.4 MiB), SIMT per-batch (dead in practice) ----
        float* pScore = (float*)ws;
        float* pAL   = pScore + (size_t)M_ * R_;
        float* pAR   = pAL    + (size_t)M_ * R_;
        float* px    = pAR    + (size_t)M_ * R_;
        float* q     = px     + (size_t)B_ * R_ * C_;
        float* kk    = q      + (size_t)B_ * R_ * DK_;
        float* vv    = kk     + (size_t)B_ * R_ * DK_;
        float* alpha = vv     + (size_t)B_ * R_ * H_;
        float* zs    = alpha  + (size_t)B_ * R_ * R_;
        bf16* gate_b = (bf16*)(zs + (size_t)B_ * R_ * H_);
        bf16* y_b    = (bf16*)((char*)gate_b + (size_t)L_ * H_ * 2);

        gemm64<float, float, float, 0, 1><<<dim3(R_ / 64, M_ / 64), 256, 0, stream>>>(
            x, Wp, bp, maskPAD, (const float*)nullptr, pScore, nullptr, R_, C_, 0);
        softmaxL<<<B_ * R_, 256, 0, stream>>>(pScore, pAL);
        softmaxR<0><<<M_, 64, 0, stream>>>(pScore, pAR, nullptr);
        compress_part<<<dim3(C_ / 64, 4, B_), 256, 0, stream>>>(pAL, x, pScore);
        compress_reduce<<<(B_ * R_ * C_) / 256, 256, 0, stream>>>(pScore, px);
        qkv_gemm<<<dim3(2 + H_ / 64, (B_ * R_) / 64), 256, 0, stream>>>(
            px, Wq, bq, Wk, bk, Wv, bv, q, kk, vv);
        attn_scores<<<B_ * R_, 64, 0, stream>>>(q, kk, preS, alpha);
        attn_z<0><<<B_ * R_, 256, 0, stream>>>(alpha, vv, zs, nullptr);

        for (int b = 0; b < B_; ++b) {
            const float* xb = x + (size_t)b * L_ * C_;
            gemm64<float, float, float, 1, 0><<<dim3(H_ / 64, L_ / 64), 256, 0, stream>>>(
                xb, Wu, bu, nullptr, (const float*)nullptr, nullptr, gate_b, H_, C_, 0);
            gemm64<float, float, bf16, 0, 3><<<dim3(H_ / 64, L_ / 64), 256, 0, stream>>>(
                pAR + (size_t)b * L_ * R_, zs + (size_t)b * R_ * H_,
                nullptr, nullptr, gate_b, nullptr, gate_b, H_, R_, 0);
            gemm64<bf16, float, float, 0, 2><<<dim3(C_ / 64, L_ / 64), 256, 0, stream>>>(
                gate_b, Wo, bo, nullptr, xb, nullptr, y_b, C_, H_, 0);
            layernorm<<<L_ / 4, 256, 0, stream>>>((const ushort*)y_b, gamma, beta, out + (size_t)b * L_ * C_);
        }
    }
}

// Round 11
// 243.602 us; speedup vs baseline: 1.1723x; 1.0129x over previous
//
#include <hip/hip_runtime.h>
#include <hip/hip_bf16.h>

// Problem constants
constexpr int B_ = 8;
constexpr int L_ = 2048;
constexpr int C_ = 512;
constexpr int R_ = 64;
constexpr int DK_ = 64;
constexpr int H_ = 1024;   // 2*C
constexpr int M_ = B_ * L_;  // 16384
constexpr int NQKV_ = 1152;  // 64 + 64 + 1024 (q|k|v concat)
constexpr float NEG_ = -32767.0f;

__device__ __forceinline__ float toF(float x) { return x; }
__device__ __forceinline__ float toF(__hip_bfloat16 x) { return __bfloat162float(x); }
__device__ __forceinline__ float siluf(float v) { return v / (1.0f + __expf(-v)); }
__device__ __forceinline__ ushort bfbits(float f) {
    __hip_bfloat16 h = __float2bfloat16(f);
    union { __hip_bfloat16 h; ushort u; } cv; cv.h = h; return cv.u;
}
__device__ __forceinline__ float bf2f(ushort u) {
    union { uint u; float f; } cv; cv.u = (uint)u << 16; return cv.f;
}

typedef __attribute__((ext_vector_type(8))) short bf16x8;   // 8 bf16 (4 VGPRs)
typedef __attribute__((ext_vector_type(4))) float f32x4;    // 4 fp32 acc

#define GLOBAL_AS __attribute__((address_space(1)))
#define LDS_AS    __attribute__((address_space(3)))
__device__ __forceinline__ void glds16(const ushort* g, ushort* l) {
    __builtin_amdgcn_global_load_lds((const GLOBAL_AS void*)g, (LDS_AS void*)l, 16, 0, 0);
}

// counted-vmcnt + raw barrier helpers (T4): loads stay in flight across barriers.
#define VMCNT(n) asm volatile("s_waitcnt vmcnt(" #n ")" ::: "memory")
#define BARRIER() do { __builtin_amdgcn_s_barrier(); asm volatile("" ::: "memory"); } while (0)

// ---------------------------------------------------------------------------
// MFMA bf16 GEMM, 128x128 tile, BK=32, 4 waves (2x2 of 64x64).
// 3-buffer, 2-deep prefetch, counted vmcnt(4). Used for Wo (EPI 2, grid 512).
// ---------------------------------------------------------------------------
template <int EPI>
__global__ __launch_bounds__(256) void mfma_gemm5(
    const ushort* __restrict__ A, const ushort* __restrict__ Bt,
    const float* __restrict__ bias,
    const float* __restrict__ residF, const ushort* __restrict__ residB,
    const int* __restrict__ mask,
    ushort* __restrict__ outB, float* __restrict__ outF, float* __restrict__ outF2,
    int Ndim, int Kdim, int gridN, long bBatch)
{
    __shared__ ushort As[3][128 * 32];   // 3 x 8 KB
    __shared__ ushort Bs[3][128 * 32];

    const int i = blockIdx.x;
    const int G = gridDim.x >> 3;        // blocks per XCD
    const int gi = (gridDim.x & 7) ? i : ((i & 7) * G + (i >> 3));
    const int nt = gi % gridN, mt = gi / gridN;
    const int m0 = mt * 128, n0 = nt * 128;

    const int tid = threadIdx.x;
    const int lane = tid & 63, w = tid >> 6;
    const int wm = (w & 1) * 64, wn = (w >> 1) * 64;
    const int lr = lane & 15, lq = lane >> 4;

    const int sr = lane >> 2;
    const int sc = (lane & 3) * 8;
    const int s0 = w * 2, s1 = w * 2 + 1;

    const ushort* Bp = Bt + (bBatch ? (long)(m0 / L_) * bBatch : 0);
    int br0 = n0 + s0 * 16 + sr; if (br0 >= Ndim) br0 = Ndim - 1;   // clamp (N<128)
    int br1 = n0 + s1 * 16 + sr; if (br1 >= Ndim) br1 = Ndim - 1;
    const ushort* a0p = A  + (size_t)(m0 + s0 * 16 + sr) * Kdim + sc;
    const ushort* a1p = A  + (size_t)(m0 + s1 * 16 + sr) * Kdim + sc;
    const ushort* b0p = Bp + (size_t)br0 * Kdim + sc;
    const ushort* b1p = Bp + (size_t)br1 * Kdim + sc;
    const int lo0 = s0 * 512 + lane * 8;
    const int lo1 = s1 * 512 + lane * 8;

    f32x4 acc[4][4];
#pragma unroll
    for (int a = 0; a < 4; ++a)
#pragma unroll
        for (int b = 0; b < 4; ++b) acc[a][b] = (f32x4){0.f, 0.f, 0.f, 0.f};

    glds16(a0p, &As[0][lo0]);
    glds16(a1p, &As[0][lo1]);
    glds16(b0p, &Bs[0][lo0]);
    glds16(b1p, &Bs[0][lo1]);
    if (32 < Kdim) {
        glds16(a0p + 32, &As[1][lo0]);
        glds16(a1p + 32, &As[1][lo1]);
        glds16(b0p + 32, &Bs[1][lo0]);
        glds16(b1p + 32, &Bs[1][lo1]);
    }

    int cur = 0;
    for (int k0 = 0; k0 < Kdim; k0 += 32) {
        if (k0 + 32 < Kdim) VMCNT(4); else VMCNT(0);
        BARRIER();
        if (k0 + 64 < Kdim) {
            const int nx = cur ? cur - 1 : 2;   // (cur+2)%3
            glds16(a0p + k0 + 64, &As[nx][lo0]);
            glds16(a1p + k0 + 64, &As[nx][lo1]);
            glds16(b0p + k0 + 64, &Bs[nx][lo0]);
            glds16(b1p + k0 + 64, &Bs[nx][lo1]);
        }
        bf16x8 af[4], bf[4];
#pragma unroll
        for (int a = 0; a < 4; ++a)
            af[a] = *(const bf16x8*)&As[cur][(wm + a * 16 + lr) * 32 + lq * 8];
#pragma unroll
        for (int b = 0; b < 4; ++b)
            bf[b] = *(const bf16x8*)&Bs[cur][(wn + b * 16 + lr) * 32 + lq * 8];
#pragma unroll
        for (int a = 0; a < 4; ++a)
#pragma unroll
            for (int b = 0; b < 4; ++b)
                acc[a][b] = __builtin_amdgcn_mfma_f32_16x16x32_bf16(af[a], bf[b], acc[a][b], 0, 0, 0);
        cur = (cur == 2) ? 0 : cur + 1;
    }

#pragma unroll
    for (int a = 0; a < 4; ++a) {
#pragma unroll
        for (int b = 0; b < 4; ++b) {
            const int col = n0 + wn + b * 16 + lr;
            if (col < Ndim) {
                const float bn = (EPI == 3) ? 0.f : bias[col];
#pragma unroll
                for (int r = 0; r < 4; ++r) {
                    const int row = m0 + wm + a * 16 + lq * 4 + r;
                    float v = acc[a][b][r];
                    if (EPI == 0) {
                        v = siluf(v + bn);
                        outB[(size_t)row * Ndim + col] = bfbits(v);
                    } else if (EPI == 2) {
                        v += bn + residF[(size_t)row * Ndim + col];
                        outB[(size_t)row * Ndim + col] = bfbits(v);
                    } else {
                        v *= bf2f(residB[(size_t)row * Ndim + col]);
                        outB[(size_t)row * Ndim + col] = bfbits(v);
                    }
                }
            }
        }
    }
}

// ---------------------------------------------------------------------------
// pScore GEMM: tile 64(M) x 64(N), K=C=512, 4 waves each 16(M)x64(N).
// grid 256 (1 block/CU). 3-buffer counted vmcnt(2).
// Fused epilogue:
//  - r-softmax (max-sub, 16-lane shfl) -> pAR16 bf16     [dead rows -> 1/64]
//  - L-path: pALT = bf16(exp(score)) UNNORMALIZED + col-sum atomics.
// ---------------------------------------------------------------------------
__global__ __launch_bounds__(256) void pscore_gemm(
    const ushort* __restrict__ x16, const ushort* __restrict__ Wpt,
    const float* __restrict__ bp, const int* __restrict__ mask,
    ushort* __restrict__ pAR16, ushort* __restrict__ pALT,
    float* __restrict__ sums)
{
    __shared__ ushort As[3][64 * 32];   // 3 x 4 KB
    __shared__ ushort Bs[3][64 * 32];   // 3 x 4 KB

    const int i = blockIdx.x;
    const int G = gridDim.x >> 3;
    const int gi = (i & 7) * G + (i >> 3);   // grid = 256, %8==0
    const int m0 = gi * 64;

    const int tid = threadIdx.x;
    const int lane = tid & 63, w = tid >> 6;
    const int lr = lane & 15, lq = lane >> 4;
    const int sr = lane >> 2, sc = (lane & 3) * 8;

    const ushort* ap  = x16 + (size_t)(m0 + w * 16 + sr) * C_ + sc;   // A seg w
    const ushort* bwp = Wpt + (size_t)(w * 16 + sr) * C_ + sc;        // B seg w
    const int loa = w * 512 + lane * 8;

    f32x4 acc[4];
#pragma unroll
    for (int b = 0; b < 4; ++b) acc[b] = (f32x4){0.f, 0.f, 0.f, 0.f};

    glds16(ap, &As[0][loa]);
    glds16(bwp, &Bs[0][loa]);
    glds16(ap + 32, &As[1][loa]);
    glds16(bwp + 32, &Bs[1][loa]);

    int cur = 0;
    for (int k0 = 0; k0 < C_; k0 += 32) {
        if (k0 + 32 < C_) VMCNT(2); else VMCNT(0);
        BARRIER();
        if (k0 + 64 < C_) {
            const int nx = cur ? cur - 1 : 2;
            glds16(ap + k0 + 64, &As[nx][loa]);
            glds16(bwp + k0 + 64, &Bs[nx][loa]);
        }
        bf16x8 af, bf[4];
        af = *(const bf16x8*)&As[cur][(w * 16 + lr) * 32 + lq * 8];
#pragma unroll
        for (int b = 0; b < 4; ++b)
            bf[b] = *(const bf16x8*)&Bs[cur][(b * 16 + lr) * 32 + lq * 8];
#pragma unroll
        for (int b = 0; b < 4; ++b)
            acc[b] = __builtin_amdgcn_mfma_f32_16x16x32_bf16(af, bf[b], acc[b], 0, 0, 0);
        cur = (cur == 2) ? 0 : cur + 1;
    }

    // epilogue
    const int bb = m0 >> 11;   // batch uniform per block (64 | 2048)
    float colsum[4] = {0.f, 0.f, 0.f, 0.f};
#pragma unroll
    for (int r = 0; r < 4; ++r) {
        const int row = m0 + w * 16 + lq * 4 + r;
        const bool dead = (mask[row] == 0);
        const int ll = row & (L_ - 1);
        float v[4];
        float mx = -3.4e38f;
#pragma unroll
        for (int b = 0; b < 4; ++b) {
            const int col = b * 16 + lr;
            float t = acc[b][r] + bp[col];
            if (dead) t = NEG_;
            v[b] = t;
            mx = fmaxf(mx, t);
            const float eL = __expf(t);          // 0 for dead rows
            colsum[b] += eL;
            pALT[((size_t)bb * R_ + col) * L_ + ll] = bfbits(eL);
        }
        // r-softmax (keeps max-sub: dead rows give uniform 1/64 like ref)
#pragma unroll
        for (int o = 1; o < 16; o <<= 1) mx = fmaxf(mx, __shfl_xor(mx, o, 64));
        float e[4], s = 0.f;
#pragma unroll
        for (int b = 0; b < 4; ++b) { e[b] = __expf(v[b] - mx); s += e[b]; }
#pragma unroll
        for (int o = 1; o < 16; o <<= 1) s += __shfl_xor(s, o, 64);
        const float inv = 1.0f / s;
#pragma unroll
        for (int b = 0; b < 4; ++b)
            pAR16[(size_t)row * R_ + b * 16 + lr] = bfbits(e[b] * inv);
    }
    // per-column exp-sum: reduce over lq (rows within wave), then atomics
#pragma unroll
    for (int b = 0; b < 4; ++b) {
        colsum[b] += __shfl_xor(colsum[b], 16, 64);
        colsum[b] += __shfl_xor(colsum[b], 32, 64);
    }
    if (lq == 0) {
#pragma unroll
        for (int b = 0; b < 4; ++b)
            atomicAdd(&sums[bb * R_ + b * 16 + lr], colsum[b]);
    }
}

// ---------------------------------------------------------------------------
// qkv GEMM: tile 64(M) x 64(N), K=C=512, grid 8 x 18 = 144 blocks.
// Same verified geometry as pscore_gemm; silu epilogue to qkv16 [B*R, 1152].
// ---------------------------------------------------------------------------
__global__ __launch_bounds__(256) void qkv64(
    const ushort* __restrict__ px16, const ushort* __restrict__ Wqkvt,
    const float* __restrict__ bqkv, ushort* __restrict__ qkv16)
{
    __shared__ ushort As[3][64 * 32];
    __shared__ ushort Bs[3][64 * 32];

    const int nt = blockIdx.x % 18, mt = blockIdx.x / 18;
    const int m0 = mt * 64, n0 = nt * 64;

    const int tid = threadIdx.x;
    const int lane = tid & 63, w = tid >> 6;
    const int lr = lane & 15, lq = lane >> 4;
    const int sr = lane >> 2, sc = (lane & 3) * 8;

    const ushort* ap  = px16 + (size_t)(m0 + w * 16 + sr) * C_ + sc;
    const ushort* bwp = Wqkvt + (size_t)(n0 + w * 16 + sr) * C_ + sc;
    const int loa = w * 512 + lane * 8;

    f32x4 acc[4];
#pragma unroll
    for (int b = 0; b < 4; ++b) acc[b] = (f32x4){0.f, 0.f, 0.f, 0.f};

    glds16(ap, &As[0][loa]);
    glds16(bwp, &Bs[0][loa]);
    glds16(ap + 32, &As[1][loa]);
    glds16(bwp + 32, &Bs[1][loa]);

    int cur = 0;
    for (int k0 = 0; k0 < C_; k0 += 32) {
        if (k0 + 32 < C_) VMCNT(2); else VMCNT(0);
        BARRIER();
        if (k0 + 64 < C_) {
            const int nx = cur ? cur - 1 : 2;
            glds16(ap + k0 + 64, &As[nx][loa]);
            glds16(bwp + k0 + 64, &Bs[nx][loa]);
        }
        bf16x8 af, bf[4];
        af = *(const bf16x8*)&As[cur][(w * 16 + lr) * 32 + lq * 8];
#pragma unroll
        for (int b = 0; b < 4; ++b)
            bf[b] = *(const bf16x8*)&Bs[cur][(b * 16 + lr) * 32 + lq * 8];
#pragma unroll
        for (int b = 0; b < 4; ++b)
            acc[b] = __builtin_amdgcn_mfma_f32_16x16x32_bf16(af, bf[b], acc[b], 0, 0, 0);
        cur = (cur == 2) ? 0 : cur + 1;
    }

#pragma unroll
    for (int r = 0; r < 4; ++r) {
        const int row = m0 + w * 16 + lq * 4 + r;
#pragma unroll
        for (int b = 0; b < 4; ++b) {
            const int col = n0 + b * 16 + lr;
            qkv16[(size_t)row * NQKV_ + col] = bfbits(siluf(acc[b][r] + bqkv[col]));
        }
    }
}

// ---------------------------------------------------------------------------
// Fused gate+expand: zg = silu(x@Wu + bu) * (pAR @ zsT[b]) over [M, H].
// 256x128 tile, 8 waves (4M x 2N), 18-tile stream (2 expand + 16 gate),
// 2-buffer ping-pong __syncthreads. 48 KB LDS, grid 512.
// [round-7/8/9 measured: 43.4 us, VGPR 92 — kept byte-identical.
//  NOTE: the 3-buf counted-vmcnt variant of THIS kernel is implicated in
//  container failures r5 and r10 — do not retry without isolation.]
// ---------------------------------------------------------------------------
__global__ __launch_bounds__(512) void fused_gate_z(
    const ushort* __restrict__ x16, const ushort* __restrict__ Wut,
    const float* __restrict__ bu,
    const ushort* __restrict__ pAR, const ushort* __restrict__ zsT,
    ushort* __restrict__ zg)
{
    __shared__ ushort As[2][256 * 32];   // 2 x 16 KB
    __shared__ ushort Bs[2][128 * 32];   // 2 x 8 KB

    const int i = blockIdx.x;
    const int G = gridDim.x >> 3;        // grid = 512, %8==0
    const int gi = (i & 7) * G + (i >> 3);
    constexpr int gridN = H_ / 128;      // 8
    const int nt = gi % gridN, mt = gi / gridN;
    const int m0 = mt * 256, n0 = nt * 128;

    const int tid = threadIdx.x;
    const int lane = tid & 63, w = tid >> 6;   // 8 waves
    const int wm = (w & 3) * 64, wn = (w >> 2) * 64;
    const int lr = lane & 15, lq = lane >> 4;
    const int sr = lane >> 2, sc = (lane & 3) * 8;
    const int s0 = w * 2, s1 = w * 2 + 1;

    const int bidx = m0 >> 11;           // batch (2048 % 256 == 0)
    const ushort* a0p = x16 + (size_t)(m0 + s0 * 16 + sr) * C_ + sc;
    const ushort* a1p = x16 + (size_t)(m0 + s1 * 16 + sr) * C_ + sc;
    const ushort* b0p = Wut + (size_t)(n0 + w * 16 + sr) * C_ + sc;
    const ushort* zb  = zsT + (size_t)bidx * H_ * R_;
    const ushort* c0p = pAR + (size_t)(m0 + s0 * 16 + sr) * R_ + sc;
    const ushort* c1p = pAR + (size_t)(m0 + s1 * 16 + sr) * R_ + sc;
    const ushort* d0p = zb + (size_t)(n0 + w * 16 + sr) * R_ + sc;
    const int lo0 = s0 * 512 + lane * 8;
    const int lo1 = s1 * 512 + lane * 8;
    const int lob = w * 512 + lane * 8;

    // tile t: t<2 -> expand (pAR/zsT, k=t*32); t>=2 -> gate (x16/Wut, k=(t-2)*32)
    auto stage = [&](int t, int bsel) {
        if (t < 2) {
            const int off = t * 32;
            glds16(c0p + off, &As[bsel][lo0]);
            glds16(c1p + off, &As[bsel][lo1]);
            glds16(d0p + off, &Bs[bsel][lob]);
        } else {
            const int off = (t - 2) * 32;
            glds16(a0p + off, &As[bsel][lo0]);
            glds16(a1p + off, &As[bsel][lo1]);
            glds16(b0p + off, &Bs[bsel][lob]);
        }
    };

    f32x4 acc[4][4];
#pragma unroll
    for (int a = 0; a < 4; ++a)
#pragma unroll
        for (int b = 0; b < 4; ++b) acc[a][b] = (f32x4){0.f, 0.f, 0.f, 0.f};

    uint pk[4][4][2];

    stage(0, 0);

    int cur = 0;
    for (int t = 0; t < 18; ++t) {
        __syncthreads();
        if (t + 1 < 18) stage(t + 1, cur ^ 1);
        bf16x8 af[4], bf[4];
#pragma unroll
        for (int a = 0; a < 4; ++a)
            af[a] = *(const bf16x8*)&As[cur][(wm + a * 16 + lr) * 32 + lq * 8];
#pragma unroll
        for (int b = 0; b < 4; ++b)
            bf[b] = *(const bf16x8*)&Bs[cur][(wn + b * 16 + lr) * 32 + lq * 8];
#pragma unroll
        for (int a = 0; a < 4; ++a)
#pragma unroll
            for (int b = 0; b < 4; ++b)
                acc[a][b] = __builtin_amdgcn_mfma_f32_16x16x32_bf16(af[a], bf[b], acc[a][b], 0, 0, 0);
        if (t == 1) {
            // expand done: pack to bf16 (matches old zg path precision), reset acc
#pragma unroll
            for (int a = 0; a < 4; ++a)
#pragma unroll
                for (int b = 0; b < 4; ++b) {
                    pk[a][b][0] = (uint)bfbits(acc[a][b][0]) | ((uint)bfbits(acc[a][b][1]) << 16);
                    pk[a][b][1] = (uint)bfbits(acc[a][b][2]) | ((uint)bfbits(acc[a][b][3]) << 16);
                    acc[a][b] = (f32x4){0.f, 0.f, 0.f, 0.f};
                }
        }
        cur ^= 1;
    }

    // epilogue: zg = silu(gate) * expand
#pragma unroll
    for (int a = 0; a < 4; ++a) {
#pragma unroll
        for (int b = 0; b < 4; ++b) {
            const int col = n0 + wn + b * 16 + lr;
            const float bn = bu[col];
#pragma unroll
            for (int r = 0; r < 4; ++r) {
                const int row = m0 + wm + a * 16 + lq * 4 + r;
                const ushort zu = (ushort)((r & 1) ? (pk[a][b][r >> 1] >> 16)
                                                   : (pk[a][b][r >> 1] & 0xffff));
                const float v = siluf(acc[a][b][r] + bn) * bf2f(zu);
                zg[(size_t)row * H_ + col] = bfbits(v);
            }
        }
    }
}

// ---------------------------------------------------------------------------
// Merged prep: blocks [0, 8192): x fp32 -> x16 + xT16; [8192, 9824): weight
// transposes; block 9824: zero sums[B*R] for pscore atomics.
// ---------------------------------------------------------------------------
__global__ __launch_bounds__(256) void xw_prep(
    const float* __restrict__ x, ushort* __restrict__ x16, ushort* __restrict__ xT16,
    const float* __restrict__ Wu, const float* __restrict__ Wo, const float* __restrict__ Wp,
    const float* __restrict__ Wq, const float* __restrict__ bq,
    const float* __restrict__ Wk, const float* __restrict__ bk,
    const float* __restrict__ Wv, const float* __restrict__ bv,
    ushort* __restrict__ Wut, ushort* __restrict__ Wot, ushort* __restrict__ Wpt,
    ushort* __restrict__ Wqkvt, float* __restrict__ bqkv, float* __restrict__ sums)
{
    __shared__ float tile[32][33];
    const int tx = threadIdx.x & 31, ty = threadIdx.x >> 5;   // 32x8
    int id = blockIdx.x;

    if (id == 8192 + 1632) {   // zero sums (512 floats)
        sums[threadIdx.x] = 0.f;
        sums[threadIdx.x + 256] = 0.f;
        return;
    }

    if (id < 8192) {   // x part: 16 x 512 tiles of 32x32
        const int c0 = (id & 15) * 32, l0 = (id >> 4) * 32;
#pragma unroll
        for (int i = 0; i < 32; i += 8) {
            const float v = x[(size_t)(l0 + ty + i) * C_ + c0 + tx];
            tile[ty + i][tx] = v;
            x16[(size_t)(l0 + ty + i) * C_ + c0 + tx] = bfbits(v);
        }
        __syncthreads();
        const int bb = l0 >> 11, ll0 = l0 & (L_ - 1);
#pragma unroll
        for (int i = 0; i < 32; i += 8)
            xT16[((size_t)bb * C_ + c0 + ty + i) * L_ + ll0 + tx] = bfbits(tile[tx][ty + i]);
        return;
    }
    id -= 8192;

    const float* W; ushort* Wt; const float* bsrc = nullptr;
    int K, Nloc, n0, k0, nn0;
    if (id < 512) {                 // Wu [512,1024] -> Wut [1024,512]
        W = Wu; Wt = Wut; K = 512; Nloc = 1024;
        n0 = (id & 31) * 32; k0 = (id >> 5) * 32; nn0 = n0;
    } else if (id < 1024) {         // Wo [1024,512] -> Wot [512,1024]
        id -= 512; W = Wo; Wt = Wot; K = 1024; Nloc = 512;
        n0 = (id & 15) * 32; k0 = (id >> 4) * 32; nn0 = n0;
    } else if (id < 1056) {         // Wp [512,64] -> Wpt [64,512]
        id -= 1024; W = Wp; Wt = Wpt; K = 512; Nloc = 64;
        n0 = (id & 1) * 32; k0 = (id >> 1) * 32; nn0 = n0;
    } else {                        // qkv: 36 x 16 tiles over [1152,512]
        id -= 1056; K = 512; Wt = Wqkvt;
        n0 = (id % 36) * 32; k0 = (id / 36) * 32;
        if (n0 < 64)       { W = Wq; bsrc = bq; Nloc = 64;   nn0 = n0; }
        else if (n0 < 128) { W = Wk; bsrc = bk; Nloc = 64;   nn0 = n0 - 64; }
        else               { W = Wv; bsrc = bv; Nloc = 1024; nn0 = n0 - 128; }
    }
#pragma unroll
    for (int i = 0; i < 32; i += 8)
        tile[ty + i][tx] = W[(size_t)(k0 + ty + i) * Nloc + nn0 + tx];
    __syncthreads();
#pragma unroll
    for (int i = 0; i < 32; i += 8)
        Wt[(size_t)(n0 + ty + i) * K + k0 + tx] = bfbits(tile[tx][ty + i]);
    if (bsrc && k0 == 0 && threadIdx.x < 32) bqkv[n0 + threadIdx.x] = bsrc[nn0 + threadIdx.x];
}

// px parts: K-split(8) MFMA compress. Tile 64(M=R) x 128(N), BK=32, 4 waves,
// grid dim3(C/128=4, B=8, 8) = 256 blocks. 3-buffer counted vmcnt(3).
// A = pALT (unnormalized exp bf16) — normalization applied in reduce.
__global__ __launch_bounds__(256) void compress_mfma(
    const ushort* __restrict__ pALT, const ushort* __restrict__ xT,
    float* __restrict__ parts)
{
    __shared__ ushort As[3][64 * 32];    // 3 x 4 KB
    __shared__ ushort Bs[3][128 * 32];   // 3 x 8 KB

    const int bidx = blockIdx.y;
    const int n0 = blockIdx.x * 128;
    const int ks = blockIdx.z;
    const int kbeg = ks * (L_ / 8), kend = kbeg + L_ / 8;
    const int tid = threadIdx.x;
    const int lane = tid & 63, w = tid >> 6;          // 4 waves
    const int lr = lane & 15, lq = lane >> 4;
    const int sr = lane >> 2, sc = (lane & 3) * 8;
    const int wm = (w & 1) * 32, wn = (w >> 1) * 64;

    const ushort* Ab = pALT + (size_t)bidx * R_ * L_;
    const ushort* Bb = xT + (size_t)bidx * C_ * L_;

    const ushort* ap  = Ab + (size_t)(w * 16 + sr) * L_ + sc;              // A seg w (4)
    const ushort* b0p = Bb + (size_t)(n0 + (2 * w) * 16 + sr) * L_ + sc;   // B segs 2w, 2w+1
    const ushort* b1p = Bb + (size_t)(n0 + (2 * w + 1) * 16 + sr) * L_ + sc;
    const int alo  = w * 512 + lane * 8;
    const int blo0 = (2 * w) * 512 + lane * 8;
    const int blo1 = (2 * w + 1) * 512 + lane * 8;

    auto stage = [&](int k0, int bsel) {
        glds16(ap + k0, &As[bsel][alo]);
        glds16(b0p + k0, &Bs[bsel][blo0]);
        glds16(b1p + k0, &Bs[bsel][blo1]);
    };

    f32x4 acc[2][4];
#pragma unroll
    for (int a = 0; a < 2; ++a)
#pragma unroll
        for (int b = 0; b < 4; ++b) acc[a][b] = (f32x4){0.f, 0.f, 0.f, 0.f};

    stage(kbeg, 0);
    stage(kbeg + 32, 1);

    int cur = 0;
    for (int k0 = kbeg; k0 < kend; k0 += 32) {
        if (k0 + 32 < kend) VMCNT(3); else VMCNT(0);
        BARRIER();
        if (k0 + 64 < kend) stage(k0 + 64, cur ? cur - 1 : 2);
        bf16x8 af[2], bf[4];
#pragma unroll
        for (int a = 0; a < 2; ++a)
            af[a] = *(const bf16x8*)&As[cur][(wm + a * 16 + lr) * 32 + lq * 8];
#pragma unroll
        for (int b = 0; b < 4; ++b)
            bf[b] = *(const bf16x8*)&Bs[cur][(wn + b * 16 + lr) * 32 + lq * 8];
#pragma unroll
        for (int a = 0; a < 2; ++a)
#pragma unroll
            for (int b = 0; b < 4; ++b)
                acc[a][b] = __builtin_amdgcn_mfma_f32_16x16x32_bf16(af[a], bf[b], acc[a][b], 0, 0, 0);
        cur = (cur == 2) ? 0 : cur + 1;
    }
#pragma unroll
    for (int a = 0; a < 2; ++a)
#pragma unroll
        for (int b = 0; b < 4; ++b)
#pragma unroll
            for (int r = 0; r < 4; ++r) {
                const int row = wm + a * 16 + lq * 4 + r;
                const int col = n0 + wn + b * 16 + lr;
                parts[(((size_t)ks * B_ + bidx) * R_ + row) * C_ + col] = acc[a][b][r];
            }
}

// reduce 8 K-split parts -> px16 bf16, applying 1/sums[row] (L-softmax norm)
__global__ __launch_bounds__(256) void compress_reduce16(const float* __restrict__ parts,
                                                         const float* __restrict__ sums,
                                                         ushort* __restrict__ px16)
{
    const size_t i = ((size_t)blockIdx.x * 256 + threadIdx.x) * 4;
    constexpr size_t S = (size_t)B_ * R_ * C_;
    float4 s = *(const float4*)(parts + i);
#pragma unroll
    for (int k = 1; k < 8; ++k) {
        const float4 p = *(const float4*)(parts + i + (size_t)k * S);
        s.x += p.x; s.y += p.y; s.z += p.z; s.w += p.w;
    }
    const float inv = 1.0f / sums[i / C_];
    ushort4 o;
    o.x = bfbits(s.x * inv); o.y = bfbits(s.y * inv);
    o.z = bfbits(s.z * inv); o.w = bfbits(s.w * inv);
    *(ushort4*)(px16 + i) = o;
}

// fused scores+softmax+z from bf16 qkv16 [B*R, 1152] (q|k|v concat).
// PV vectorized: each thread owns 4 consecutive h (ushort4 V loads,
// 8B-aligned: row stride 2304 B, offset 256 B, both 8-divisible).
__global__ __launch_bounds__(256) void attn_fused(
    const ushort* __restrict__ qkv, const float* __restrict__ preS,
    ushort* __restrict__ zsT)
{
    const int b = blockIdx.x >> 6, r = blockIdx.x & 63;
    const int t = threadIdx.x;
    __shared__ float al[R_];
    if (t < 64) {
        const ushort* qr = qkv + (size_t)(b * R_ + r) * NQKV_;
        const ushort* ks = qkv + (size_t)(b * R_ + t) * NQKV_ + 64;
        float acc = 0.f;
#pragma unroll
        for (int d = 0; d < DK_; d += 4) {
            const ushort4 qa = *(const ushort4*)(qr + d);
            const ushort4 ka = *(const ushort4*)(ks + d);
            acc += bf2f(qa.x) * bf2f(ka.x) + bf2f(qa.y) * bf2f(ka.y)
                 + bf2f(qa.z) * bf2f(ka.z) + bf2f(qa.w) * bf2f(ka.w);
        }
        acc = acc * 0.125f + preS[((size_t)b * R_ + r) * R_ + t];
        float mx = acc;
#pragma unroll
        for (int o = 32; o > 0; o >>= 1) mx = fmaxf(mx, __shfl_xor(mx, o, 64));
        float e = __expf(acc - mx);
        float sm = e;
#pragma unroll
        for (int o = 32; o > 0; o >>= 1) sm += __shfl_xor(sm, o, 64);
        al[t] = e / sm;
    }
    __syncthreads();
    float acc[4] = {};
    for (int s = 0; s < R_; ++s) {
        const float a = al[s];
        const ushort4 vv = *(const ushort4*)(qkv + (size_t)(b * R_ + s) * NQKV_ + 128 + t * 4);
        acc[0] += a * bf2f(vv.x);
        acc[1] += a * bf2f(vv.y);
        acc[2] += a * bf2f(vv.z);
        acc[3] += a * bf2f(vv.w);
    }
#pragma unroll
    for (int j = 0; j < 4; ++j) {
        const int h = t * 4 + j;
        zsT[((size_t)b * H_ + h) * R_ + r] = bfbits(acc[j]);
    }
}

// Row layernorm, wave-per-row: 4 rows/block, shuffle-only reduce (no LDS).
__global__ __launch_bounds__(256) void layernorm(const ushort* __restrict__ y,
                                                 const float* __restrict__ gamma,
                                                 const float* __restrict__ beta,
                                                 float* __restrict__ out)
{
    const int w = threadIdx.x >> 6, lane = threadIdx.x & 63;
    const size_t m = (size_t)blockIdx.x * 4 + w;
    const ushort* yr = y + m * C_ + lane * 8;
    const ushort4 p0 = *(const ushort4*)(yr);
    const ushort4 p1 = *(const ushort4*)(yr + 4);
    float v[8] = { bf2f(p0.x), bf2f(p0.y), bf2f(p0.z), bf2f(p0.w),
                   bf2f(p1.x), bf2f(p1.y), bf2f(p1.z), bf2f(p1.w) };
    float s = 0.f, q = 0.f;
#pragma unroll
    for (int j = 0; j < 8; ++j) { s += v[j]; q += v[j] * v[j]; }
#pragma unroll
    for (int o = 32; o > 0; o >>= 1) {
        s += __shfl_xor(s, o, 64);
        q += __shfl_xor(q, o, 64);
    }
    const float mu = s * (1.0f / C_);
    const float var = q * (1.0f / C_) - mu * mu;
    const float inv = rsqrtf(var + 1e-5f);
    const float4 g0 = *(const float4*)(gamma + lane * 8);
    const float4 g1 = *(const float4*)(gamma + lane * 8 + 4);
    const float4 b0 = *(const float4*)(beta + lane * 8);
    const float4 b1 = *(const float4*)(beta + lane * 8 + 4);
    float4 o0, o1;
    o0.x = (v[0] - mu) * inv * g0.x + b0.x;
    o0.y = (v[1] - mu) * inv * g0.y + b0.y;
    o0.z = (v[2] - mu) * inv * g0.z + b0.z;
    o0.w = (v[3] - mu) * inv * g0.w + b0.w;
    o1.x = (v[4] - mu) * inv * g1.x + b1.x;
    o1.y = (v[5] - mu) * inv * g1.y + b1.y;
    o1.z = (v[6] - mu) * inv * g1.z + b1.z;
    o1.w = (v[7] - mu) * inv * g1.w + b1.w;
    *(float4*)(out + m * C_ + lane * 8) = o0;
    *(float4*)(out + m * C_ + lane * 8 + 4) = o1;
}

// ---- compact-path SIMT kernels (dead in practice, kept for safety) ----
template <typename AT, typename BT, typename RT, int ACT, int EPI>
__global__ __launch_bounds__(256) void gemm64(
    const AT* __restrict__ A, const BT* __restrict__ Bw,
    const float* __restrict__ bias, const int* __restrict__ mask,
    const RT* resid, float* __restrict__ outF, __hip_bfloat16* outB,
    int Ndim, int Kdim, long bBatchStride)
{
    __shared__ float As[16][68];
    __shared__ float Bs[16][64];
    const int tid = threadIdx.x;
    const int tx = tid & 15, ty = tid >> 4;
    const int n0 = blockIdx.x * 64, m0 = blockIdx.y * 64;
    const BT* Bp = Bw + (bBatchStride ? (long)(m0 / L_) * bBatchStride : 0);
    float acc[4][4] = {};
    for (int k0 = 0; k0 < Kdim; k0 += 16) {
#pragma unroll
        for (int s = 0; s < 4; ++s) {
            int idx = tid + s * 256;
            int am = idx >> 4, ak = idx & 15;
            As[ak][am] = toF(A[(size_t)(m0 + am) * Kdim + k0 + ak]);
        }
#pragma unroll
        for (int s = 0; s < 4; ++s) {
            int idx = tid + s * 256;
            int bk = idx >> 6, bn = idx & 63;
            Bs[bk][bn] = toF(Bp[(size_t)(k0 + bk) * Ndim + n0 + bn]);
        }
        __syncthreads();
#pragma unroll
        for (int kk = 0; kk < 16; ++kk) {
            float av[4], bv[4];
            *(float4*)av = *(const float4*)&As[kk][ty * 4];
            *(float4*)bv = *(const float4*)&Bs[kk][tx * 4];
#pragma unroll
            for (int i = 0; i < 4; ++i)
#pragma unroll
                for (int j = 0; j < 4; ++j) acc[i][j] += av[i] * bv[j];
        }
        __syncthreads();
    }
#pragma unroll
    for (int i = 0; i < 4; ++i) {
        int m = m0 + ty * 4 + i;
#pragma unroll
        for (int j = 0; j < 4; ++j) {
            int n = n0 + tx * 4 + j;
            float val = acc[i][j];
            if (EPI != 3) val += bias[n];
            if (ACT) val = siluf(val);
            if (EPI == 0) outB[(size_t)m * Ndim + n] = __float2bfloat16(val);
            else if (EPI == 1) { if (mask[m] == 0) val = NEG_; outF[(size_t)m * Ndim + n] = val; }
            else if (EPI == 2) { val += toF(resid[(size_t)m * Ndim + n]); outB[(size_t)m * Ndim + n] = __float2bfloat16(val); }
            else { val *= toF(resid[(size_t)m * Ndim + n]); outB[(size_t)m * Ndim + n] = __float2bfloat16(val); }
        }
    }
}

template <int OUT>
__global__ __launch_bounds__(64) void softmaxR(const float* __restrict__ pScore,
                                               float* __restrict__ outF,
                                               ushort* __restrict__ outU)
{
    const size_t m = blockIdx.x;
    const int t = threadIdx.x;
    float v = pScore[m * R_ + t];
    float mx = v;
#pragma unroll
    for (int o = 32; o > 0; o >>= 1) mx = fmaxf(mx, __shfl_xor(mx, o, 64));
    float e = __expf(v - mx);
    float s = e;
#pragma unroll
    for (int o = 32; o > 0; o >>= 1) s += __shfl_xor(s, o, 64);
    if (OUT == 0) outF[m * R_ + t] = e / s;
    else          outU[m * R_ + t] = bfbits(e / s);
}

__global__ __launch_bounds__(256) void softmaxL(const float* __restrict__ pScore,
                                                float* __restrict__ pAlpha)
{
    const int b = blockIdx.x >> 6, r = blockIdx.x & 63;
    const int t = threadIdx.x;
    const float* base = pScore + (size_t)b * L_ * R_ + r;
    float* out = pAlpha + (size_t)b * L_ * R_ + r;
    __shared__ float red[256];
    float mx = -3.4e38f;
    for (int l = t; l < L_; l += 256) mx = fmaxf(mx, base[(size_t)l * R_]);
    red[t] = mx; __syncthreads();
    for (int s = 128; s > 0; s >>= 1) { if (t < s) red[t] = fmaxf(red[t], red[t + s]); __syncthreads(); }
    mx = red[0]; __syncthreads();
    float sum = 0.f;
    for (int l = t; l < L_; l += 256) {
        float e = __expf(base[(size_t)l * R_] - mx);
        out[(size_t)l * R_] = e; sum += e;
    }
    red[t] = sum; __syncthreads();
    for (int s = 128; s > 0; s >>= 1) { if (t < s) red[t] += red[t + s]; __syncthreads(); }
    const float inv = 1.0f / red[0];
    for (int l = t; l < L_; l += 256) out[(size_t)l * R_] *= inv;
}

__global__ __launch_bounds__(256) void compress_part(
    const float* __restrict__ pAlpha, const float* __restrict__ x,
    float* __restrict__ parts)
{
    __shared__ float As[16][64];
    __shared__ float Bs[16][64];
    const int tid = threadIdx.x;
    const int tx = tid & 15, ty = tid >> 4;
    const int n0 = blockIdx.x * 64;
    const int ks = blockIdx.y;
    const int b  = blockIdx.z;
    const float* pa = pAlpha + (size_t)b * L_ * R_;
    const float* xb = x + (size_t)b * L_ * C_;
    float acc[4][4] = {};
    const int kbeg = ks * (L_ / 4), kend = kbeg + L_ / 4;
    for (int k0 = kbeg; k0 < kend; k0 += 16) {
#pragma unroll
        for (int s = 0; s < 4; ++s) {
            int idx = tid + s * 256;
            int kk = idx >> 6, m = idx & 63;
            As[kk][m] = pa[(size_t)(k0 + kk) * R_ + m];
        }
#pragma unroll
        for (int s = 0; s < 4; ++s) {
            int idx = tid + s * 256;
            int kk = idx >> 6, n = idx & 63;
            Bs[kk][n] = xb[(size_t)(k0 + kk) * C_ + n0 + n];
        }
        __syncthreads();
#pragma unroll
        for (int kk = 0; kk < 16; ++kk) {
            float av[4], bv[4];
            *(float4*)av = *(const float4*)&As[kk][ty * 4];
            *(float4*)bv = *(const float4*)&Bs[kk][tx * 4];
#pragma unroll
            for (int i = 0; i < 4; ++i)
#pragma unroll
                for (int j = 0; j < 4; ++j) acc[i][j] += av[i] * bv[j];
        }
        __syncthreads();
    }
#pragma unroll
    for (int i = 0; i < 4; ++i)
#pragma unroll
        for (int j = 0; j < 4; ++j)
            parts[((((size_t)ks * B_ + b) * R_) + ty * 4 + i) * C_ + n0 + tx * 4 + j] = acc[i][j];
}

__global__ __launch_bounds__(256) void compress_reduce(const float* __restrict__ parts,
                                                       float* __restrict__ px)
{
    const size_t i = (size_t)blockIdx.x * 256 + threadIdx.x;
    constexpr size_t S = (size_t)B_ * R_ * C_;
    px[i] = parts[i] + parts[i + S] + parts[i + 2 * S] + parts[i + 3 * S];
}

__global__ __launch_bounds__(256) void qkv_gemm(
    const float* __restrict__ px,
    const float* __restrict__ Wq, const float* __restrict__ bq,
    const float* __restrict__ Wk, const float* __restrict__ bk,
    const float* __restrict__ Wv, const float* __restrict__ bv,
    float* __restrict__ q, float* __restrict__ k, float* __restrict__ v)
{
    __shared__ float As[16][68];
    __shared__ float Bs[16][64];
    const int tid = threadIdx.x;
    const int tx = tid & 15, ty = tid >> 4;
    const int bx = blockIdx.x;
    const int m0 = blockIdx.y * 64;
    const float* W; const float* bias; float* dst; int Nloc, ncol0;
    if (bx == 0)      { W = Wq; bias = bq; dst = q; Nloc = 64;   ncol0 = 0; }
    else if (bx == 1) { W = Wk; bias = bk; dst = k; Nloc = 64;   ncol0 = 0; }
    else              { W = Wv; bias = bv; dst = v; Nloc = H_;   ncol0 = (bx - 2) * 64; }

    float acc[4][4] = {};
    for (int k0 = 0; k0 < C_; k0 += 16) {
#pragma unroll
        for (int s = 0; s < 4; ++s) {
            int idx = tid + s * 256;
            int am = idx >> 4, ak = idx & 15;
            As[ak][am] = px[(size_t)(m0 + am) * C_ + k0 + ak];
        }
#pragma unroll
        for (int s = 0; s < 4; ++s) {
            int idx = tid + s * 256;
            int kk = idx >> 6, bn = idx & 63;
            Bs[kk][bn] = W[(size_t)(k0 + kk) * Nloc + ncol0 + bn];
        }
        __syncthreads();
#pragma unroll
        for (int kk = 0; kk < 16; ++kk) {
            float av[4], bv4[4];
            *(float4*)av = *(const float4*)&As[kk][ty * 4];
            *(float4*)bv4 = *(const float4*)&Bs[kk][tx * 4];
#pragma unroll
            for (int i = 0; i < 4; ++i)
#pragma unroll
                for (int j = 0; j < 4; ++j) acc[i][j] += av[i] * bv4[j];
        }
        __syncthreads();
    }
#pragma unroll
    for (int i = 0; i < 4; ++i) {
        int m = m0 + ty * 4 + i;
#pragma unroll
        for (int j = 0; j < 4; ++j) {
            int n = ncol0 + tx * 4 + j;
            dst[(size_t)m * Nloc + n] = siluf(acc[i][j] + bias[n]);
        }
    }
}

template <int MODE>
__global__ __launch_bounds__(256) void attn_z(const float* __restrict__ alpha,
                                              const float* __restrict__ v,
                                              float* __restrict__ zsF,
                                              ushort* __restrict__ zsT)
{
    const int b = blockIdx.x >> 6, r = blockIdx.x & 63;
    const int t = threadIdx.x;
    __shared__ float al[R_];
    if (t < R_) al[t] = alpha[((size_t)b * R_ + r) * R_ + t];
    __syncthreads();
    float acc[4] = {};
    for (int s = 0; s < R_; ++s) {
        float a = al[s];
        const float* vr = v + ((size_t)b * R_ + s) * H_;
#pragma unroll
        for (int j = 0; j < 4; ++j) acc[j] += a * vr[t + j * 256];
    }
#pragma unroll
    for (int j = 0; j < 4; ++j) {
        const int h = t + j * 256;
        if (MODE == 0) zsF[((size_t)b * R_ + r) * H_ + h] = acc[j];
        else           zsT[((size_t)b * H_ + h) * R_ + r] = bfbits(acc[j]);
    }
}

__global__ __launch_bounds__(64) void attn_scores(
    const float* __restrict__ q, const float* __restrict__ k,
    const float* __restrict__ preS, float* __restrict__ alpha)
{
    const int b = blockIdx.x >> 6, r = blockIdx.x & 63;
    const int s = threadIdx.x;
    const float* qr = q + ((size_t)b * R_ + r) * DK_;
    const float* ks = k + ((size_t)b * R_ + s) * DK_;
    float acc = 0.f;
#pragma unroll
    for (int d = 0; d < DK_; ++d) acc += qr[d] * ks[d];
    acc = acc * 0.125f + preS[((size_t)b * R_ + r) * R_ + s];
    float mx = acc;
#pragma unroll
    for (int o = 32; o > 0; o >>= 1) mx = fmaxf(mx, __shfl_xor(mx, o, 64));
    float e = __expf(acc - mx);
    float sm = e;
#pragma unroll
    for (int o = 32; o > 0; o >>= 1) sm += __shfl_xor(sm, o, 64);
    alpha[((size_t)b * R_ + r) * R_ + s] = e / sm;
}

extern "C" void kernel_launch(void* const* d_in, const int* in_sizes, int n_in,
                              void* d_out, int out_size, void* d_ws, size_t ws_size,
                              hipStream_t stream)
{
    using bf16 = __hip_bfloat16;
    const float* x      = (const float*)d_in[0];
    const int*  maskPAD = (const int*)d_in[1];
    const float* preS   = (const float*)d_in[2];
    const float* Wp     = (const float*)d_in[3];
    const float* bp     = (const float*)d_in[4];
    const float* Wq     = (const float*)d_in[5];
    const float* bq     = (const float*)d_in[6];
    const float* Wk     = (const float*)d_in[7];
    const float* bk     = (const float*)d_in[8];
    const float* Wv     = (const float*)d_in[9];
    const float* bv     = (const float*)d_in[10];
    const float* Wu     = (const float*)d_in[11];
    const float* bu     = (const float*)d_in[12];
    const float* Wo     = (const float*)d_in[13];
    const float* bo     = (const float*)d_in[14];
    const float* gamma  = (const float*)d_in[15];
    const float* beta   = (const float*)d_in[16];
    float* out          = (float*)d_out;

    char* ws = (char*)d_ws;
    const bool bigWS = ws_size >= (size_t)52 * 1024 * 1024;  // proven taken

    if (bigWS) {
        // layout: zg 33.5 MB | pool 18.2 MB | Wut | Wot | Wpt
        bf16* zg = (bf16*)ws;                                   // M*H bf16 (written by fused_gate_z)
        float* parts = (float*)ws;                              // 8 MB K-split parts (dead before zg)
        char* pool = ws + (size_t)M_ * H_ * 2;
        ushort* pALT   = (ushort*)pool;                         // B*R*L bf16 exp (2 MB)
        ushort* pAR16  = pALT + (size_t)B_ * R_ * L_;           // M*R bf16 (2 MB)
        ushort* px16   = pAR16 + (size_t)M_ * R_;               // B*R*C bf16 (0.5 MB)
        ushort* qkv16  = px16 + (size_t)B_ * R_ * C_;           // B*R*1152 bf16 (1.19 MB)
        ushort* zsT16  = qkv16 + (size_t)B_ * R_ * NQKV_;       // B*H*R bf16 (1 MB)
        ushort* Wqkvt  = zsT16 + (size_t)B_ * H_ * R_;          // [1152, C] bf16 (1.13 MB)
        float*  bqkv   = (float*)(Wqkvt + (size_t)NQKV_ * C_);  // 4.6 KB
        float*  sums   = bqkv + NQKV_;                          // B*R exp-sums (2 KB)
        bf16*  y       = (bf16*)pool;                           // pre-LN y (16.8 MB), pool dead
        ushort* Wut    = (ushort*)(pool + 18221568);            // [H, C] bf16
        ushort* Wot    = Wut + (size_t)C_ * H_;                 // [C, H] bf16
        ushort* Wpt    = Wot + (size_t)C_ * H_;                 // [R, C] bf16
        ushort* x16    = (ushort*)d_out;                        // [M, C] bf16 (dead before LN)
        ushort* xT16   = x16 + (size_t)M_ * C_;                 // [B, C, L] bf16 (in d_out)

        // 1) prep: x->bf16 (+transpose), weight transposes, zero sums
        xw_prep<<<8192 + 1632 + 1, 256, 0, stream>>>(
            x, x16, xT16, Wu, Wo, Wp, Wq, bq, Wk, bk, Wv, bv,
            Wut, Wot, Wpt, Wqkvt, bqkv, sums);
        // 2) pScore GEMM + fused r-softmax + unnorm exp + col-sum atomics
        pscore_gemm<<<M_ / 64, 256, 0, stream>>>(x16, Wpt, bp, maskPAD,
                                                 pAR16, pALT, sums);
        // 3) px = (exp @ x) / sums  (MFMA K-split x8 -> parts -> scaled bf16)
        compress_mfma<<<dim3(C_ / 128, B_, 8), 256, 0, stream>>>(pALT, xT16, parts);
        compress_reduce16<<<(B_ * R_ * C_) / 1024, 256, 0, stream>>>(parts, sums, px16);
        // 4) q|k|v = silu(px @ Wqkv + b)  (64x64 tiles, grid 144)
        qkv64<<<(B_ * R_ / 64) * (NQKV_ / 64), 256, 0, stream>>>(px16, Wqkvt, bqkv, qkv16);
        attn_fused<<<B_ * R_, 256, 0, stream>>>(qkv16, preS, zsT16);
        // 5) zg = silu(x@Wu+bu) * (pAR @ zsT)   [256x128, 8 waves, 2-buf r9]
        fused_gate_z<<<(H_ / 128) * (M_ / 256), 512, 0, stream>>>(
            x16, Wut, bu, pAR16, zsT16, (ushort*)zg);
        // 6) y = x + zg @ Wo + bo   [128^2 3-buf counted, grid 512 = 2/CU]
        mfma_gemm5<2><<<(C_ / 128) * (M_ / 128), 256, 0, stream>>>(
            (ushort*)zg, Wot, bo, x, nullptr, nullptr, (ushort*)y, nullptr, nullptr,
            C_, H_, C_ / 128, 0);
        layernorm<<<M_ / 4, 256, 0, stream>>>((const ushort*)y, gamma, beta, out);
    } else {
        // ---- Compact plan (~23.4 MiB), SIMT per-batch (dead in practice) ----
        float* pScore = (float*)ws;
        float* pAL   = pScore + (size_t)M_ * R_;
        float* pAR   = pAL    + (size_t)M_ * R_;
        float* px    = pAR    + (size_t)M_ * R_;
        float* q     = px     + (size_t)B_ * R_ * C_;
        float* kk    = q      + (size_t)B_ * R_ * DK_;
        float* vv    = kk     + (size_t)B_ * R_ * DK_;
        float* alpha = vv     + (size_t)B_ * R_ * H_;
        float* zs    = alpha  + (size_t)B_ * R_ * R_;
        bf16* gate_b = (bf16*)(zs + (size_t)B_ * R_ * H_);
        bf16* y_b    = (bf16*)((char*)gate_b + (size_t)L_ * H_ * 2);

        gemm64<float, float, float, 0, 1><<<dim3(R_ / 64, M_ / 64), 256, 0, stream>>>(
            x, Wp, bp, maskPAD, (const float*)nullptr, pScore, nullptr, R_, C_, 0);
        softmaxL<<<B_ * R_, 256, 0, stream>>>(pScore, pAL);
        softmaxR<0><<<M_, 64, 0, stream>>>(pScore, pAR, nullptr);
        compress_part<<<dim3(C_ / 64, 4, B_), 256, 0, stream>>>(pAL, x, pScore);
        compress_reduce<<<(B_ * R_ * C_) / 256, 256, 0, stream>>>(pScore, px);
        qkv_gemm<<<dim3(2 + H_ / 64, (B_ * R_) / 64), 256, 0, stream>>>(
            px, Wq, bq, Wk, bk, Wv, bv, q, kk, vv);
        attn_scores<<<B_ * R_, 64, 0, stream>>>(q, kk, preS, alpha);
        attn_z<0><<<B_ * R_, 256, 0, stream>>>(alpha, vv, zs, nullptr);

        for (int b = 0; b < B_; ++b) {
            const float* xb = x + (size_t)b * L_ * C_;
            gemm64<float, float, float, 1, 0><<<dim3(H_ / 64, L_ / 64), 256, 0, stream>>>(
                xb, Wu, bu, nullptr, (const float*)nullptr, nullptr, gate_b, H_, C_, 0);
            gemm64<float, float, bf16, 0, 3><<<dim3(H_ / 64, L_ / 64), 256, 0, stream>>>(
                pAR + (size_t)b * L_ * R_, zs + (size_t)b * R_ * H_,
                nullptr, nullptr, gate_b, nullptr, gate_b, H_, R_, 0);
            gemm64<bf16, float, float, 0, 2><<<dim3(C_ / 64, L_ / 64), 256, 0, stream>>>(
                gate_b, Wo, bo, nullptr, xb, nullptr, y_b, C_, H_, 0);
            layernorm<<<L_ / 4, 256, 0, stream>>>((const ushort*)y_b, gamma, beta, out + (size_t)b * L_ * C_);
        }
    }
}